// Round 4
// baseline (1907.708 us; speedup 1.0000x reference)
//
#include <hip/hip_runtime.h>
#include <hip/hip_bf16.h>

#define BB 4
#define KK 16
#define NN 50000
#define EE 300000
#define RR 64
#define ERE 2048
#define RT 4
#define DD 64
#define LL 4
#define FCAP 256

__device__ __forceinline__ float wsum64(float v) {
#pragma unroll
    for (int off = 32; off > 0; off >>= 1) v += __shfl_xor(v, off, 64);
    return v;
}

// ==================== CSR build (once per call) ==============================
__global__ __launch_bounds__(256) void csr_hist(
    const int* __restrict__ edge_index, int* __restrict__ deg)
{
    int e = blockIdx.x * 256 + threadIdx.x;
    if (e < EE) atomicAdd(&deg[edge_index[EE + e]], 1);
}

__global__ __launch_bounds__(1024) void csr_scan(
    const int* __restrict__ deg, int* __restrict__ rowptr, int* __restrict__ cursor)
{
    __shared__ int psum[1024];
    const int t = threadIdx.x;
    const int CH = (NN + 1023) / 1024;  // 49
    int base = t * CH;
    int s = 0;
    for (int i = 0; i < CH; ++i) {
        int idx = base + i;
        if (idx < NN) s += deg[idx];
    }
    psum[t] = s;
    __syncthreads();
    for (int off = 1; off < 1024; off <<= 1) {
        int v = (t >= off) ? psum[t - off] : 0;
        __syncthreads();
        psum[t] += v;
        __syncthreads();
    }
    int run = (t == 0) ? 0 : psum[t - 1];
    for (int i = 0; i < CH; ++i) {
        int idx = base + i;
        if (idx < NN) {
            rowptr[idx] = run;
            cursor[idx] = run;
            run += deg[idx];
        }
    }
    if (t == 0) rowptr[NN] = EE;
}

__global__ __launch_bounds__(256) void csr_fill(
    const int* __restrict__ edge_index, const int* __restrict__ edge_type,
    int* __restrict__ cursor, int* __restrict__ pack)
{
    int e = blockIdx.x * 256 + threadIdx.x;
    if (e >= EE) return;
    int s = edge_index[e];
    int d = edge_index[EE + e];
    int t = edge_type[e];
    int pos = atomicAdd(&cursor[d], 1);
    pack[pos] = s | (t << 16);  // src < 2^16, et < 64
}

// ==================== relation stage =========================================
__global__ __launch_bounds__(256) void rel_init(
    const int* __restrict__ bt, float* __restrict__ xrel)
{
    int i = blockIdx.x * 256 + threadIdx.x;
    if (i >= BB * RR * DD) return;
    int b = i / (RR * DD);
    int r = (i % (RR * DD)) / DD;
    int r0 = bt[(b * KK) * 3 + 2];
    xrel[i] = (r == r0) ? 1.0f : 0.0f;
}

__global__ __launch_bounds__(256) void rel_scatter(
    const int* __restrict__ rel_edge_index, const int* __restrict__ rel_edge_type,
    const float* __restrict__ xrel, const float* __restrict__ rel_emb_l,
    float* __restrict__ rel_agg)
{
    int gw = (int)((blockIdx.x * 256 + threadIdx.x) >> 6);  // 0..B*ER-1
    int lane = threadIdx.x & 63;
    if (gw >= BB * ERE) return;
    int b = gw / ERE, e = gw - b * ERE;
    int s = rel_edge_index[e];
    int dd = rel_edge_index[ERE + e];
    int et = rel_edge_type[e];
    float xv = xrel[(b * RR + s) * DD + lane];
    float rv = rel_emb_l[et * DD + lane];
    atomicAdd(&rel_agg[(b * RR + dd) * DD + lane], xv * rv);
}

__global__ __launch_bounds__(256) void rel_dense(
    const int* __restrict__ bt,
    const float* __restrict__ W, const float* __restrict__ bias,
    const float* __restrict__ g, const float* __restrict__ beta,
    float* __restrict__ xrel, const float* __restrict__ rel_agg)
{
    int row = (int)((blockIdx.x * 256 + threadIdx.x) >> 6);  // 0..B*R-1
    int lane = threadIdx.x & 63;
    if (row >= BB * RR) return;
    int b = row / RR, r = row - b * RR;
    int r0 = bt[(b * KK) * 3 + 2];
    float xv = xrel[row * DD + lane];
    float av = rel_agg[row * DD + lane] + ((r == r0) ? 1.0f : 0.0f);
    float acc = bias[lane];
#pragma unroll 8
    for (int k = 0; k < DD; ++k) {
        acc += __shfl(xv, k, 64) * W[k * DD + lane];
        acc += __shfl(av, k, 64) * W[(DD + k) * DD + lane];
    }
    float m = wsum64(acc) * (1.0f / DD);
    float c = acc - m;
    float v = wsum64(c * c) * (1.0f / DD);
    float o = c * rsqrtf(v + 1e-5f) * g[lane] + beta[lane];
    o = fmaxf(o, 0.0f) + xv;
    xrel[row * DD + lane] = o;
}

__global__ __launch_bounds__(256) void rel_finish(
    const int* __restrict__ bt, const float* __restrict__ xrel,
    float* __restrict__ query)
{
    int i = threadIdx.x;  // 0..255 = B*D
    int b = i / DD, d = i - b * DD;
    int r0 = bt[(b * KK) * 3 + 2];
    query[b * DD + d] = xrel[(b * RR + r0) * DD + d];
}

// ==================== entity stage ===========================================
__global__ __launch_bounds__(256) void rel_proj(
    const float* __restrict__ rel_repr,
    const float* __restrict__ W1, const float* __restrict__ b1,
    const float* __restrict__ W2, const float* __restrict__ b2,
    float* __restrict__ rel_buf)
{
    int row = (blockIdx.x * 256 + threadIdx.x) >> 6;  // 0..B*R-1
    int lane = threadIdx.x & 63;
    if (row >= BB * RR) return;
    const float* xr = &rel_repr[row * DD];
    float h = b1[lane];
#pragma unroll 8
    for (int k = 0; k < DD; ++k) h += xr[k] * W1[k * DD + lane];
    h = fmaxf(h, 0.0f);
    float o = b2[lane];
#pragma unroll 8
    for (int k = 0; k < DD; ++k) o += __shfl(h, k, 64) * W2[k * DD + lane];
    rel_buf[row * DD + lane] = o;
}

// ---------- layer-0 fast path ----------
// find edges whose src == h0[b]; add a marker entry for the h0 row itself
__global__ __launch_bounds__(256) void l0_scan(
    const int* __restrict__ edge_index, const int* __restrict__ edge_type,
    const int* __restrict__ bt, int* __restrict__ fixlist, int* __restrict__ cnt)
{
    int e = blockIdx.x * 256 + threadIdx.x;
    if (e < BB) {
        int h0 = bt[e * KK * 3];
        int pos = atomicAdd(&cnt[e], 1);
        if (pos < FCAP) fixlist[e * FCAP + pos] = h0 | (int)(0xFFFFu << 16);
    }
    if (e >= EE) return;
    int s = edge_index[e];
    int d = edge_index[EE + e];
    int t = edge_type[e];
#pragma unroll
    for (int b = 0; b < BB; ++b) {
        int h0 = bt[b * KK * 3];
        if (s == h0) {
            int pos = atomicAdd(&cnt[b], 1);
            if (pos < FCAP) fixlist[b * FCAP + pos] = d | (t << 16);
        }
    }
}

// write the "default" layer-0 output row to every node
__global__ __launch_bounds__(256) void l0_broadcast(
    const float* __restrict__ b0, const float* __restrict__ g0,
    const float* __restrict__ be0, float* __restrict__ x)
{
    int lane = threadIdx.x & 63;
    float bv = b0[lane];
    float m = wsum64(bv) * (1.0f / DD);
    float c = bv - m;
    float v = wsum64(c * c) * (1.0f / DD);
    float d = fmaxf(c * rsqrtf(v + 1e-5f) * g0[lane] + be0[lane], 0.0f);
    int gw = blockIdx.x * 4 + (threadIdx.x >> 6);
    int nw = gridDim.x * 4;
    for (int row = gw; row < BB * NN; row += nw)
        x[(size_t)row * DD + lane] = d;
}

// recompute affected rows exactly (idempotent across duplicate entries)
__global__ __launch_bounds__(256) void l0_fix(
    const int* __restrict__ bt, const int* __restrict__ fixlist,
    const int* __restrict__ cnt, const float* __restrict__ query,
    const float* __restrict__ rel_buf,
    const float* __restrict__ W0, const float* __restrict__ b0,
    const float* __restrict__ g0, const float* __restrict__ be0,
    float* __restrict__ x)
{
    int gidx = blockIdx.x * 4 + (threadIdx.x >> 6);  // 0..BB*FCAP-1
    int lane = threadIdx.x & 63;
    int b = gidx / FCAP, i = gidx - b * FCAP;
    int nc = min(cnt[b], FCAP);
    if (i >= nc) return;
    unsigned ent = (unsigned)fixlist[b * FCAP + i];
    int v = (int)(ent & 0xFFFFu);
    int h0 = bt[b * KK * 3];
    float q = query[b * DD + lane];
    float agg = (v == h0) ? q : 0.0f;
    for (int j = 0; j < nc; ++j) {
        unsigned ej = (unsigned)fixlist[b * FCAP + j];
        if ((int)(ej & 0xFFFFu) == v) {
            unsigned et = ej >> 16;
            if (et != 0xFFFFu)
                agg += q * rel_buf[(b * RR + (int)et) * DD + lane];
        }
    }
    float xr = (v == h0) ? q : 0.0f;
    float acc = b0[lane];
#pragma unroll 8
    for (int k = 0; k < DD; ++k) {
        acc += __shfl(xr, k, 64) * W0[k * DD + lane];
        acc += __shfl(agg, k, 64) * W0[(DD + k) * DD + lane];
    }
    float m = wsum64(acc) * (1.0f / DD);
    float c = acc - m;
    float vv = wsum64(c * c) * (1.0f / DD);
    float o = c * rsqrtf(vv + 1e-5f) * g0[lane] + be0[lane];
    x[((size_t)b * NN + v) * DD + lane] = fmaxf(o, 0.0f) + xr;
}

// ---------- layers 1..3 ----------
// gather: one wave per (b, v) — atomic-free aggregation + boundary fold-in
__global__ __launch_bounds__(256) void gather_agg(
    const int* __restrict__ rowptr, const int* __restrict__ pack,
    const int* __restrict__ bt,
    const float* __restrict__ x, const float* __restrict__ rel_buf,
    const float* __restrict__ query, float* __restrict__ agg)
{
    int gw = blockIdx.x * 4 + (int)(threadIdx.x >> 6);
    int lane = threadIdx.x & 63;
    if (gw >= BB * NN) return;
    int b = gw / NN, v = gw - b * NN;
    int beg = rowptr[v], end = rowptr[v + 1];
    const float* xb = x + (size_t)b * NN * DD;
    const float* rb = rel_buf + b * RR * DD;
    float acc = 0.0f;
    int j = beg;
    for (; j + 1 < end; j += 2) {
        int p0 = pack[j], p1 = pack[j + 1];
        float m0 = xb[(p0 & 0xFFFF) * DD + lane] * rb[(p0 >> 16) * DD + lane];
        float m1 = xb[(p1 & 0xFFFF) * DD + lane] * rb[(p1 >> 16) * DD + lane];
        acc += m0 + m1;
    }
    if (j < end) {
        int p0 = pack[j];
        acc += xb[(p0 & 0xFFFF) * DD + lane] * rb[(p0 >> 16) * DD + lane];
    }
    int h0 = bt[b * KK * 3];
    if (v == h0) acc += query[b * DD + lane];
    agg[(size_t)gw * DD + lane] = acc;
}

// dense: W in LDS (32KB), 8 rows per wave per pass, ds_read amortized 8x
#define D3_BLOCKS 1280
#define D3_R 8
__global__ __launch_bounds__(256) void ent_dense3(
    const float* __restrict__ W, const float* __restrict__ bias,
    const float* __restrict__ g, const float* __restrict__ beta,
    float* __restrict__ x, const float* __restrict__ agg)
{
    __shared__ float Wl[2 * DD * DD];  // 32 KB
    for (int i = threadIdx.x; i < 2 * DD * DD; i += 256) Wl[i] = W[i];
    __syncthreads();
    int lane = threadIdx.x & 63;
    int wid = threadIdx.x >> 6;
    float bi = bias[lane], gg = g[lane], be = beta[lane];
    const int stride = D3_BLOCKS * 4 * D3_R;
    for (int base = (blockIdx.x * 4 + wid) * D3_R; base < BB * NN; base += stride) {
        float acc[D3_R];
#pragma unroll
        for (int r = 0; r < D3_R; ++r) acc[r] = bi;
#pragma unroll
        for (int q = 0; q < 16; ++q) {
            float4 c[D3_R];
#pragma unroll
            for (int r = 0; r < D3_R; ++r)
                c[r] = *(const float4*)&x[(size_t)(base + r) * DD + q * 4];
#pragma unroll
            for (int i = 0; i < 4; ++i) {
                float w = Wl[(q * 4 + i) * DD + lane];
#pragma unroll
                for (int r = 0; r < D3_R; ++r)
                    acc[r] += ((const float*)&c[r])[i] * w;
            }
        }
#pragma unroll
        for (int q = 0; q < 16; ++q) {
            float4 c[D3_R];
#pragma unroll
            for (int r = 0; r < D3_R; ++r)
                c[r] = *(const float4*)&agg[(size_t)(base + r) * DD + q * 4];
#pragma unroll
            for (int i = 0; i < 4; ++i) {
                float w = Wl[(DD + q * 4 + i) * DD + lane];
#pragma unroll
                for (int r = 0; r < D3_R; ++r)
                    acc[r] += ((const float*)&c[r])[i] * w;
            }
        }
#pragma unroll
        for (int r = 0; r < D3_R; ++r) {
            float m = wsum64(acc[r]) * (1.0f / DD);
            float cc = acc[r] - m;
            float vv = wsum64(cc * cc) * (1.0f / DD);
            float xv = x[(size_t)(base + r) * DD + lane];
            float o = cc * rsqrtf(vv + 1e-5f) * gg + be;
            x[(size_t)(base + r) * DD + lane] = fmaxf(o, 0.0f) + xv;
        }
    }
}

// ==================== readout ================================================
__global__ __launch_bounds__(128) void readout(
    const int* __restrict__ bt, const float* __restrict__ x,
    const float* __restrict__ query,
    const float* __restrict__ W1, const float* __restrict__ b1,
    const float* __restrict__ W2, const float* __restrict__ b2,
    float* __restrict__ out)
{
    int b = blockIdx.x / KK, k = blockIdx.x - b * KK;
    int t = bt[(b * KK + k) * 3 + 1];
    __shared__ float feat[2 * DD];
    __shared__ float red[2 * DD];
    int j = threadIdx.x;
    if (j < DD) feat[j] = x[((size_t)b * NN + t) * DD + j];
    else        feat[j] = query[b * DD + (j - DD)];
    __syncthreads();
    float h = b1[j];
#pragma unroll 8
    for (int i = 0; i < 2 * DD; ++i) h += feat[i] * W1[i * 2 * DD + j];
    h = fmaxf(h, 0.0f);
    red[j] = h * W2[j];
    __syncthreads();
    for (int s = 64; s > 0; s >>= 1) {
        if (j < s) red[j] += red[j + s];
        __syncthreads();
    }
    if (j == 0) out[blockIdx.x] = red[0] + b2[0];
}

extern "C" void kernel_launch(void* const* d_in, const int* in_sizes, int n_in,
                              void* d_out, int out_size, void* d_ws, size_t ws_size,
                              hipStream_t stream) {
    const int*   edge_index     = (const int*)d_in[0];
    const int*   edge_type      = (const int*)d_in[1];
    const int*   rel_edge_index = (const int*)d_in[2];
    const int*   rel_edge_type  = (const int*)d_in[3];
    const int*   batch_triples  = (const int*)d_in[4];
    const float* rel_emb        = (const float*)d_in[5];
    const float* rel_W          = (const float*)d_in[6];
    const float* rel_b          = (const float*)d_in[7];
    const float* rel_g          = (const float*)d_in[8];
    const float* rel_beta       = (const float*)d_in[9];
    const float* proj_W1        = (const float*)d_in[10];
    const float* proj_b1        = (const float*)d_in[11];
    const float* proj_W2        = (const float*)d_in[12];
    const float* proj_b2        = (const float*)d_in[13];
    const float* ent_W          = (const float*)d_in[14];
    const float* ent_b          = (const float*)d_in[15];
    const float* ent_g          = (const float*)d_in[16];
    const float* ent_beta       = (const float*)d_in[17];
    const float* mlp_W1         = (const float*)d_in[18];
    const float* mlp_b1         = (const float*)d_in[19];
    const float* mlp_W2         = (const float*)d_in[20];
    const float* mlp_b2         = (const float*)d_in[21];

    float* ws = (float*)d_ws;
    float* x_ent    = ws;                                   // B*N*D
    float* agg_ent  = x_ent    + (size_t)BB * NN * DD;      // B*N*D
    float* rel_repr = agg_ent  + (size_t)BB * NN * DD;      // B*R*D
    float* rel_buf  = rel_repr + BB * RR * DD;              // B*R*D
    float* rel_agg  = rel_buf  + BB * RR * DD;              // B*R*D
    float* query    = rel_agg  + BB * RR * DD;              // B*D
    int*   deg      = (int*)(query + BB * DD);              // N
    int*   rowptr   = deg + NN;                             // N+1
    int*   cursor   = rowptr + NN + 1;                      // N
    int*   pack     = cursor + NN;                          // E
    int*   fixlist  = pack + EE;                            // BB*FCAP
    int*   fixcnt   = fixlist + BB * FCAP;                  // BB

    // ---- CSR build ----
    hipMemsetAsync(deg, 0, sizeof(int) * NN, stream);
    hipMemsetAsync(fixcnt, 0, sizeof(int) * BB, stream);
    csr_hist<<<(EE + 255) / 256, 256, 0, stream>>>(edge_index, deg);
    csr_scan<<<1, 1024, 0, stream>>>(deg, rowptr, cursor);
    csr_fill<<<(EE + 255) / 256, 256, 0, stream>>>(edge_index, edge_type, cursor, pack);

    // ---- relation stage ----
    rel_init<<<(BB * RR * DD + 255) / 256, 256, 0, stream>>>(batch_triples, rel_repr);
    for (int l = 0; l < LL; ++l) {
        hipMemsetAsync(rel_agg, 0, sizeof(float) * BB * RR * DD, stream);
        rel_scatter<<<(BB * ERE) / 4, 256, 0, stream>>>(
            rel_edge_index, rel_edge_type, rel_repr,
            rel_emb + l * RT * DD, rel_agg);
        rel_dense<<<(BB * RR) / 4, 256, 0, stream>>>(
            batch_triples, rel_W + l * 2 * DD * DD, rel_b + l * DD,
            rel_g + l * DD, rel_beta + l * DD, rel_repr, rel_agg);
    }
    rel_finish<<<1, 256, 0, stream>>>(batch_triples, rel_repr, query);

    // ---- entity stage: layer 0 fast path ----
    rel_proj<<<(BB * RR * 64) / 256, 256, 0, stream>>>(
        rel_repr, proj_W1, proj_b1, proj_W2, proj_b2, rel_buf);
    l0_scan<<<(EE + 255) / 256, 256, 0, stream>>>(
        edge_index, edge_type, batch_triples, fixlist, fixcnt);
    l0_broadcast<<<1024, 256, 0, stream>>>(ent_b, ent_g, ent_beta, x_ent);
    l0_fix<<<(BB * FCAP) / 4, 256, 0, stream>>>(
        batch_triples, fixlist, fixcnt, query, rel_buf,
        ent_W, ent_b, ent_g, ent_beta, x_ent);

    // ---- entity stage: layers 1..3 ----
    for (int l = 1; l < LL; ++l) {
        rel_proj<<<(BB * RR * 64) / 256, 256, 0, stream>>>(
            rel_repr, proj_W1 + l * DD * DD, proj_b1 + l * DD,
            proj_W2 + l * DD * DD, proj_b2 + l * DD, rel_buf);
        gather_agg<<<(BB * NN) / 4, 256, 0, stream>>>(
            rowptr, pack, batch_triples, x_ent, rel_buf, query, agg_ent);
        ent_dense3<<<D3_BLOCKS, 256, 0, stream>>>(
            ent_W + l * 2 * DD * DD, ent_b + l * DD, ent_g + l * DD,
            ent_beta + l * DD, x_ent, agg_ent);
    }

    readout<<<BB * KK, 2 * DD, 0, stream>>>(batch_triples, x_ent, query,
                                            mlp_W1, mlp_b1, mlp_W2, mlp_b2,
                                            (float*)d_out);
}

// Round 5
// 1732.568 us; speedup vs baseline: 1.1011x; 1.1011x over previous
//
#include <hip/hip_runtime.h>
#include <hip/hip_bf16.h>

#define BB 4
#define KK 16
#define NN 50000
#define EE 300000
#define RR 64
#define ERE 2048
#define RT 4
#define DD 64
#define LL 4
#define FCAP 256

__device__ __forceinline__ float wsum64(float v) {
#pragma unroll
    for (int off = 32; off > 0; off >>= 1) v += __shfl_xor(v, off, 64);
    return v;
}

// ==================== CSR build (once per call) ==============================
__global__ __launch_bounds__(256) void csr_hist(
    const int* __restrict__ edge_index, int* __restrict__ deg)
{
    int e = blockIdx.x * 256 + threadIdx.x;
    if (e < EE) atomicAdd(&deg[edge_index[EE + e]], 1);
}

__global__ __launch_bounds__(1024) void csr_scan(
    const int* __restrict__ deg, int* __restrict__ rowptr, int* __restrict__ cursor)
{
    __shared__ int psum[1024];
    const int t = threadIdx.x;
    const int CH = (NN + 1023) / 1024;  // 49
    int base = t * CH;
    int s = 0;
    for (int i = 0; i < CH; ++i) {
        int idx = base + i;
        if (idx < NN) s += deg[idx];
    }
    psum[t] = s;
    __syncthreads();
    for (int off = 1; off < 1024; off <<= 1) {
        int v = (t >= off) ? psum[t - off] : 0;
        __syncthreads();
        psum[t] += v;
        __syncthreads();
    }
    int run = (t == 0) ? 0 : psum[t - 1];
    for (int i = 0; i < CH; ++i) {
        int idx = base + i;
        if (idx < NN) {
            rowptr[idx] = run;
            cursor[idx] = run;
            run += deg[idx];
        }
    }
    if (t == 0) rowptr[NN] = EE;
}

__global__ __launch_bounds__(256) void csr_fill(
    const int* __restrict__ edge_index, const int* __restrict__ edge_type,
    int* __restrict__ cursor, int* __restrict__ pack)
{
    int e = blockIdx.x * 256 + threadIdx.x;
    if (e >= EE) return;
    int s = edge_index[e];
    int d = edge_index[EE + e];
    int t = edge_type[e];
    int pos = atomicAdd(&cursor[d], 1);
    pack[pos] = s | (t << 16);  // src < 2^16, et < 64
}

// ==================== relation stage =========================================
__global__ __launch_bounds__(256) void rel_init(
    const int* __restrict__ bt, float* __restrict__ xrel)
{
    int i = blockIdx.x * 256 + threadIdx.x;
    if (i >= BB * RR * DD) return;
    int b = i / (RR * DD);
    int r = (i % (RR * DD)) / DD;
    int r0 = bt[(b * KK) * 3 + 2];
    xrel[i] = (r == r0) ? 1.0f : 0.0f;
}

__global__ __launch_bounds__(256) void rel_scatter(
    const int* __restrict__ rel_edge_index, const int* __restrict__ rel_edge_type,
    const float* __restrict__ xrel, const float* __restrict__ rel_emb_l,
    float* __restrict__ rel_agg)
{
    int gw = (int)((blockIdx.x * 256 + threadIdx.x) >> 6);  // 0..B*ER-1
    int lane = threadIdx.x & 63;
    if (gw >= BB * ERE) return;
    int b = gw / ERE, e = gw - b * ERE;
    int s = rel_edge_index[e];
    int dd = rel_edge_index[ERE + e];
    int et = rel_edge_type[e];
    float xv = xrel[(b * RR + s) * DD + lane];
    float rv = rel_emb_l[et * DD + lane];
    atomicAdd(&rel_agg[(b * RR + dd) * DD + lane], xv * rv);
}

__global__ __launch_bounds__(256) void rel_dense(
    const int* __restrict__ bt,
    const float* __restrict__ W, const float* __restrict__ bias,
    const float* __restrict__ g, const float* __restrict__ beta,
    float* __restrict__ xrel, const float* __restrict__ rel_agg)
{
    int row = (int)((blockIdx.x * 256 + threadIdx.x) >> 6);  // 0..B*R-1
    int lane = threadIdx.x & 63;
    if (row >= BB * RR) return;
    int b = row / RR, r = row - b * RR;
    int r0 = bt[(b * KK) * 3 + 2];
    float xv = xrel[row * DD + lane];
    float av = rel_agg[row * DD + lane] + ((r == r0) ? 1.0f : 0.0f);
    float acc = bias[lane];
#pragma unroll 8
    for (int k = 0; k < DD; ++k) {
        acc += __shfl(xv, k, 64) * W[k * DD + lane];
        acc += __shfl(av, k, 64) * W[(DD + k) * DD + lane];
    }
    float m = wsum64(acc) * (1.0f / DD);
    float c = acc - m;
    float v = wsum64(c * c) * (1.0f / DD);
    float o = c * rsqrtf(v + 1e-5f) * g[lane] + beta[lane];
    o = fmaxf(o, 0.0f) + xv;
    xrel[row * DD + lane] = o;
}

__global__ __launch_bounds__(256) void rel_finish(
    const int* __restrict__ bt, const float* __restrict__ xrel,
    float* __restrict__ query)
{
    int i = threadIdx.x;  // 0..255 = B*D
    int b = i / DD, d = i - b * DD;
    int r0 = bt[(b * KK) * 3 + 2];
    query[b * DD + d] = xrel[(b * RR + r0) * DD + d];
}

// ==================== entity stage ===========================================
__global__ __launch_bounds__(256) void rel_proj(
    const float* __restrict__ rel_repr,
    const float* __restrict__ W1, const float* __restrict__ b1,
    const float* __restrict__ W2, const float* __restrict__ b2,
    float* __restrict__ rel_buf)
{
    int row = (blockIdx.x * 256 + threadIdx.x) >> 6;  // 0..B*R-1
    int lane = threadIdx.x & 63;
    if (row >= BB * RR) return;
    const float* xr = &rel_repr[row * DD];
    float h = b1[lane];
#pragma unroll 8
    for (int k = 0; k < DD; ++k) h += xr[k] * W1[k * DD + lane];
    h = fmaxf(h, 0.0f);
    float o = b2[lane];
#pragma unroll 8
    for (int k = 0; k < DD; ++k) o += __shfl(h, k, 64) * W2[k * DD + lane];
    rel_buf[row * DD + lane] = o;
}

// ---------- layer-0 fast path ----------
__global__ __launch_bounds__(256) void l0_scan(
    const int* __restrict__ edge_index, const int* __restrict__ edge_type,
    const int* __restrict__ bt, int* __restrict__ fixlist, int* __restrict__ cnt)
{
    int e = blockIdx.x * 256 + threadIdx.x;
    if (e < BB) {
        int h0 = bt[e * KK * 3];
        int pos = atomicAdd(&cnt[e], 1);
        if (pos < FCAP) fixlist[e * FCAP + pos] = h0 | (int)(0xFFFFu << 16);
    }
    if (e >= EE) return;
    int s = edge_index[e];
    int d = edge_index[EE + e];
    int t = edge_type[e];
#pragma unroll
    for (int b = 0; b < BB; ++b) {
        int h0 = bt[b * KK * 3];
        if (s == h0) {
            int pos = atomicAdd(&cnt[b], 1);
            if (pos < FCAP) fixlist[b * FCAP + pos] = d | (t << 16);
        }
    }
}

__global__ __launch_bounds__(256) void l0_broadcast(
    const float* __restrict__ b0, const float* __restrict__ g0,
    const float* __restrict__ be0, float* __restrict__ x)
{
    int lane = threadIdx.x & 63;
    float bv = b0[lane];
    float m = wsum64(bv) * (1.0f / DD);
    float c = bv - m;
    float v = wsum64(c * c) * (1.0f / DD);
    float d = fmaxf(c * rsqrtf(v + 1e-5f) * g0[lane] + be0[lane], 0.0f);
    int gw = blockIdx.x * 4 + (threadIdx.x >> 6);
    int nw = gridDim.x * 4;
    for (int row = gw; row < BB * NN; row += nw)
        x[(size_t)row * DD + lane] = d;
}

__global__ __launch_bounds__(256) void l0_fix(
    const int* __restrict__ bt, const int* __restrict__ fixlist,
    const int* __restrict__ cnt, const float* __restrict__ query,
    const float* __restrict__ rel_buf,
    const float* __restrict__ W0, const float* __restrict__ b0,
    const float* __restrict__ g0, const float* __restrict__ be0,
    float* __restrict__ x)
{
    int gidx = blockIdx.x * 4 + (threadIdx.x >> 6);  // 0..BB*FCAP-1
    int lane = threadIdx.x & 63;
    int b = gidx / FCAP, i = gidx - b * FCAP;
    int nc = min(cnt[b], FCAP);
    if (i >= nc) return;
    unsigned ent = (unsigned)fixlist[b * FCAP + i];
    int v = (int)(ent & 0xFFFFu);
    int h0 = bt[b * KK * 3];
    float q = query[b * DD + lane];
    float agg = (v == h0) ? q : 0.0f;
    for (int j = 0; j < nc; ++j) {
        unsigned ej = (unsigned)fixlist[b * FCAP + j];
        if ((int)(ej & 0xFFFFu) == v) {
            unsigned et = ej >> 16;
            if (et != 0xFFFFu)
                agg += q * rel_buf[(b * RR + (int)et) * DD + lane];
        }
    }
    float xr = (v == h0) ? q : 0.0f;
    float acc = b0[lane];
#pragma unroll 8
    for (int k = 0; k < DD; ++k) {
        acc += __shfl(xr, k, 64) * W0[k * DD + lane];
        acc += __shfl(agg, k, 64) * W0[(DD + k) * DD + lane];
    }
    float m = wsum64(acc) * (1.0f / DD);
    float c = acc - m;
    float vv = wsum64(c * c) * (1.0f / DD);
    float o = c * rsqrtf(vv + 1e-5f) * g0[lane] + be0[lane];
    x[((size_t)b * NN + v) * DD + lane] = fmaxf(o, 0.0f) + xr;
}

// ---------- layers 1..3 ----------
__global__ __launch_bounds__(256) void gather_agg(
    const int* __restrict__ rowptr, const int* __restrict__ pack,
    const int* __restrict__ bt,
    const float* __restrict__ x, const float* __restrict__ rel_buf,
    const float* __restrict__ query, float* __restrict__ agg)
{
    int gw = blockIdx.x * 4 + (int)(threadIdx.x >> 6);
    int lane = threadIdx.x & 63;
    if (gw >= BB * NN) return;
    int b = gw / NN, v = gw - b * NN;
    int beg = rowptr[v], end = rowptr[v + 1];
    const float* xb = x + (size_t)b * NN * DD;
    const float* rb = rel_buf + b * RR * DD;
    float acc = 0.0f;
    int j = beg;
    for (; j + 1 < end; j += 2) {
        int p0 = pack[j], p1 = pack[j + 1];
        float m0 = xb[(p0 & 0xFFFF) * DD + lane] * rb[(p0 >> 16) * DD + lane];
        float m1 = xb[(p1 & 0xFFFF) * DD + lane] * rb[(p1 >> 16) * DD + lane];
        acc += m0 + m1;
    }
    if (j < end) {
        int p0 = pack[j];
        acc += xb[(p0 & 0xFFFF) * DD + lane] * rb[(p0 >> 16) * DD + lane];
    }
    int h0 = bt[b * KK * 3];
    if (v == h0) acc += query[b * DD + lane];
    agg[(size_t)gw * DD + lane] = acc;
}

// dense: W in 32KB LDS amortized over 8 rows/wave; row data via wave-uniform
// loads consumed directly into FMAs (no register staging arrays).
#define D4_BLOCKS 1280
#define D4_R 8
__global__ __launch_bounds__(256) void ent_dense4(
    const float* __restrict__ W, const float* __restrict__ bias,
    const float* __restrict__ g, const float* __restrict__ beta,
    float* __restrict__ x, const float* __restrict__ agg)
{
    __shared__ float Wl[2 * DD * DD];  // 32 KB
    for (int i = threadIdx.x; i < 2 * DD * DD; i += 256) Wl[i] = W[i];
    __syncthreads();
    int lane = threadIdx.x & 63;
    int wid = threadIdx.x >> 6;
    float bi = bias[lane], gg = g[lane], be = beta[lane];
    const int stride = D4_BLOCKS * 4 * D4_R;
    for (int base0 = (blockIdx.x * 4 + wid) * D4_R; base0 < BB * NN; base0 += stride) {
        int base = __builtin_amdgcn_readfirstlane(base0);
        float acc[D4_R];
#pragma unroll
        for (int r = 0; r < D4_R; ++r) acc[r] = bi;
        // x half: k = 0..63
#pragma unroll
        for (int q = 0; q < 16; ++q) {
            float w0 = Wl[(q * 4 + 0) * DD + lane];
            float w1 = Wl[(q * 4 + 1) * DD + lane];
            float w2 = Wl[(q * 4 + 2) * DD + lane];
            float w3 = Wl[(q * 4 + 3) * DD + lane];
#pragma unroll
            for (int r = 0; r < D4_R; ++r) {
                const float* p = &x[(size_t)(base + r) * DD + q * 4];
                acc[r] += p[0] * w0 + p[1] * w1 + p[2] * w2 + p[3] * w3;
            }
        }
        // agg half: k = 64..127
#pragma unroll
        for (int q = 0; q < 16; ++q) {
            float w0 = Wl[(DD + q * 4 + 0) * DD + lane];
            float w1 = Wl[(DD + q * 4 + 1) * DD + lane];
            float w2 = Wl[(DD + q * 4 + 2) * DD + lane];
            float w3 = Wl[(DD + q * 4 + 3) * DD + lane];
#pragma unroll
            for (int r = 0; r < D4_R; ++r) {
                const float* p = &agg[(size_t)(base + r) * DD + q * 4];
                acc[r] += p[0] * w0 + p[1] * w1 + p[2] * w2 + p[3] * w3;
            }
        }
#pragma unroll
        for (int r = 0; r < D4_R; ++r) {
            float m = wsum64(acc[r]) * (1.0f / DD);
            float cc = acc[r] - m;
            float vv = wsum64(cc * cc) * (1.0f / DD);
            float xv = x[(size_t)(base + r) * DD + lane];
            float o = cc * rsqrtf(vv + 1e-5f) * gg + be;
            x[(size_t)(base + r) * DD + lane] = fmaxf(o, 0.0f) + xv;
        }
    }
}

// ==================== readout ================================================
__global__ __launch_bounds__(128) void readout(
    const int* __restrict__ bt, const float* __restrict__ x,
    const float* __restrict__ query,
    const float* __restrict__ W1, const float* __restrict__ b1,
    const float* __restrict__ W2, const float* __restrict__ b2,
    float* __restrict__ out)
{
    int b = blockIdx.x / KK, k = blockIdx.x - b * KK;
    int t = bt[(b * KK + k) * 3 + 1];
    __shared__ float feat[2 * DD];
    __shared__ float red[2 * DD];
    int j = threadIdx.x;
    if (j < DD) feat[j] = x[((size_t)b * NN + t) * DD + j];
    else        feat[j] = query[b * DD + (j - DD)];
    __syncthreads();
    float h = b1[j];
#pragma unroll 8
    for (int i = 0; i < 2 * DD; ++i) h += feat[i] * W1[i * 2 * DD + j];
    h = fmaxf(h, 0.0f);
    red[j] = h * W2[j];
    __syncthreads();
    for (int s = 64; s > 0; s >>= 1) {
        if (j < s) red[j] += red[j + s];
        __syncthreads();
    }
    if (j == 0) out[blockIdx.x] = red[0] + b2[0];
}

extern "C" void kernel_launch(void* const* d_in, const int* in_sizes, int n_in,
                              void* d_out, int out_size, void* d_ws, size_t ws_size,
                              hipStream_t stream) {
    const int*   edge_index     = (const int*)d_in[0];
    const int*   edge_type      = (const int*)d_in[1];
    const int*   rel_edge_index = (const int*)d_in[2];
    const int*   rel_edge_type  = (const int*)d_in[3];
    const int*   batch_triples  = (const int*)d_in[4];
    const float* rel_emb        = (const float*)d_in[5];
    const float* rel_W          = (const float*)d_in[6];
    const float* rel_b          = (const float*)d_in[7];
    const float* rel_g          = (const float*)d_in[8];
    const float* rel_beta       = (const float*)d_in[9];
    const float* proj_W1        = (const float*)d_in[10];
    const float* proj_b1        = (const float*)d_in[11];
    const float* proj_W2        = (const float*)d_in[12];
    const float* proj_b2        = (const float*)d_in[13];
    const float* ent_W          = (const float*)d_in[14];
    const float* ent_b          = (const float*)d_in[15];
    const float* ent_g          = (const float*)d_in[16];
    const float* ent_beta       = (const float*)d_in[17];
    const float* mlp_W1         = (const float*)d_in[18];
    const float* mlp_b1         = (const float*)d_in[19];
    const float* mlp_W2         = (const float*)d_in[20];
    const float* mlp_b2         = (const float*)d_in[21];

    float* ws = (float*)d_ws;
    float* x_ent    = ws;                                   // B*N*D
    float* agg_ent  = x_ent    + (size_t)BB * NN * DD;      // B*N*D
    float* rel_repr = agg_ent  + (size_t)BB * NN * DD;      // B*R*D
    float* rel_buf  = rel_repr + BB * RR * DD;              // B*R*D
    float* rel_agg  = rel_buf  + BB * RR * DD;              // B*R*D
    float* query    = rel_agg  + BB * RR * DD;              // B*D
    int*   deg      = (int*)(query + BB * DD);              // N
    int*   rowptr   = deg + NN;                             // N+1
    int*   cursor   = rowptr + NN + 1;                      // N
    int*   pack     = cursor + NN;                          // E
    int*   fixlist  = pack + EE;                            // BB*FCAP
    int*   fixcnt   = fixlist + BB * FCAP;                  // BB

    // ---- CSR build ----
    hipMemsetAsync(deg, 0, sizeof(int) * NN, stream);
    hipMemsetAsync(fixcnt, 0, sizeof(int) * BB, stream);
    csr_hist<<<(EE + 255) / 256, 256, 0, stream>>>(edge_index, deg);
    csr_scan<<<1, 1024, 0, stream>>>(deg, rowptr, cursor);
    csr_fill<<<(EE + 255) / 256, 256, 0, stream>>>(edge_index, edge_type, cursor, pack);

    // ---- relation stage ----
    rel_init<<<(BB * RR * DD + 255) / 256, 256, 0, stream>>>(batch_triples, rel_repr);
    for (int l = 0; l < LL; ++l) {
        hipMemsetAsync(rel_agg, 0, sizeof(float) * BB * RR * DD, stream);
        rel_scatter<<<(BB * ERE) / 4, 256, 0, stream>>>(
            rel_edge_index, rel_edge_type, rel_repr,
            rel_emb + l * RT * DD, rel_agg);
        rel_dense<<<(BB * RR) / 4, 256, 0, stream>>>(
            batch_triples, rel_W + l * 2 * DD * DD, rel_b + l * DD,
            rel_g + l * DD, rel_beta + l * DD, rel_repr, rel_agg);
    }
    rel_finish<<<1, 256, 0, stream>>>(batch_triples, rel_repr, query);

    // ---- entity stage: layer 0 fast path ----
    rel_proj<<<(BB * RR * 64) / 256, 256, 0, stream>>>(
        rel_repr, proj_W1, proj_b1, proj_W2, proj_b2, rel_buf);
    l0_scan<<<(EE + 255) / 256, 256, 0, stream>>>(
        edge_index, edge_type, batch_triples, fixlist, fixcnt);
    l0_broadcast<<<1024, 256, 0, stream>>>(ent_b, ent_g, ent_beta, x_ent);
    l0_fix<<<(BB * FCAP) / 4, 256, 0, stream>>>(
        batch_triples, fixlist, fixcnt, query, rel_buf,
        ent_W, ent_b, ent_g, ent_beta, x_ent);

    // ---- entity stage: layers 1..3 ----
    for (int l = 1; l < LL; ++l) {
        rel_proj<<<(BB * RR * 64) / 256, 256, 0, stream>>>(
            rel_repr, proj_W1 + l * DD * DD, proj_b1 + l * DD,
            proj_W2 + l * DD * DD, proj_b2 + l * DD, rel_buf);
        gather_agg<<<(BB * NN) / 4, 256, 0, stream>>>(
            rowptr, pack, batch_triples, x_ent, rel_buf, query, agg_ent);
        ent_dense4<<<D4_BLOCKS, 256, 0, stream>>>(
            ent_W + l * 2 * DD * DD, ent_b + l * DD, ent_g + l * DD,
            ent_beta + l * DD, x_ent, agg_ent);
    }

    readout<<<BB * KK, 2 * DD, 0, stream>>>(batch_triples, x_ent, query,
                                            mlp_W1, mlp_b1, mlp_W2, mlp_b2,
                                            (float*)d_out);
}

// Round 6
// 993.563 us; speedup vs baseline: 1.9201x; 1.7438x over previous
//
#include <hip/hip_runtime.h>
#include <hip/hip_bf16.h>

#define BB 4
#define KK 16
#define NN 50000
#define EE 300000
#define RR 64
#define ERE 2048
#define RT 4
#define DD 64
#define LL 4
#define FCAP 256

__device__ __forceinline__ float wsum64(float v) {
#pragma unroll
    for (int off = 32; off > 0; off >>= 1) v += __shfl_xor(v, off, 64);
    return v;
}

// ==================== CSR build (once per call) ==============================
__global__ __launch_bounds__(256) void csr_hist(
    const int* __restrict__ edge_index, int* __restrict__ deg)
{
    int e = blockIdx.x * 256 + threadIdx.x;
    if (e < EE) atomicAdd(&deg[edge_index[EE + e]], 1);
}

__global__ __launch_bounds__(1024) void csr_scan(
    const int* __restrict__ deg, int* __restrict__ rowptr, int* __restrict__ cursor)
{
    __shared__ int psum[1024];
    const int t = threadIdx.x;
    const int CH = (NN + 1023) / 1024;  // 49
    int base = t * CH;
    int s = 0;
    for (int i = 0; i < CH; ++i) {
        int idx = base + i;
        if (idx < NN) s += deg[idx];
    }
    psum[t] = s;
    __syncthreads();
    for (int off = 1; off < 1024; off <<= 1) {
        int v = (t >= off) ? psum[t - off] : 0;
        __syncthreads();
        psum[t] += v;
        __syncthreads();
    }
    int run = (t == 0) ? 0 : psum[t - 1];
    for (int i = 0; i < CH; ++i) {
        int idx = base + i;
        if (idx < NN) {
            rowptr[idx] = run;
            cursor[idx] = run;
            run += deg[idx];
        }
    }
    if (t == 0) rowptr[NN] = EE;
}

__global__ __launch_bounds__(256) void csr_fill(
    const int* __restrict__ edge_index, const int* __restrict__ edge_type,
    int* __restrict__ cursor, int* __restrict__ pack)
{
    int e = blockIdx.x * 256 + threadIdx.x;
    if (e >= EE) return;
    int s = edge_index[e];
    int d = edge_index[EE + e];
    int t = edge_type[e];
    int pos = atomicAdd(&cursor[d], 1);
    pack[pos] = s | (t << 16);  // src < 2^16, et < 64
}

// ==================== relation stage =========================================
__global__ __launch_bounds__(256) void rel_init(
    const int* __restrict__ bt, float* __restrict__ xrel)
{
    int i = blockIdx.x * 256 + threadIdx.x;
    if (i >= BB * RR * DD) return;
    int b = i / (RR * DD);
    int r = (i % (RR * DD)) / DD;
    int r0 = bt[(b * KK) * 3 + 2];
    xrel[i] = (r == r0) ? 1.0f : 0.0f;
}

__global__ __launch_bounds__(256) void rel_scatter(
    const int* __restrict__ rel_edge_index, const int* __restrict__ rel_edge_type,
    const float* __restrict__ xrel, const float* __restrict__ rel_emb_l,
    float* __restrict__ rel_agg)
{
    int gw = (int)((blockIdx.x * 256 + threadIdx.x) >> 6);  // 0..B*ER-1
    int lane = threadIdx.x & 63;
    if (gw >= BB * ERE) return;
    int b = gw / ERE, e = gw - b * ERE;
    int s = rel_edge_index[e];
    int dd = rel_edge_index[ERE + e];
    int et = rel_edge_type[e];
    float xv = xrel[(b * RR + s) * DD + lane];
    float rv = rel_emb_l[et * DD + lane];
    atomicAdd(&rel_agg[(b * RR + dd) * DD + lane], xv * rv);
}

__global__ __launch_bounds__(256) void rel_dense(
    const int* __restrict__ bt,
    const float* __restrict__ W, const float* __restrict__ bias,
    const float* __restrict__ g, const float* __restrict__ beta,
    float* __restrict__ xrel, const float* __restrict__ rel_agg)
{
    int row = (int)((blockIdx.x * 256 + threadIdx.x) >> 6);  // 0..B*R-1
    int lane = threadIdx.x & 63;
    if (row >= BB * RR) return;
    int b = row / RR, r = row - b * RR;
    int r0 = bt[(b * KK) * 3 + 2];
    float xv = xrel[row * DD + lane];
    float av = rel_agg[row * DD + lane] + ((r == r0) ? 1.0f : 0.0f);
    float acc = bias[lane];
#pragma unroll 8
    for (int k = 0; k < DD; ++k) {
        acc += __shfl(xv, k, 64) * W[k * DD + lane];
        acc += __shfl(av, k, 64) * W[(DD + k) * DD + lane];
    }
    float m = wsum64(acc) * (1.0f / DD);
    float c = acc - m;
    float v = wsum64(c * c) * (1.0f / DD);
    float o = c * rsqrtf(v + 1e-5f) * g[lane] + beta[lane];
    o = fmaxf(o, 0.0f) + xv;
    xrel[row * DD + lane] = o;
}

__global__ __launch_bounds__(256) void rel_finish(
    const int* __restrict__ bt, const float* __restrict__ xrel,
    float* __restrict__ query)
{
    int i = threadIdx.x;  // 0..255 = B*D
    int b = i / DD, d = i - b * DD;
    int r0 = bt[(b * KK) * 3 + 2];
    query[b * DD + d] = xrel[(b * RR + r0) * DD + d];
}

// ==================== entity stage ===========================================
__global__ __launch_bounds__(256) void rel_proj(
    const float* __restrict__ rel_repr,
    const float* __restrict__ W1, const float* __restrict__ b1,
    const float* __restrict__ W2, const float* __restrict__ b2,
    float* __restrict__ rel_buf)
{
    int row = (blockIdx.x * 256 + threadIdx.x) >> 6;  // 0..B*R-1
    int lane = threadIdx.x & 63;
    if (row >= BB * RR) return;
    const float* xr = &rel_repr[row * DD];
    float h = b1[lane];
#pragma unroll 8
    for (int k = 0; k < DD; ++k) h += xr[k] * W1[k * DD + lane];
    h = fmaxf(h, 0.0f);
    float o = b2[lane];
#pragma unroll 8
    for (int k = 0; k < DD; ++k) o += __shfl(h, k, 64) * W2[k * DD + lane];
    rel_buf[row * DD + lane] = o;
}

// ---------- layer-0 fast path ----------
__global__ __launch_bounds__(256) void l0_scan(
    const int* __restrict__ edge_index, const int* __restrict__ edge_type,
    const int* __restrict__ bt, int* __restrict__ fixlist, int* __restrict__ cnt)
{
    int e = blockIdx.x * 256 + threadIdx.x;
    if (e < BB) {
        int h0 = bt[e * KK * 3];
        int pos = atomicAdd(&cnt[e], 1);
        if (pos < FCAP) fixlist[e * FCAP + pos] = h0 | (int)(0xFFFFu << 16);
    }
    if (e >= EE) return;
    int s = edge_index[e];
    int d = edge_index[EE + e];
    int t = edge_type[e];
#pragma unroll
    for (int b = 0; b < BB; ++b) {
        int h0 = bt[b * KK * 3];
        if (s == h0) {
            int pos = atomicAdd(&cnt[b], 1);
            if (pos < FCAP) fixlist[b * FCAP + pos] = d | (t << 16);
        }
    }
}

__global__ __launch_bounds__(256) void l0_broadcast(
    const float* __restrict__ b0, const float* __restrict__ g0,
    const float* __restrict__ be0, float* __restrict__ x)
{
    int lane = threadIdx.x & 63;
    float bv = b0[lane];
    float m = wsum64(bv) * (1.0f / DD);
    float c = bv - m;
    float v = wsum64(c * c) * (1.0f / DD);
    float d = fmaxf(c * rsqrtf(v + 1e-5f) * g0[lane] + be0[lane], 0.0f);
    int gw = blockIdx.x * 4 + (threadIdx.x >> 6);
    int nw = gridDim.x * 4;
    for (int row = gw; row < BB * NN; row += nw)
        x[(size_t)row * DD + lane] = d;
}

__global__ __launch_bounds__(256) void l0_fix(
    const int* __restrict__ bt, const int* __restrict__ fixlist,
    const int* __restrict__ cnt, const float* __restrict__ query,
    const float* __restrict__ rel_buf,
    const float* __restrict__ W0, const float* __restrict__ b0,
    const float* __restrict__ g0, const float* __restrict__ be0,
    float* __restrict__ x)
{
    int gidx = blockIdx.x * 4 + (threadIdx.x >> 6);  // 0..BB*FCAP-1
    int lane = threadIdx.x & 63;
    int b = gidx / FCAP, i = gidx - b * FCAP;
    int nc = min(cnt[b], FCAP);
    if (i >= nc) return;
    unsigned ent = (unsigned)fixlist[b * FCAP + i];
    int v = (int)(ent & 0xFFFFu);
    int h0 = bt[b * KK * 3];
    float q = query[b * DD + lane];
    float agg = (v == h0) ? q : 0.0f;
    for (int j = 0; j < nc; ++j) {
        unsigned ej = (unsigned)fixlist[b * FCAP + j];
        if ((int)(ej & 0xFFFFu) == v) {
            unsigned et = ej >> 16;
            if (et != 0xFFFFu)
                agg += q * rel_buf[(b * RR + (int)et) * DD + lane];
        }
    }
    float xr = (v == h0) ? q : 0.0f;
    float acc = b0[lane];
#pragma unroll 8
    for (int k = 0; k < DD; ++k) {
        acc += __shfl(xr, k, 64) * W0[k * DD + lane];
        acc += __shfl(agg, k, 64) * W0[(DD + k) * DD + lane];
    }
    float m = wsum64(acc) * (1.0f / DD);
    float c = acc - m;
    float vv = wsum64(c * c) * (1.0f / DD);
    float o = c * rsqrtf(vv + 1e-5f) * g0[lane] + be0[lane];
    x[((size_t)b * NN + v) * DD + lane] = fmaxf(o, 0.0f) + xr;
}

// ---------- layers 1..3 ----------
__global__ __launch_bounds__(256) void gather_agg(
    const int* __restrict__ rowptr, const int* __restrict__ pack,
    const int* __restrict__ bt,
    const float* __restrict__ x, const float* __restrict__ rel_buf,
    const float* __restrict__ query, float* __restrict__ agg)
{
    int gw = blockIdx.x * 4 + (int)(threadIdx.x >> 6);
    int lane = threadIdx.x & 63;
    if (gw >= BB * NN) return;
    int b = gw / NN, v = gw - b * NN;
    int beg = rowptr[v], end = rowptr[v + 1];
    const float* xb = x + (size_t)b * NN * DD;
    const float* rb = rel_buf + b * RR * DD;
    float acc = 0.0f;
    int j = beg;
    for (; j + 1 < end; j += 2) {
        int p0 = pack[j], p1 = pack[j + 1];
        float m0 = xb[(p0 & 0xFFFF) * DD + lane] * rb[(p0 >> 16) * DD + lane];
        float m1 = xb[(p1 & 0xFFFF) * DD + lane] * rb[(p1 >> 16) * DD + lane];
        acc += m0 + m1;
    }
    if (j < end) {
        int p0 = pack[j];
        acc += xb[(p0 & 0xFFFF) * DD + lane] * rb[(p0 >> 16) * DD + lane];
    }
    int h0 = bt[b * KK * 3];
    if (v == h0) acc += query[b * DD + lane];
    agg[(size_t)gw * DD + lane] = acc;
}

// dense: W in 32KB LDS; 4 rows/wave; k-chunk loop NOT unrolled so the
// compiler cannot register-pipeline row data (the R4/R5 failure mode).
// Row loads are wave-uniform (scalar path); VGPR capped via launch_bounds.
#define D5_BLOCKS 1280
#define D5_R 4
__global__ __launch_bounds__(256, 4) void ent_dense5(
    const float* __restrict__ W, const float* __restrict__ bias,
    const float* __restrict__ g, const float* __restrict__ beta,
    float* __restrict__ x, const float* __restrict__ agg)
{
    __shared__ float Wl[2 * DD * DD];  // 32 KB
    for (int i = threadIdx.x; i < 2 * DD * DD; i += 256)
        Wl[i] = W[i];
    __syncthreads();
    int lane = threadIdx.x & 63;
    int wid = threadIdx.x >> 6;
    float bi = bias[lane], gg = g[lane], be = beta[lane];
    const int stride = D5_BLOCKS * 4 * D5_R;
    for (int base0 = (blockIdx.x * 4 + wid) * D5_R; base0 < BB * NN; base0 += stride) {
        int base = __builtin_amdgcn_readfirstlane(base0);
        const float* xrow = x + (size_t)base * DD;    // wave-uniform
        const float* arow = agg + (size_t)base * DD;  // wave-uniform
        float acc[D5_R];
#pragma unroll
        for (int r = 0; r < D5_R; ++r) acc[r] = bi;
#pragma unroll 1
        for (int q = 0; q < 16; ++q) {
            float w0 = Wl[(q * 4 + 0) * DD + lane];
            float w1 = Wl[(q * 4 + 1) * DD + lane];
            float w2 = Wl[(q * 4 + 2) * DD + lane];
            float w3 = Wl[(q * 4 + 3) * DD + lane];
#pragma unroll
            for (int r = 0; r < D5_R; ++r) {
                const float* p = xrow + r * DD + q * 4;
                acc[r] += p[0] * w0 + p[1] * w1 + p[2] * w2 + p[3] * w3;
            }
        }
#pragma unroll 1
        for (int q = 0; q < 16; ++q) {
            float w0 = Wl[(DD + q * 4 + 0) * DD + lane];
            float w1 = Wl[(DD + q * 4 + 1) * DD + lane];
            float w2 = Wl[(DD + q * 4 + 2) * DD + lane];
            float w3 = Wl[(DD + q * 4 + 3) * DD + lane];
#pragma unroll
            for (int r = 0; r < D5_R; ++r) {
                const float* p = arow + r * DD + q * 4;
                acc[r] += p[0] * w0 + p[1] * w1 + p[2] * w2 + p[3] * w3;
            }
        }
#pragma unroll
        for (int r = 0; r < D5_R; ++r) {
            float m = wsum64(acc[r]) * (1.0f / DD);
            float cc = acc[r] - m;
            float vv = wsum64(cc * cc) * (1.0f / DD);
            float xv = x[(size_t)(base + r) * DD + lane];
            float o = cc * rsqrtf(vv + 1e-5f) * gg + be;
            x[(size_t)(base + r) * DD + lane] = fmaxf(o, 0.0f) + xv;
        }
    }
}

// ==================== readout ================================================
__global__ __launch_bounds__(128) void readout(
    const int* __restrict__ bt, const float* __restrict__ x,
    const float* __restrict__ query,
    const float* __restrict__ W1, const float* __restrict__ b1,
    const float* __restrict__ W2, const float* __restrict__ b2,
    float* __restrict__ out)
{
    int b = blockIdx.x / KK, k = blockIdx.x - b * KK;
    int t = bt[(b * KK + k) * 3 + 1];
    __shared__ float feat[2 * DD];
    __shared__ float red[2 * DD];
    int j = threadIdx.x;
    if (j < DD) feat[j] = x[((size_t)b * NN + t) * DD + j];
    else        feat[j] = query[b * DD + (j - DD)];
    __syncthreads();
    float h = b1[j];
#pragma unroll 8
    for (int i = 0; i < 2 * DD; ++i) h += feat[i] * W1[i * 2 * DD + j];
    h = fmaxf(h, 0.0f);
    red[j] = h * W2[j];
    __syncthreads();
    for (int s = 64; s > 0; s >>= 1) {
        if (j < s) red[j] += red[j + s];
        __syncthreads();
    }
    if (j == 0) out[blockIdx.x] = red[0] + b2[0];
}

extern "C" void kernel_launch(void* const* d_in, const int* in_sizes, int n_in,
                              void* d_out, int out_size, void* d_ws, size_t ws_size,
                              hipStream_t stream) {
    const int*   edge_index     = (const int*)d_in[0];
    const int*   edge_type      = (const int*)d_in[1];
    const int*   rel_edge_index = (const int*)d_in[2];
    const int*   rel_edge_type  = (const int*)d_in[3];
    const int*   batch_triples  = (const int*)d_in[4];
    const float* rel_emb        = (const float*)d_in[5];
    const float* rel_W          = (const float*)d_in[6];
    const float* rel_b          = (const float*)d_in[7];
    const float* rel_g          = (const float*)d_in[8];
    const float* rel_beta       = (const float*)d_in[9];
    const float* proj_W1        = (const float*)d_in[10];
    const float* proj_b1        = (const float*)d_in[11];
    const float* proj_W2        = (const float*)d_in[12];
    const float* proj_b2        = (const float*)d_in[13];
    const float* ent_W          = (const float*)d_in[14];
    const float* ent_b          = (const float*)d_in[15];
    const float* ent_g          = (const float*)d_in[16];
    const float* ent_beta       = (const float*)d_in[17];
    const float* mlp_W1         = (const float*)d_in[18];
    const float* mlp_b1         = (const float*)d_in[19];
    const float* mlp_W2         = (const float*)d_in[20];
    const float* mlp_b2         = (const float*)d_in[21];

    float* ws = (float*)d_ws;
    float* x_ent    = ws;                                   // B*N*D
    float* agg_ent  = x_ent    + (size_t)BB * NN * DD;      // B*N*D
    float* rel_repr = agg_ent  + (size_t)BB * NN * DD;      // B*R*D
    float* rel_buf  = rel_repr + BB * RR * DD;              // B*R*D
    float* rel_agg  = rel_buf  + BB * RR * DD;              // B*R*D
    float* query    = rel_agg  + BB * RR * DD;              // B*D
    int*   deg      = (int*)(query + BB * DD);              // N
    int*   rowptr   = deg + NN;                             // N+1
    int*   cursor   = rowptr + NN + 1;                      // N
    int*   pack     = cursor + NN;                          // E
    int*   fixlist  = pack + EE;                            // BB*FCAP
    int*   fixcnt   = fixlist + BB * FCAP;                  // BB

    // ---- CSR build ----
    hipMemsetAsync(deg, 0, sizeof(int) * NN, stream);
    hipMemsetAsync(fixcnt, 0, sizeof(int) * BB, stream);
    csr_hist<<<(EE + 255) / 256, 256, 0, stream>>>(edge_index, deg);
    csr_scan<<<1, 1024, 0, stream>>>(deg, rowptr, cursor);
    csr_fill<<<(EE + 255) / 256, 256, 0, stream>>>(edge_index, edge_type, cursor, pack);

    // ---- relation stage ----
    rel_init<<<(BB * RR * DD + 255) / 256, 256, 0, stream>>>(batch_triples, rel_repr);
    for (int l = 0; l < LL; ++l) {
        hipMemsetAsync(rel_agg, 0, sizeof(float) * BB * RR * DD, stream);
        rel_scatter<<<(BB * ERE) / 4, 256, 0, stream>>>(
            rel_edge_index, rel_edge_type, rel_repr,
            rel_emb + l * RT * DD, rel_agg);
        rel_dense<<<(BB * RR) / 4, 256, 0, stream>>>(
            batch_triples, rel_W + l * 2 * DD * DD, rel_b + l * DD,
            rel_g + l * DD, rel_beta + l * DD, rel_repr, rel_agg);
    }
    rel_finish<<<1, 256, 0, stream>>>(batch_triples, rel_repr, query);

    // ---- entity stage: layer 0 fast path ----
    rel_proj<<<(BB * RR * 64) / 256, 256, 0, stream>>>(
        rel_repr, proj_W1, proj_b1, proj_W2, proj_b2, rel_buf);
    l0_scan<<<(EE + 255) / 256, 256, 0, stream>>>(
        edge_index, edge_type, batch_triples, fixlist, fixcnt);
    l0_broadcast<<<1024, 256, 0, stream>>>(ent_b, ent_g, ent_beta, x_ent);
    l0_fix<<<(BB * FCAP) / 4, 256, 0, stream>>>(
        batch_triples, fixlist, fixcnt, query, rel_buf,
        ent_W, ent_b, ent_g, ent_beta, x_ent);

    // ---- entity stage: layers 1..3 ----
    for (int l = 1; l < LL; ++l) {
        rel_proj<<<(BB * RR * 64) / 256, 256, 0, stream>>>(
            rel_repr, proj_W1 + l * DD * DD, proj_b1 + l * DD,
            proj_W2 + l * DD * DD, proj_b2 + l * DD, rel_buf);
        gather_agg<<<(BB * NN) / 4, 256, 0, stream>>>(
            rowptr, pack, batch_triples, x_ent, rel_buf, query, agg_ent);
        ent_dense5<<<D5_BLOCKS, 256, 0, stream>>>(
            ent_W + l * 2 * DD * DD, ent_b + l * DD, ent_g + l * DD,
            ent_beta + l * DD, x_ent, agg_ent);
    }

    readout<<<BB * KK, 2 * DD, 0, stream>>>(batch_triples, x_ent, query,
                                            mlp_W1, mlp_b1, mlp_W2, mlp_b2,
                                            (float*)d_out);
}

// Round 7
// 630.922 us; speedup vs baseline: 3.0237x; 1.5748x over previous
//
#include <hip/hip_runtime.h>
#include <hip/hip_bf16.h>

#define BB 4
#define KK 16
#define NN 50000
#define EE 300000
#define RR 64
#define ERE 2048
#define RT 4
#define DD 64
#define LL 4
#define FCAP 256

typedef short s16x8 __attribute__((ext_vector_type(8)));
typedef float f32x4 __attribute__((ext_vector_type(4)));

__device__ __forceinline__ float wsum64(float v) {
#pragma unroll
    for (int off = 32; off > 0; off >>= 1) v += __shfl_xor(v, off, 64);
    return v;
}

__device__ __forceinline__ unsigned short f2bf_rne(float f) {
    unsigned u = __builtin_bit_cast(unsigned, f);
    return (unsigned short)((u + 0x7FFFu + ((u >> 16) & 1u)) >> 16);
}

// ==================== CSR build (once per call) ==============================
__global__ __launch_bounds__(256) void csr_hist(
    const int* __restrict__ edge_index, int* __restrict__ deg)
{
    int e = blockIdx.x * 256 + threadIdx.x;
    if (e < EE) atomicAdd(&deg[edge_index[EE + e]], 1);
}

__global__ __launch_bounds__(1024) void csr_scan(
    const int* __restrict__ deg, int* __restrict__ rowptr, int* __restrict__ cursor)
{
    __shared__ int psum[1024];
    const int t = threadIdx.x;
    const int CH = (NN + 1023) / 1024;  // 49
    int base = t * CH;
    int s = 0;
    for (int i = 0; i < CH; ++i) {
        int idx = base + i;
        if (idx < NN) s += deg[idx];
    }
    psum[t] = s;
    __syncthreads();
    for (int off = 1; off < 1024; off <<= 1) {
        int v = (t >= off) ? psum[t - off] : 0;
        __syncthreads();
        psum[t] += v;
        __syncthreads();
    }
    int run = (t == 0) ? 0 : psum[t - 1];
    for (int i = 0; i < CH; ++i) {
        int idx = base + i;
        if (idx < NN) {
            rowptr[idx] = run;
            cursor[idx] = run;
            run += deg[idx];
        }
    }
    if (t == 0) rowptr[NN] = EE;
}

__global__ __launch_bounds__(256) void csr_fill(
    const int* __restrict__ edge_index, const int* __restrict__ edge_type,
    int* __restrict__ cursor, int* __restrict__ pack)
{
    int e = blockIdx.x * 256 + threadIdx.x;
    if (e >= EE) return;
    int s = edge_index[e];
    int d = edge_index[EE + e];
    int t = edge_type[e];
    int pos = atomicAdd(&cursor[d], 1);
    pack[pos] = s | (t << 16);  // src < 2^16, et < 64
}

// ==================== relation stage =========================================
__global__ __launch_bounds__(256) void rel_init(
    const int* __restrict__ bt, float* __restrict__ xrel)
{
    int i = blockIdx.x * 256 + threadIdx.x;
    if (i >= BB * RR * DD) return;
    int b = i / (RR * DD);
    int r = (i % (RR * DD)) / DD;
    int r0 = bt[(b * KK) * 3 + 2];
    xrel[i] = (r == r0) ? 1.0f : 0.0f;
}

__global__ __launch_bounds__(256) void rel_scatter(
    const int* __restrict__ rel_edge_index, const int* __restrict__ rel_edge_type,
    const float* __restrict__ xrel, const float* __restrict__ rel_emb_l,
    float* __restrict__ rel_agg)
{
    int gw = (int)((blockIdx.x * 256 + threadIdx.x) >> 6);  // 0..B*ER-1
    int lane = threadIdx.x & 63;
    if (gw >= BB * ERE) return;
    int b = gw / ERE, e = gw - b * ERE;
    int s = rel_edge_index[e];
    int dd = rel_edge_index[ERE + e];
    int et = rel_edge_type[e];
    float xv = xrel[(b * RR + s) * DD + lane];
    float rv = rel_emb_l[et * DD + lane];
    atomicAdd(&rel_agg[(b * RR + dd) * DD + lane], xv * rv);
}

__global__ __launch_bounds__(256) void rel_dense(
    const int* __restrict__ bt,
    const float* __restrict__ W, const float* __restrict__ bias,
    const float* __restrict__ g, const float* __restrict__ beta,
    float* __restrict__ xrel, const float* __restrict__ rel_agg)
{
    int row = (int)((blockIdx.x * 256 + threadIdx.x) >> 6);  // 0..B*R-1
    int lane = threadIdx.x & 63;
    if (row >= BB * RR) return;
    int b = row / RR, r = row - b * RR;
    int r0 = bt[(b * KK) * 3 + 2];
    float xv = xrel[row * DD + lane];
    float av = rel_agg[row * DD + lane] + ((r == r0) ? 1.0f : 0.0f);
    float acc = bias[lane];
#pragma unroll 8
    for (int k = 0; k < DD; ++k) {
        acc += __shfl(xv, k, 64) * W[k * DD + lane];
        acc += __shfl(av, k, 64) * W[(DD + k) * DD + lane];
    }
    float m = wsum64(acc) * (1.0f / DD);
    float c = acc - m;
    float v = wsum64(c * c) * (1.0f / DD);
    float o = c * rsqrtf(v + 1e-5f) * g[lane] + beta[lane];
    o = fmaxf(o, 0.0f) + xv;
    xrel[row * DD + lane] = o;
}

__global__ __launch_bounds__(256) void rel_finish(
    const int* __restrict__ bt, const float* __restrict__ xrel,
    float* __restrict__ query)
{
    int i = threadIdx.x;  // 0..255 = B*D
    int b = i / DD, d = i - b * DD;
    int r0 = bt[(b * KK) * 3 + 2];
    query[b * DD + d] = xrel[(b * RR + r0) * DD + d];
}

// ==================== entity stage ===========================================
__global__ __launch_bounds__(256) void rel_proj(
    const float* __restrict__ rel_repr,
    const float* __restrict__ W1, const float* __restrict__ b1,
    const float* __restrict__ W2, const float* __restrict__ b2,
    float* __restrict__ rel_buf)
{
    int row = (blockIdx.x * 256 + threadIdx.x) >> 6;  // 0..B*R-1
    int lane = threadIdx.x & 63;
    if (row >= BB * RR) return;
    const float* xr = &rel_repr[row * DD];
    float h = b1[lane];
#pragma unroll 8
    for (int k = 0; k < DD; ++k) h += xr[k] * W1[k * DD + lane];
    h = fmaxf(h, 0.0f);
    float o = b2[lane];
#pragma unroll 8
    for (int k = 0; k < DD; ++k) o += __shfl(h, k, 64) * W2[k * DD + lane];
    rel_buf[row * DD + lane] = o;
}

// ---------- layer-0 fast path ----------
__global__ __launch_bounds__(256) void l0_scan(
    const int* __restrict__ edge_index, const int* __restrict__ edge_type,
    const int* __restrict__ bt, int* __restrict__ fixlist, int* __restrict__ cnt)
{
    int e = blockIdx.x * 256 + threadIdx.x;
    if (e < BB) {
        int h0 = bt[e * KK * 3];
        int pos = atomicAdd(&cnt[e], 1);
        if (pos < FCAP) fixlist[e * FCAP + pos] = h0 | (int)(0xFFFFu << 16);
    }
    if (e >= EE) return;
    int s = edge_index[e];
    int d = edge_index[EE + e];
    int t = edge_type[e];
#pragma unroll
    for (int b = 0; b < BB; ++b) {
        int h0 = bt[b * KK * 3];
        if (s == h0) {
            int pos = atomicAdd(&cnt[b], 1);
            if (pos < FCAP) fixlist[b * FCAP + pos] = d | (t << 16);
        }
    }
}

__global__ __launch_bounds__(256) void l0_broadcast(
    const float* __restrict__ b0, const float* __restrict__ g0,
    const float* __restrict__ be0, float* __restrict__ x)
{
    int lane = threadIdx.x & 63;
    float bv = b0[lane];
    float m = wsum64(bv) * (1.0f / DD);
    float c = bv - m;
    float v = wsum64(c * c) * (1.0f / DD);
    float d = fmaxf(c * rsqrtf(v + 1e-5f) * g0[lane] + be0[lane], 0.0f);
    int gw = blockIdx.x * 4 + (threadIdx.x >> 6);
    int nw = gridDim.x * 4;
    for (int row = gw; row < BB * NN; row += nw)
        x[(size_t)row * DD + lane] = d;
}

__global__ __launch_bounds__(256) void l0_fix(
    const int* __restrict__ bt, const int* __restrict__ fixlist,
    const int* __restrict__ cnt, const float* __restrict__ query,
    const float* __restrict__ rel_buf,
    const float* __restrict__ W0, const float* __restrict__ b0,
    const float* __restrict__ g0, const float* __restrict__ be0,
    float* __restrict__ x)
{
    int gidx = blockIdx.x * 4 + (threadIdx.x >> 6);  // 0..BB*FCAP-1
    int lane = threadIdx.x & 63;
    int b = gidx / FCAP, i = gidx - b * FCAP;
    int nc = min(cnt[b], FCAP);
    if (i >= nc) return;
    unsigned ent = (unsigned)fixlist[b * FCAP + i];
    int v = (int)(ent & 0xFFFFu);
    int h0 = bt[b * KK * 3];
    float q = query[b * DD + lane];
    float agg = (v == h0) ? q : 0.0f;
    for (int j = 0; j < nc; ++j) {
        unsigned ej = (unsigned)fixlist[b * FCAP + j];
        if ((int)(ej & 0xFFFFu) == v) {
            unsigned et = ej >> 16;
            if (et != 0xFFFFu)
                agg += q * rel_buf[(b * RR + (int)et) * DD + lane];
        }
    }
    float xr = (v == h0) ? q : 0.0f;
    float acc = b0[lane];
#pragma unroll 8
    for (int k = 0; k < DD; ++k) {
        acc += __shfl(xr, k, 64) * W0[k * DD + lane];
        acc += __shfl(agg, k, 64) * W0[(DD + k) * DD + lane];
    }
    float m = wsum64(acc) * (1.0f / DD);
    float c = acc - m;
    float vv = wsum64(c * c) * (1.0f / DD);
    float o = c * rsqrtf(vv + 1e-5f) * g0[lane] + be0[lane];
    x[((size_t)b * NN + v) * DD + lane] = fmaxf(o, 0.0f) + xr;
}

// ---------- layers 1..3 ----------
__global__ __launch_bounds__(256) void gather_agg(
    const int* __restrict__ rowptr, const int* __restrict__ pack,
    const int* __restrict__ bt,
    const float* __restrict__ x, const float* __restrict__ rel_buf,
    const float* __restrict__ query, float* __restrict__ agg)
{
    int gw = blockIdx.x * 4 + (int)(threadIdx.x >> 6);
    int lane = threadIdx.x & 63;
    if (gw >= BB * NN) return;
    int b = gw / NN, v = gw - b * NN;
    int beg = rowptr[v], end = rowptr[v + 1];
    const float* xb = x + (size_t)b * NN * DD;
    const float* rb = rel_buf + b * RR * DD;
    float acc = 0.0f;
    int j = beg;
    for (; j + 1 < end; j += 2) {
        int p0 = pack[j], p1 = pack[j + 1];
        float m0 = xb[(p0 & 0xFFFF) * DD + lane] * rb[(p0 >> 16) * DD + lane];
        float m1 = xb[(p1 & 0xFFFF) * DD + lane] * rb[(p1 >> 16) * DD + lane];
        acc += m0 + m1;
    }
    if (j < end) {
        int p0 = pack[j];
        acc += xb[(p0 & 0xFFFF) * DD + lane] * rb[(p0 >> 16) * DD + lane];
    }
    int h0 = bt[b * KK * 3];
    if (v == h0) acc += query[b * DD + lane];
    agg[(size_t)gw * DD + lane] = acc;
}

// ---- pack W (layers 1..3) into bf16 B-fragments for mfma_f32_16x16x32_bf16 --
// B operand layout: lane l holds B[k=(l>>4)*8+j][n=l&15], j=0..7.
// Storage: wbf[li][t][s][lane][j], li = layer-1, t = col-tile, s = k-step.
__global__ __launch_bounds__(64) void wfrag_build(
    const float* __restrict__ entW, unsigned short* __restrict__ wbf)
{
    int blk = blockIdx.x;            // li*16 + t*4 + s
    int li = blk >> 4;
    int t = (blk >> 2) & 3, s = blk & 3;
    int lane = threadIdx.x;
    const float* W = entW + (li + 1) * 2 * DD * DD;
    unsigned short* dst = wbf + ((size_t)blk * 64 + lane) * 8;
#pragma unroll
    for (int j = 0; j < 8; ++j) {
        int k = s * 32 + (lane >> 4) * 8 + j;
        int n = t * 16 + (lane & 15);
        dst[j] = f2bf_rne(W[k * DD + n]);
    }
}

// dense via MFMA: 1 wave = 16 rows x 64 cols, K=128 (x||agg), W in registers.
// C layout (verified): col = lane&15, row = (lane>>4)*4 + reg.
__global__ __launch_bounds__(256) void ent_dense6(
    const unsigned short* __restrict__ wfrag,
    const float* __restrict__ bias, const float* __restrict__ g,
    const float* __restrict__ beta,
    float* __restrict__ x, const float* __restrict__ agg)
{
    int lane = threadIdx.x & 63;
    int gw = blockIdx.x * 4 + (int)(threadIdx.x >> 6);
    int base = gw * 16;
    if (base >= BB * NN) return;

    // B fragments: [s][t], 16 x 16B coalesced loads
    s16x8 bfr[4][4];
#pragma unroll
    for (int t = 0; t < 4; ++t)
#pragma unroll
        for (int s = 0; s < 4; ++s)
            bfr[s][t] = *(const s16x8*)&wfrag[((size_t)(t * 4 + s) * 64 + lane) * 8];

    // A: lane l holds A[m=l&15][k=(l>>4)*8+j]; rows = base..base+15
    f32x4 acc[4] = {f32x4{0,0,0,0}, f32x4{0,0,0,0}, f32x4{0,0,0,0}, f32x4{0,0,0,0}};
    const size_t arow = (size_t)(base + (lane & 15)) * DD;
    const int koff = (lane >> 4) * 8;
#pragma unroll
    for (int s = 0; s < 4; ++s) {
        const float* src = (s < 2) ? (x + arow + s * 32 + koff)
                                   : (agg + arow + (s - 2) * 32 + koff);
        float4 v0 = *(const float4*)src;
        float4 v1 = *(const float4*)(src + 4);
        s16x8 a;
        a[0] = (short)f2bf_rne(v0.x); a[1] = (short)f2bf_rne(v0.y);
        a[2] = (short)f2bf_rne(v0.z); a[3] = (short)f2bf_rne(v0.w);
        a[4] = (short)f2bf_rne(v1.x); a[5] = (short)f2bf_rne(v1.y);
        a[6] = (short)f2bf_rne(v1.z); a[7] = (short)f2bf_rne(v1.w);
#pragma unroll
        for (int t = 0; t < 4; ++t)
            acc[t] = __builtin_amdgcn_mfma_f32_16x16x32_bf16(a, bfr[s][t], acc[t], 0, 0, 0);
    }

    // epilogue: bias + LN + relu + residual, in-place
    float bia[4], gt[4], bet[4];
#pragma unroll
    for (int t = 0; t < 4; ++t) {
        int col = (lane & 15) + 16 * t;
        bia[t] = bias[col]; gt[t] = g[col]; bet[t] = beta[col];
    }
#pragma unroll
    for (int r = 0; r < 4; ++r) {
        float v0 = acc[0][r] + bia[0];
        float v1 = acc[1][r] + bia[1];
        float v2 = acc[2][r] + bia[2];
        float v3 = acc[3][r] + bia[3];
        float sum = v0 + v1 + v2 + v3;
#pragma unroll
        for (int off = 1; off < 16; off <<= 1) sum += __shfl_xor(sum, off, 64);
        float m = sum * (1.0f / DD);
        float c0 = v0 - m, c1 = v1 - m, c2 = v2 - m, c3 = v3 - m;
        float q = c0 * c0 + c1 * c1 + c2 * c2 + c3 * c3;
#pragma unroll
        for (int off = 1; off < 16; off <<= 1) q += __shfl_xor(q, off, 64);
        float inv = rsqrtf(q * (1.0f / DD) + 1e-5f);
        size_t row = (size_t)(base + (lane >> 4) * 4 + r) * DD;
        float cs[4] = {c0, c1, c2, c3};
#pragma unroll
        for (int t = 0; t < 4; ++t) {
            int col = (lane & 15) + 16 * t;
            float xo = x[row + col];
            float o = cs[t] * inv * gt[t] + bet[t];
            x[row + col] = fmaxf(o, 0.0f) + xo;
        }
    }
}

// ==================== readout ================================================
__global__ __launch_bounds__(128) void readout(
    const int* __restrict__ bt, const float* __restrict__ x,
    const float* __restrict__ query,
    const float* __restrict__ W1, const float* __restrict__ b1,
    const float* __restrict__ W2, const float* __restrict__ b2,
    float* __restrict__ out)
{
    int b = blockIdx.x / KK, k = blockIdx.x - b * KK;
    int t = bt[(b * KK + k) * 3 + 1];
    __shared__ float feat[2 * DD];
    __shared__ float red[2 * DD];
    int j = threadIdx.x;
    if (j < DD) feat[j] = x[((size_t)b * NN + t) * DD + j];
    else        feat[j] = query[b * DD + (j - DD)];
    __syncthreads();
    float h = b1[j];
#pragma unroll 8
    for (int i = 0; i < 2 * DD; ++i) h += feat[i] * W1[i * 2 * DD + j];
    h = fmaxf(h, 0.0f);
    red[j] = h * W2[j];
    __syncthreads();
    for (int s = 64; s > 0; s >>= 1) {
        if (j < s) red[j] += red[j + s];
        __syncthreads();
    }
    if (j == 0) out[blockIdx.x] = red[0] + b2[0];
}

extern "C" void kernel_launch(void* const* d_in, const int* in_sizes, int n_in,
                              void* d_out, int out_size, void* d_ws, size_t ws_size,
                              hipStream_t stream) {
    const int*   edge_index     = (const int*)d_in[0];
    const int*   edge_type      = (const int*)d_in[1];
    const int*   rel_edge_index = (const int*)d_in[2];
    const int*   rel_edge_type  = (const int*)d_in[3];
    const int*   batch_triples  = (const int*)d_in[4];
    const float* rel_emb        = (const float*)d_in[5];
    const float* rel_W          = (const float*)d_in[6];
    const float* rel_b          = (const float*)d_in[7];
    const float* rel_g          = (const float*)d_in[8];
    const float* rel_beta       = (const float*)d_in[9];
    const float* proj_W1        = (const float*)d_in[10];
    const float* proj_b1        = (const float*)d_in[11];
    const float* proj_W2        = (const float*)d_in[12];
    const float* proj_b2        = (const float*)d_in[13];
    const float* ent_W          = (const float*)d_in[14];
    const float* ent_b          = (const float*)d_in[15];
    const float* ent_g          = (const float*)d_in[16];
    const float* ent_beta       = (const float*)d_in[17];
    const float* mlp_W1         = (const float*)d_in[18];
    const float* mlp_b1         = (const float*)d_in[19];
    const float* mlp_W2         = (const float*)d_in[20];
    const float* mlp_b2         = (const float*)d_in[21];

    float* ws = (float*)d_ws;
    float* x_ent    = ws;                                   // B*N*D
    float* agg_ent  = x_ent    + (size_t)BB * NN * DD;      // B*N*D
    float* rel_repr = agg_ent  + (size_t)BB * NN * DD;      // B*R*D
    float* rel_buf  = rel_repr + BB * RR * DD;              // B*R*D
    float* rel_agg  = rel_buf  + BB * RR * DD;              // B*R*D
    float* query    = rel_agg  + BB * RR * DD;              // B*D
    int*   deg      = (int*)(query + BB * DD);              // N
    int*   rowptr   = deg + NN;                             // N+1
    int*   cursor   = rowptr + NN + 1;                      // N
    int*   pack     = cursor + NN;                          // E
    int*   fixlist  = pack + EE;                            // BB*FCAP
    int*   fixcnt   = fixlist + BB * FCAP;                  // BB
    uintptr_t wp = (uintptr_t)(fixcnt + BB);
    wp = (wp + 15) & ~(uintptr_t)15;
    unsigned short* wbf = (unsigned short*)wp;              // 3*16*64*8 ushort

    // ---- CSR build + W fragment pack ----
    hipMemsetAsync(deg, 0, sizeof(int) * NN, stream);
    hipMemsetAsync(fixcnt, 0, sizeof(int) * BB, stream);
    csr_hist<<<(EE + 255) / 256, 256, 0, stream>>>(edge_index, deg);
    csr_scan<<<1, 1024, 0, stream>>>(deg, rowptr, cursor);
    csr_fill<<<(EE + 255) / 256, 256, 0, stream>>>(edge_index, edge_type, cursor, pack);
    wfrag_build<<<48, 64, 0, stream>>>(ent_W, wbf);

    // ---- relation stage ----
    rel_init<<<(BB * RR * DD + 255) / 256, 256, 0, stream>>>(batch_triples, rel_repr);
    for (int l = 0; l < LL; ++l) {
        hipMemsetAsync(rel_agg, 0, sizeof(float) * BB * RR * DD, stream);
        rel_scatter<<<(BB * ERE) / 4, 256, 0, stream>>>(
            rel_edge_index, rel_edge_type, rel_repr,
            rel_emb + l * RT * DD, rel_agg);
        rel_dense<<<(BB * RR) / 4, 256, 0, stream>>>(
            batch_triples, rel_W + l * 2 * DD * DD, rel_b + l * DD,
            rel_g + l * DD, rel_beta + l * DD, rel_repr, rel_agg);
    }
    rel_finish<<<1, 256, 0, stream>>>(batch_triples, rel_repr, query);

    // ---- entity stage: layer 0 fast path ----
    rel_proj<<<(BB * RR * 64) / 256, 256, 0, stream>>>(
        rel_repr, proj_W1, proj_b1, proj_W2, proj_b2, rel_buf);
    l0_scan<<<(EE + 255) / 256, 256, 0, stream>>>(
        edge_index, edge_type, batch_triples, fixlist, fixcnt);
    l0_broadcast<<<1024, 256, 0, stream>>>(ent_b, ent_g, ent_beta, x_ent);
    l0_fix<<<(BB * FCAP) / 4, 256, 0, stream>>>(
        batch_triples, fixlist, fixcnt, query, rel_buf,
        ent_W, ent_b, ent_g, ent_beta, x_ent);

    // ---- entity stage: layers 1..3 (MFMA dense) ----
    for (int l = 1; l < LL; ++l) {
        rel_proj<<<(BB * RR * 64) / 256, 256, 0, stream>>>(
            rel_repr, proj_W1 + l * DD * DD, proj_b1 + l * DD,
            proj_W2 + l * DD * DD, proj_b2 + l * DD, rel_buf);
        gather_agg<<<(BB * NN) / 4, 256, 0, stream>>>(
            rowptr, pack, batch_triples, x_ent, rel_buf, query, agg_ent);
        ent_dense6<<<(BB * NN / 16 + 3) / 4, 256, 0, stream>>>(
            wbf + (size_t)(l - 1) * 16 * 64 * 8,
            ent_b + l * DD, ent_g + l * DD, ent_beta + l * DD,
            x_ent, agg_ent);
    }

    readout<<<BB * KK, 2 * DD, 0, stream>>>(batch_triples, x_ent, query,
                                            mlp_W1, mlp_b1, mlp_W2, mlp_b2,
                                            (float*)d_out);
}

// Round 8
// 430.082 us; speedup vs baseline: 4.4357x; 1.4670x over previous
//
#include <hip/hip_runtime.h>
#include <hip/hip_bf16.h>

#define BB 4
#define KK 16
#define NN 50000
#define EE 300000
#define RR 64
#define ERE 2048
#define RT 4
#define DD 64
#define LL 4
#define FCAP 256
#define NSB 196  // (NN+255)/256

typedef short s16x8 __attribute__((ext_vector_type(8)));
typedef float f32x4 __attribute__((ext_vector_type(4)));

__device__ __forceinline__ float wsum64(float v) {
#pragma unroll
    for (int off = 32; off > 0; off >>= 1) v += __shfl_xor(v, off, 64);
    return v;
}

__device__ __forceinline__ unsigned short f2bf_rne(float f) {
    unsigned u = __builtin_bit_cast(unsigned, f);
    return (unsigned short)((u + 0x7FFFu + ((u >> 16) & 1u)) >> 16);
}

// ==================== CSR build (once per call) ==============================
__global__ __launch_bounds__(256) void csr_hist(
    const int* __restrict__ edge_index, int* __restrict__ deg)
{
    int e = blockIdx.x * 256 + threadIdx.x;
    if (e < EE) atomicAdd(&deg[edge_index[EE + e]], 1);
}

__global__ __launch_bounds__(256) void scan_a(
    const int* __restrict__ deg, int* __restrict__ bsum)
{
    int i = blockIdx.x * 256 + threadIdx.x;
    int v = (i < NN) ? deg[i] : 0;
    int s = v;
#pragma unroll
    for (int off = 32; off > 0; off >>= 1) s += __shfl_xor(s, off, 64);
    __shared__ int ls[4];
    if ((threadIdx.x & 63) == 0) ls[threadIdx.x >> 6] = s;
    __syncthreads();
    if (threadIdx.x == 0) bsum[blockIdx.x] = ls[0] + ls[1] + ls[2] + ls[3];
}

__global__ __launch_bounds__(256) void scan_b(
    const int* __restrict__ bsum, int* __restrict__ boff, int* __restrict__ rowptr)
{
    __shared__ int tmp[256];
    int t = threadIdx.x;
    int v = (t < NSB) ? bsum[t] : 0;
    tmp[t] = v;
    __syncthreads();
    for (int off = 1; off < 256; off <<= 1) {
        int u = (t >= off) ? tmp[t - off] : 0;
        __syncthreads();
        tmp[t] += u;
        __syncthreads();
    }
    if (t < NSB) boff[t] = tmp[t] - v;
    if (t == 0) rowptr[NN] = EE;
}

__global__ __launch_bounds__(256) void scan_c(
    const int* __restrict__ deg, const int* __restrict__ boff,
    int* __restrict__ rowptr, int* __restrict__ cursor)
{
    __shared__ int tmp[256];
    int t = threadIdx.x;
    int i = blockIdx.x * 256 + t;
    int v = (i < NN) ? deg[i] : 0;
    tmp[t] = v;
    __syncthreads();
    for (int off = 1; off < 256; off <<= 1) {
        int u = (t >= off) ? tmp[t - off] : 0;
        __syncthreads();
        tmp[t] += u;
        __syncthreads();
    }
    if (i < NN) {
        int excl = tmp[t] - v + boff[blockIdx.x];
        rowptr[i] = excl;
        cursor[i] = excl;
    }
}

__global__ __launch_bounds__(256) void csr_fill(
    const int* __restrict__ edge_index, const int* __restrict__ edge_type,
    int* __restrict__ cursor, int* __restrict__ pack)
{
    int e = blockIdx.x * 256 + threadIdx.x;
    if (e >= EE) return;
    int s = edge_index[e];
    int d = edge_index[EE + e];
    int t = edge_type[e];
    int pos = atomicAdd(&cursor[d], 1);
    pack[pos] = s | (t << 16);  // src < 2^16, et < 64
}

// ==================== relation stage =========================================
// tiny CSR for the relation graph, one block
__global__ __launch_bounds__(256) void rel_csr(
    const int* __restrict__ rel_edge_index, const int* __restrict__ rel_edge_type,
    int* __restrict__ rptr, int* __restrict__ rpack)
{
    __shared__ int hdeg[RR];
    __shared__ int hcur[RR];
    int t = threadIdx.x;
    if (t < RR) hdeg[t] = 0;
    __syncthreads();
    for (int e = t; e < ERE; e += 256) atomicAdd(&hdeg[rel_edge_index[ERE + e]], 1);
    __syncthreads();
    if (t == 0) {
        int run = 0;
        for (int r = 0; r < RR; ++r) { hcur[r] = run; rptr[r] = run; run += hdeg[r]; }
        rptr[RR] = run;
    }
    __syncthreads();
    for (int e = t; e < ERE; e += 256) {
        int s = rel_edge_index[e];
        int d = rel_edge_index[ERE + e];
        int ty = rel_edge_type[e];
        int pos = atomicAdd(&hcur[d], 1);
        rpack[pos] = s | (ty << 16);
    }
}

__global__ __launch_bounds__(256) void rel_init(
    const int* __restrict__ bt, float* __restrict__ xrel)
{
    int i = blockIdx.x * 256 + threadIdx.x;
    if (i >= BB * RR * DD) return;
    int b = i / (RR * DD);
    int r = (i % (RR * DD)) / DD;
    int r0 = bt[(b * KK) * 3 + 2];
    xrel[i] = (r == r0) ? 1.0f : 0.0f;
}

// fused gather + dense + LN + relu + residual; ping-pong xin -> xout
__global__ __launch_bounds__(256) void rel_layer(
    const int* __restrict__ rptr, const int* __restrict__ rpack,
    const int* __restrict__ bt, const float* __restrict__ emb,
    const float* __restrict__ W, const float* __restrict__ bias,
    const float* __restrict__ g, const float* __restrict__ beta,
    const float* __restrict__ xin, float* __restrict__ xout)
{
    int row = blockIdx.x * 4 + (int)(threadIdx.x >> 6);  // 0..BB*RR-1
    int lane = threadIdx.x & 63;
    int b = row >> 6, r = row & 63;
    int r0 = bt[(b * KK) * 3 + 2];
    int beg = rptr[r], end = rptr[r + 1];
    const float* xb = xin + b * RR * DD;
    float av = (r == r0) ? 1.0f : 0.0f;
    for (int j = beg; j < end; ++j) {
        int p = rpack[j];
        av += xb[(p & 0xFFFF) * DD + lane] * emb[(p >> 16) * DD + lane];
    }
    float xv = xin[row * DD + lane];
    float acc = bias[lane];
#pragma unroll 8
    for (int k = 0; k < DD; ++k) {
        acc += __shfl(xv, k, 64) * W[k * DD + lane];
        acc += __shfl(av, k, 64) * W[(DD + k) * DD + lane];
    }
    float m = wsum64(acc) * (1.0f / DD);
    float c = acc - m;
    float v = wsum64(c * c) * (1.0f / DD);
    float o = c * rsqrtf(v + 1e-5f) * g[lane] + beta[lane];
    xout[row * DD + lane] = fmaxf(o, 0.0f) + xv;
}

__global__ __launch_bounds__(256) void rel_finish(
    const int* __restrict__ bt, const float* __restrict__ xrel,
    float* __restrict__ query)
{
    int i = threadIdx.x;  // 0..255 = B*D
    int b = i / DD, d = i - b * DD;
    int r0 = bt[(b * KK) * 3 + 2];
    query[b * DD + d] = xrel[(b * RR + r0) * DD + d];
}

// ==================== entity stage ===========================================
__global__ __launch_bounds__(256) void rel_proj(
    const float* __restrict__ rel_repr,
    const float* __restrict__ W1, const float* __restrict__ b1,
    const float* __restrict__ W2, const float* __restrict__ b2,
    float* __restrict__ rel_buf)
{
    int row = (blockIdx.x * 256 + threadIdx.x) >> 6;  // 0..B*R-1
    int lane = threadIdx.x & 63;
    if (row >= BB * RR) return;
    const float* xr = &rel_repr[row * DD];
    float h = b1[lane];
#pragma unroll 8
    for (int k = 0; k < DD; ++k) h += xr[k] * W1[k * DD + lane];
    h = fmaxf(h, 0.0f);
    float o = b2[lane];
#pragma unroll 8
    for (int k = 0; k < DD; ++k) o += __shfl(h, k, 64) * W2[k * DD + lane];
    rel_buf[row * DD + lane] = o;
}

// ---------- layer-0 fast path ----------
__global__ __launch_bounds__(256) void l0_scan(
    const int* __restrict__ edge_index, const int* __restrict__ edge_type,
    const int* __restrict__ bt, int* __restrict__ fixlist, int* __restrict__ cnt)
{
    int e = blockIdx.x * 256 + threadIdx.x;
    if (e < BB) {
        int h0 = bt[e * KK * 3];
        int pos = atomicAdd(&cnt[e], 1);
        if (pos < FCAP) fixlist[e * FCAP + pos] = h0 | (int)(0xFFFFu << 16);
    }
    if (e >= EE) return;
    int s = edge_index[e];
    int d = edge_index[EE + e];
    int t = edge_type[e];
#pragma unroll
    for (int b = 0; b < BB; ++b) {
        int h0 = bt[b * KK * 3];
        if (s == h0) {
            int pos = atomicAdd(&cnt[b], 1);
            if (pos < FCAP) fixlist[b * FCAP + pos] = d | (t << 16);
        }
    }
}

__global__ __launch_bounds__(256) void l0_broadcast(
    const float* __restrict__ b0, const float* __restrict__ g0,
    const float* __restrict__ be0, float* __restrict__ x)
{
    int lane = threadIdx.x & 63;
    float bv = b0[lane];
    float m = wsum64(bv) * (1.0f / DD);
    float c = bv - m;
    float v = wsum64(c * c) * (1.0f / DD);
    float d = fmaxf(c * rsqrtf(v + 1e-5f) * g0[lane] + be0[lane], 0.0f);
    int gw = blockIdx.x * 4 + (threadIdx.x >> 6);
    int nw = gridDim.x * 4;
    for (int row = gw; row < BB * NN; row += nw)
        x[(size_t)row * DD + lane] = d;
}

__global__ __launch_bounds__(256) void l0_fix(
    const int* __restrict__ bt, const int* __restrict__ fixlist,
    const int* __restrict__ cnt, const float* __restrict__ query,
    const float* __restrict__ rel_buf,
    const float* __restrict__ W0, const float* __restrict__ b0,
    const float* __restrict__ g0, const float* __restrict__ be0,
    float* __restrict__ x)
{
    int gidx = blockIdx.x * 4 + (threadIdx.x >> 6);  // 0..BB*FCAP-1
    int lane = threadIdx.x & 63;
    int b = gidx / FCAP, i = gidx - b * FCAP;
    int nc = min(cnt[b], FCAP);
    if (i >= nc) return;
    unsigned ent = (unsigned)fixlist[b * FCAP + i];
    int v = (int)(ent & 0xFFFFu);
    int h0 = bt[b * KK * 3];
    float q = query[b * DD + lane];
    float agg = (v == h0) ? q : 0.0f;
    for (int j = 0; j < nc; ++j) {
        unsigned ej = (unsigned)fixlist[b * FCAP + j];
        if ((int)(ej & 0xFFFFu) == v) {
            unsigned et = ej >> 16;
            if (et != 0xFFFFu)
                agg += q * rel_buf[(b * RR + (int)et) * DD + lane];
        }
    }
    float xr = (v == h0) ? q : 0.0f;
    float acc = b0[lane];
#pragma unroll 8
    for (int k = 0; k < DD; ++k) {
        acc += __shfl(xr, k, 64) * W0[k * DD + lane];
        acc += __shfl(agg, k, 64) * W0[(DD + k) * DD + lane];
    }
    float m = wsum64(acc) * (1.0f / DD);
    float c = acc - m;
    float vv = wsum64(c * c) * (1.0f / DD);
    float o = c * rsqrtf(vv + 1e-5f) * g0[lane] + be0[lane];
    x[((size_t)b * NN + v) * DD + lane] = fmaxf(o, 0.0f) + xr;
}

// ---------- layers 1..3 ----------
// gather for all 4 batches per wave: 4 independent FMA chains, pack read once
__global__ __launch_bounds__(256) void gather_agg4(
    const int* __restrict__ rowptr, const int* __restrict__ pack,
    const int* __restrict__ bt,
    const float* __restrict__ x, const float* __restrict__ rel_buf,
    const float* __restrict__ query, float* __restrict__ agg)
{
    int v = blockIdx.x * 4 + (int)(threadIdx.x >> 6);
    int lane = threadIdx.x & 63;
    if (v >= NN) return;
    int beg = rowptr[v], end = rowptr[v + 1];
    const size_t XS = (size_t)NN * DD;   // batch stride in x/agg
    const int RS = RR * DD;              // batch stride in rel_buf
    float a0 = 0.0f, a1 = 0.0f, a2 = 0.0f, a3 = 0.0f;
    for (int j = beg; j < end; ++j) {
        int p = pack[j];
        const float* xs = x + (size_t)(p & 0xFFFF) * DD + lane;
        const float* rp = rel_buf + (p >> 16) * DD + lane;
        a0 += xs[0]      * rp[0];
        a1 += xs[XS]     * rp[RS];
        a2 += xs[2 * XS] * rp[2 * RS];
        a3 += xs[3 * XS] * rp[3 * RS];
    }
    float av[4] = {a0, a1, a2, a3};
#pragma unroll
    for (int b = 0; b < BB; ++b) {
        int h0 = bt[b * KK * 3];
        float a = av[b] + ((v == h0) ? query[b * DD + lane] : 0.0f);
        agg[(size_t)b * XS + (size_t)v * DD + lane] = a;
    }
}

// ---- pack W (layers 1..3) into bf16 B-fragments for mfma_f32_16x16x32_bf16 --
__global__ __launch_bounds__(64) void wfrag_build(
    const float* __restrict__ entW, unsigned short* __restrict__ wbf)
{
    int blk = blockIdx.x;            // li*16 + t*4 + s
    int li = blk >> 4;
    int t = (blk >> 2) & 3, s = blk & 3;
    int lane = threadIdx.x;
    const float* W = entW + (li + 1) * 2 * DD * DD;
    unsigned short* dst = wbf + ((size_t)blk * 64 + lane) * 8;
#pragma unroll
    for (int j = 0; j < 8; ++j) {
        int k = s * 32 + (lane >> 4) * 8 + j;
        int n = t * 16 + (lane & 15);
        dst[j] = f2bf_rne(W[k * DD + n]);
    }
}

// dense via MFMA: 1 wave = 16 rows x 64 cols, K=128 (x||agg), W in registers.
__global__ __launch_bounds__(256) void ent_dense6(
    const unsigned short* __restrict__ wfrag,
    const float* __restrict__ bias, const float* __restrict__ g,
    const float* __restrict__ beta,
    float* __restrict__ x, const float* __restrict__ agg)
{
    int lane = threadIdx.x & 63;
    int gw = blockIdx.x * 4 + (int)(threadIdx.x >> 6);
    int base = gw * 16;
    if (base >= BB * NN) return;

    s16x8 bfr[4][4];
#pragma unroll
    for (int t = 0; t < 4; ++t)
#pragma unroll
        for (int s = 0; s < 4; ++s)
            bfr[s][t] = *(const s16x8*)&wfrag[((size_t)(t * 4 + s) * 64 + lane) * 8];

    f32x4 acc[4] = {f32x4{0,0,0,0}, f32x4{0,0,0,0}, f32x4{0,0,0,0}, f32x4{0,0,0,0}};
    const size_t arow = (size_t)(base + (lane & 15)) * DD;
    const int koff = (lane >> 4) * 8;
#pragma unroll
    for (int s = 0; s < 4; ++s) {
        const float* src = (s < 2) ? (x + arow + s * 32 + koff)
                                   : (agg + arow + (s - 2) * 32 + koff);
        float4 v0 = *(const float4*)src;
        float4 v1 = *(const float4*)(src + 4);
        s16x8 a;
        a[0] = (short)f2bf_rne(v0.x); a[1] = (short)f2bf_rne(v0.y);
        a[2] = (short)f2bf_rne(v0.z); a[3] = (short)f2bf_rne(v0.w);
        a[4] = (short)f2bf_rne(v1.x); a[5] = (short)f2bf_rne(v1.y);
        a[6] = (short)f2bf_rne(v1.z); a[7] = (short)f2bf_rne(v1.w);
#pragma unroll
        for (int t = 0; t < 4; ++t)
            acc[t] = __builtin_amdgcn_mfma_f32_16x16x32_bf16(a, bfr[s][t], acc[t], 0, 0, 0);
    }

    float bia[4], gt[4], bet[4];
#pragma unroll
    for (int t = 0; t < 4; ++t) {
        int col = (lane & 15) + 16 * t;
        bia[t] = bias[col]; gt[t] = g[col]; bet[t] = beta[col];
    }
#pragma unroll
    for (int r = 0; r < 4; ++r) {
        float v0 = acc[0][r] + bia[0];
        float v1 = acc[1][r] + bia[1];
        float v2 = acc[2][r] + bia[2];
        float v3 = acc[3][r] + bia[3];
        float sum = v0 + v1 + v2 + v3;
#pragma unroll
        for (int off = 1; off < 16; off <<= 1) sum += __shfl_xor(sum, off, 64);
        float m = sum * (1.0f / DD);
        float c0 = v0 - m, c1 = v1 - m, c2 = v2 - m, c3 = v3 - m;
        float q = c0 * c0 + c1 * c1 + c2 * c2 + c3 * c3;
#pragma unroll
        for (int off = 1; off < 16; off <<= 1) q += __shfl_xor(q, off, 64);
        float inv = rsqrtf(q * (1.0f / DD) + 1e-5f);
        size_t row = (size_t)(base + (lane >> 4) * 4 + r) * DD;
        float cs[4] = {c0, c1, c2, c3};
#pragma unroll
        for (int t = 0; t < 4; ++t) {
            int col = (lane & 15) + 16 * t;
            float xo = x[row + col];
            float o = cs[t] * inv * gt[t] + bet[t];
            x[row + col] = fmaxf(o, 0.0f) + xo;
        }
    }
}

// ==================== readout ================================================
__global__ __launch_bounds__(128) void readout(
    const int* __restrict__ bt, const float* __restrict__ x,
    const float* __restrict__ query,
    const float* __restrict__ W1, const float* __restrict__ b1,
    const float* __restrict__ W2, const float* __restrict__ b2,
    float* __restrict__ out)
{
    int b = blockIdx.x / KK, k = blockIdx.x - b * KK;
    int t = bt[(b * KK + k) * 3 + 1];
    __shared__ float feat[2 * DD];
    __shared__ float red[2 * DD];
    int j = threadIdx.x;
    if (j < DD) feat[j] = x[((size_t)b * NN + t) * DD + j];
    else        feat[j] = query[b * DD + (j - DD)];
    __syncthreads();
    float h = b1[j];
#pragma unroll 8
    for (int i = 0; i < 2 * DD; ++i) h += feat[i] * W1[i * 2 * DD + j];
    h = fmaxf(h, 0.0f);
    red[j] = h * W2[j];
    __syncthreads();
    for (int s = 64; s > 0; s >>= 1) {
        if (j < s) red[j] += red[j + s];
        __syncthreads();
    }
    if (j == 0) out[blockIdx.x] = red[0] + b2[0];
}

extern "C" void kernel_launch(void* const* d_in, const int* in_sizes, int n_in,
                              void* d_out, int out_size, void* d_ws, size_t ws_size,
                              hipStream_t stream) {
    const int*   edge_index     = (const int*)d_in[0];
    const int*   edge_type      = (const int*)d_in[1];
    const int*   rel_edge_index = (const int*)d_in[2];
    const int*   rel_edge_type  = (const int*)d_in[3];
    const int*   batch_triples  = (const int*)d_in[4];
    const float* rel_emb        = (const float*)d_in[5];
    const float* rel_W          = (const float*)d_in[6];
    const float* rel_b          = (const float*)d_in[7];
    const float* rel_g          = (const float*)d_in[8];
    const float* rel_beta       = (const float*)d_in[9];
    const float* proj_W1        = (const float*)d_in[10];
    const float* proj_b1        = (const float*)d_in[11];
    const float* proj_W2        = (const float*)d_in[12];
    const float* proj_b2        = (const float*)d_in[13];
    const float* ent_W          = (const float*)d_in[14];
    const float* ent_b          = (const float*)d_in[15];
    const float* ent_g          = (const float*)d_in[16];
    const float* ent_beta       = (const float*)d_in[17];
    const float* mlp_W1         = (const float*)d_in[18];
    const float* mlp_b1         = (const float*)d_in[19];
    const float* mlp_W2         = (const float*)d_in[20];
    const float* mlp_b2         = (const float*)d_in[21];

    float* ws = (float*)d_ws;
    float* x_ent    = ws;                                   // B*N*D
    float* agg_ent  = x_ent    + (size_t)BB * NN * DD;      // B*N*D
    float* xrel0    = agg_ent  + (size_t)BB * NN * DD;      // B*R*D
    float* xrel1    = xrel0    + BB * RR * DD;              // B*R*D
    float* rel_buf  = xrel1    + BB * RR * DD;              // B*R*D
    float* query    = rel_buf  + BB * RR * DD;              // B*D
    int*   deg      = (int*)(query + BB * DD);              // N
    int*   rowptr   = deg + NN;                             // N+1
    int*   cursor   = rowptr + NN + 1;                      // N
    int*   pack     = cursor + NN;                          // E
    int*   fixlist  = pack + EE;                            // BB*FCAP
    int*   fixcnt   = fixlist + BB * FCAP;                  // BB
    int*   bsum     = fixcnt + BB;                          // NSB (pad 256)
    int*   boff     = bsum + 256;                           // NSB (pad 256)
    int*   rptrR    = boff + 256;                           // RR+1 (pad 66)
    int*   rpackR   = rptrR + 66;                           // ERE
    uintptr_t wp = (uintptr_t)(rpackR + ERE);
    wp = (wp + 15) & ~(uintptr_t)15;
    unsigned short* wbf = (unsigned short*)wp;              // 3*16*64*8 ushort

    // ---- CSR build (multi-block scan) + rel CSR + W fragment pack ----
    hipMemsetAsync(deg, 0, sizeof(int) * NN, stream);
    hipMemsetAsync(fixcnt, 0, sizeof(int) * BB, stream);
    csr_hist<<<(EE + 255) / 256, 256, 0, stream>>>(edge_index, deg);
    scan_a<<<NSB, 256, 0, stream>>>(deg, bsum);
    scan_b<<<1, 256, 0, stream>>>(bsum, boff, rowptr);
    scan_c<<<NSB, 256, 0, stream>>>(deg, boff, rowptr, cursor);
    csr_fill<<<(EE + 255) / 256, 256, 0, stream>>>(edge_index, edge_type, cursor, pack);
    rel_csr<<<1, 256, 0, stream>>>(rel_edge_index, rel_edge_type, rptrR, rpackR);
    wfrag_build<<<48, 64, 0, stream>>>(ent_W, wbf);

    // ---- relation stage: fused gather+dense per layer, ping-pong ----
    rel_init<<<(BB * RR * DD + 255) / 256, 256, 0, stream>>>(batch_triples, xrel0);
    for (int l = 0; l < LL; ++l) {
        const float* xin = (l & 1) ? xrel1 : xrel0;
        float* xout = (l & 1) ? xrel0 : xrel1;
        rel_layer<<<BB * RR / 4, 256, 0, stream>>>(
            rptrR, rpackR, batch_triples, rel_emb + l * RT * DD,
            rel_W + l * 2 * DD * DD, rel_b + l * DD,
            rel_g + l * DD, rel_beta + l * DD, xin, xout);
    }
    float* rel_repr = xrel0;  // LL=4 even -> final in xrel0
    rel_finish<<<1, 256, 0, stream>>>(batch_triples, rel_repr, query);

    // ---- entity stage: layer 0 fast path ----
    rel_proj<<<(BB * RR * 64) / 256, 256, 0, stream>>>(
        rel_repr, proj_W1, proj_b1, proj_W2, proj_b2, rel_buf);
    l0_scan<<<(EE + 255) / 256, 256, 0, stream>>>(
        edge_index, edge_type, batch_triples, fixlist, fixcnt);
    l0_broadcast<<<1024, 256, 0, stream>>>(ent_b, ent_g, ent_beta, x_ent);
    l0_fix<<<(BB * FCAP) / 4, 256, 0, stream>>>(
        batch_triples, fixlist, fixcnt, query, rel_buf,
        ent_W, ent_b, ent_g, ent_beta, x_ent);

    // ---- entity stage: layers 1..3 (gather4 + MFMA dense) ----
    for (int l = 1; l < LL; ++l) {
        rel_proj<<<(BB * RR * 64) / 256, 256, 0, stream>>>(
            rel_repr, proj_W1 + l * DD * DD, proj_b1 + l * DD,
            proj_W2 + l * DD * DD, proj_b2 + l * DD, rel_buf);
        gather_agg4<<<(NN + 3) / 4, 256, 0, stream>>>(
            rowptr, pack, batch_triples, x_ent, rel_buf, query, agg_ent);
        ent_dense6<<<(BB * NN / 16 + 3) / 4, 256, 0, stream>>>(
            wbf + (size_t)(l - 1) * 16 * 64 * 8,
            ent_b + l * DD, ent_g + l * DD, ent_beta + l * DD,
            x_ent, agg_ent);
    }

    readout<<<BB * KK, 2 * DD, 0, stream>>>(batch_triples, x_ent, query,
                                            mlp_W1, mlp_b1, mlp_W2, mlp_b2,
                                            (float*)d_out);
}

// Round 9
// 429.759 us; speedup vs baseline: 4.4390x; 1.0008x over previous
//
#include <hip/hip_runtime.h>
#include <hip/hip_bf16.h>

#define BB 4
#define KK 16
#define NN 50000
#define EE 300000
#define RR 64
#define ERE 2048
#define RT 4
#define DD 64
#define LL 4
#define FCAP 256
#define NSB 196  // (NN+255)/256

typedef short s16x8 __attribute__((ext_vector_type(8)));
typedef float f32x4 __attribute__((ext_vector_type(4)));

__device__ __forceinline__ float wsum64(float v) {
#pragma unroll
    for (int off = 32; off > 0; off >>= 1) v += __shfl_xor(v, off, 64);
    return v;
}

__device__ __forceinline__ unsigned short f2bf_rne(float f) {
    unsigned u = __builtin_bit_cast(unsigned, f);
    return (unsigned short)((u + 0x7FFFu + ((u >> 16) & 1u)) >> 16);
}

__device__ __forceinline__ float bf2f(unsigned short h) {
    unsigned u = ((unsigned)h) << 16;
    return __builtin_bit_cast(float, u);
}

// ==================== CSR build (once per call) ==============================
__global__ __launch_bounds__(256) void csr_hist(
    const int* __restrict__ edge_index, int* __restrict__ deg)
{
    int e = blockIdx.x * 256 + threadIdx.x;
    if (e < EE) atomicAdd(&deg[edge_index[EE + e]], 1);
}

__global__ __launch_bounds__(256) void scan_a(
    const int* __restrict__ deg, int* __restrict__ bsum)
{
    int i = blockIdx.x * 256 + threadIdx.x;
    int v = (i < NN) ? deg[i] : 0;
    int s = v;
#pragma unroll
    for (int off = 32; off > 0; off >>= 1) s += __shfl_xor(s, off, 64);
    __shared__ int ls[4];
    if ((threadIdx.x & 63) == 0) ls[threadIdx.x >> 6] = s;
    __syncthreads();
    if (threadIdx.x == 0) bsum[blockIdx.x] = ls[0] + ls[1] + ls[2] + ls[3];
}

__global__ __launch_bounds__(256) void scan_b(
    const int* __restrict__ bsum, int* __restrict__ boff, int* __restrict__ rowptr)
{
    __shared__ int tmp[256];
    int t = threadIdx.x;
    int v = (t < NSB) ? bsum[t] : 0;
    tmp[t] = v;
    __syncthreads();
    for (int off = 1; off < 256; off <<= 1) {
        int u = (t >= off) ? tmp[t - off] : 0;
        __syncthreads();
        tmp[t] += u;
        __syncthreads();
    }
    if (t < NSB) boff[t] = tmp[t] - v;
    if (t == 0) rowptr[NN] = EE;
}

__global__ __launch_bounds__(256) void scan_c(
    const int* __restrict__ deg, const int* __restrict__ boff,
    int* __restrict__ rowptr, int* __restrict__ cursor)
{
    __shared__ int tmp[256];
    int t = threadIdx.x;
    int i = blockIdx.x * 256 + t;
    int v = (i < NN) ? deg[i] : 0;
    tmp[t] = v;
    __syncthreads();
    for (int off = 1; off < 256; off <<= 1) {
        int u = (t >= off) ? tmp[t - off] : 0;
        __syncthreads();
        tmp[t] += u;
        __syncthreads();
    }
    if (i < NN) {
        int excl = tmp[t] - v + boff[blockIdx.x];
        rowptr[i] = excl;
        cursor[i] = excl;
    }
}

__global__ __launch_bounds__(256) void csr_fill(
    const int* __restrict__ edge_index, const int* __restrict__ edge_type,
    int* __restrict__ cursor, int* __restrict__ pack)
{
    int e = blockIdx.x * 256 + threadIdx.x;
    if (e >= EE) return;
    int s = edge_index[e];
    int d = edge_index[EE + e];
    int t = edge_type[e];
    int pos = atomicAdd(&cursor[d], 1);
    pack[pos] = s | (t << 16);  // src < 2^16, et < 64
}

// ==================== relation stage =========================================
__global__ __launch_bounds__(256) void rel_csr(
    const int* __restrict__ rel_edge_index, const int* __restrict__ rel_edge_type,
    int* __restrict__ rptr, int* __restrict__ rpack)
{
    __shared__ int hdeg[RR];
    __shared__ int hcur[RR];
    int t = threadIdx.x;
    if (t < RR) hdeg[t] = 0;
    __syncthreads();
    for (int e = t; e < ERE; e += 256) atomicAdd(&hdeg[rel_edge_index[ERE + e]], 1);
    __syncthreads();
    if (t == 0) {
        int run = 0;
        for (int r = 0; r < RR; ++r) { hcur[r] = run; rptr[r] = run; run += hdeg[r]; }
        rptr[RR] = run;
    }
    __syncthreads();
    for (int e = t; e < ERE; e += 256) {
        int s = rel_edge_index[e];
        int d = rel_edge_index[ERE + e];
        int ty = rel_edge_type[e];
        int pos = atomicAdd(&hcur[d], 1);
        rpack[pos] = s | (ty << 16);
    }
}

__global__ __launch_bounds__(256) void rel_init(
    const int* __restrict__ bt, float* __restrict__ xrel)
{
    int i = blockIdx.x * 256 + threadIdx.x;
    if (i >= BB * RR * DD) return;
    int b = i / (RR * DD);
    int r = (i % (RR * DD)) / DD;
    int r0 = bt[(b * KK) * 3 + 2];
    xrel[i] = (r == r0) ? 1.0f : 0.0f;
}

__global__ __launch_bounds__(256) void rel_layer(
    const int* __restrict__ rptr, const int* __restrict__ rpack,
    const int* __restrict__ bt, const float* __restrict__ emb,
    const float* __restrict__ W, const float* __restrict__ bias,
    const float* __restrict__ g, const float* __restrict__ beta,
    const float* __restrict__ xin, float* __restrict__ xout)
{
    int row = blockIdx.x * 4 + (int)(threadIdx.x >> 6);  // 0..BB*RR-1
    int lane = threadIdx.x & 63;
    int b = row >> 6, r = row & 63;
    int r0 = bt[(b * KK) * 3 + 2];
    int beg = rptr[r], end = rptr[r + 1];
    const float* xb = xin + b * RR * DD;
    float av = (r == r0) ? 1.0f : 0.0f;
    for (int j = beg; j < end; ++j) {
        int p = rpack[j];
        av += xb[(p & 0xFFFF) * DD + lane] * emb[(p >> 16) * DD + lane];
    }
    float xv = xin[row * DD + lane];
    float acc = bias[lane];
#pragma unroll 8
    for (int k = 0; k < DD; ++k) {
        acc += __shfl(xv, k, 64) * W[k * DD + lane];
        acc += __shfl(av, k, 64) * W[(DD + k) * DD + lane];
    }
    float m = wsum64(acc) * (1.0f / DD);
    float c = acc - m;
    float v = wsum64(c * c) * (1.0f / DD);
    float o = c * rsqrtf(v + 1e-5f) * g[lane] + beta[lane];
    xout[row * DD + lane] = fmaxf(o, 0.0f) + xv;
}

__global__ __launch_bounds__(256) void rel_finish(
    const int* __restrict__ bt, const float* __restrict__ xrel,
    float* __restrict__ query)
{
    int i = threadIdx.x;  // 0..255 = B*D
    int b = i / DD, d = i - b * DD;
    int r0 = bt[(b * KK) * 3 + 2];
    query[b * DD + d] = xrel[(b * RR + r0) * DD + d];
}

// ==================== entity stage ===========================================
__global__ __launch_bounds__(256) void rel_proj(
    const float* __restrict__ rel_repr,
    const float* __restrict__ W1, const float* __restrict__ b1,
    const float* __restrict__ W2, const float* __restrict__ b2,
    float* __restrict__ rel_buf)
{
    int row = (blockIdx.x * 256 + threadIdx.x) >> 6;  // 0..B*R-1
    int lane = threadIdx.x & 63;
    if (row >= BB * RR) return;
    const float* xr = &rel_repr[row * DD];
    float h = b1[lane];
#pragma unroll 8
    for (int k = 0; k < DD; ++k) h += xr[k] * W1[k * DD + lane];
    h = fmaxf(h, 0.0f);
    float o = b2[lane];
#pragma unroll 8
    for (int k = 0; k < DD; ++k) o += __shfl(h, k, 64) * W2[k * DD + lane];
    rel_buf[row * DD + lane] = o;
}

// ---------- layer-0 fast path ----------
__global__ __launch_bounds__(256) void l0_scan(
    const int* __restrict__ edge_index, const int* __restrict__ edge_type,
    const int* __restrict__ bt, int* __restrict__ fixlist, int* __restrict__ cnt)
{
    int e = blockIdx.x * 256 + threadIdx.x;
    if (e < BB) {
        int h0 = bt[e * KK * 3];
        int pos = atomicAdd(&cnt[e], 1);
        if (pos < FCAP) fixlist[e * FCAP + pos] = h0 | (int)(0xFFFFu << 16);
    }
    if (e >= EE) return;
    int s = edge_index[e];
    int d = edge_index[EE + e];
    int t = edge_type[e];
#pragma unroll
    for (int b = 0; b < BB; ++b) {
        int h0 = bt[b * KK * 3];
        if (s == h0) {
            int pos = atomicAdd(&cnt[b], 1);
            if (pos < FCAP) fixlist[b * FCAP + pos] = d | (t << 16);
        }
    }
}

__global__ __launch_bounds__(256) void l0_broadcast(
    const float* __restrict__ b0, const float* __restrict__ g0,
    const float* __restrict__ be0, float* __restrict__ x,
    unsigned short* __restrict__ x_bf)
{
    int lane = threadIdx.x & 63;
    float bv = b0[lane];
    float m = wsum64(bv) * (1.0f / DD);
    float c = bv - m;
    float v = wsum64(c * c) * (1.0f / DD);
    float d = fmaxf(c * rsqrtf(v + 1e-5f) * g0[lane] + be0[lane], 0.0f);
    unsigned short dbf = f2bf_rne(d);
    int gw = blockIdx.x * 4 + (threadIdx.x >> 6);
    int nw = gridDim.x * 4;
    for (int row = gw; row < BB * NN; row += nw) {
        x[(size_t)row * DD + lane] = d;
        x_bf[(size_t)row * DD + lane] = dbf;
    }
}

__global__ __launch_bounds__(256) void l0_fix(
    const int* __restrict__ bt, const int* __restrict__ fixlist,
    const int* __restrict__ cnt, const float* __restrict__ query,
    const float* __restrict__ rel_buf,
    const float* __restrict__ W0, const float* __restrict__ b0,
    const float* __restrict__ g0, const float* __restrict__ be0,
    float* __restrict__ x, unsigned short* __restrict__ x_bf)
{
    int gidx = blockIdx.x * 4 + (threadIdx.x >> 6);  // 0..BB*FCAP-1
    int lane = threadIdx.x & 63;
    int b = gidx / FCAP, i = gidx - b * FCAP;
    int nc = min(cnt[b], FCAP);
    if (i >= nc) return;
    unsigned ent = (unsigned)fixlist[b * FCAP + i];
    int v = (int)(ent & 0xFFFFu);
    int h0 = bt[b * KK * 3];
    float q = query[b * DD + lane];
    float agg = (v == h0) ? q : 0.0f;
    for (int j = 0; j < nc; ++j) {
        unsigned ej = (unsigned)fixlist[b * FCAP + j];
        if ((int)(ej & 0xFFFFu) == v) {
            unsigned et = ej >> 16;
            if (et != 0xFFFFu)
                agg += q * rel_buf[(b * RR + (int)et) * DD + lane];
        }
    }
    float xr = (v == h0) ? q : 0.0f;
    float acc = b0[lane];
#pragma unroll 8
    for (int k = 0; k < DD; ++k) {
        acc += __shfl(xr, k, 64) * W0[k * DD + lane];
        acc += __shfl(agg, k, 64) * W0[(DD + k) * DD + lane];
    }
    float m = wsum64(acc) * (1.0f / DD);
    float c = acc - m;
    float vv = wsum64(c * c) * (1.0f / DD);
    float o = c * rsqrtf(vv + 1e-5f) * g0[lane] + be0[lane];
    float res = fmaxf(o, 0.0f) + xr;
    x[((size_t)b * NN + v) * DD + lane] = res;
    x_bf[((size_t)b * NN + v) * DD + lane] = f2bf_rne(res);
}

// ---------- layers 1..3 ----------
// gather for all 4 batches per wave, bf16 x source, bf16 agg output
__global__ __launch_bounds__(256) void gather_agg4(
    const int* __restrict__ rowptr, const int* __restrict__ pack,
    const int* __restrict__ bt,
    const unsigned short* __restrict__ x_bf, const float* __restrict__ rel_buf,
    const float* __restrict__ query, unsigned short* __restrict__ agg_bf)
{
    int v = blockIdx.x * 4 + (int)(threadIdx.x >> 6);
    int lane = threadIdx.x & 63;
    if (v >= NN) return;
    int beg = rowptr[v], end = rowptr[v + 1];
    const size_t XS = (size_t)NN * DD;   // batch stride in x/agg
    const int RS = RR * DD;              // batch stride in rel_buf
    float a0 = 0.0f, a1 = 0.0f, a2 = 0.0f, a3 = 0.0f;
    for (int j = beg; j < end; ++j) {
        int p = pack[j];
        const unsigned short* xs = x_bf + (size_t)(p & 0xFFFF) * DD + lane;
        const float* rp = rel_buf + (p >> 16) * DD + lane;
        a0 += bf2f(xs[0])      * rp[0];
        a1 += bf2f(xs[XS])     * rp[RS];
        a2 += bf2f(xs[2 * XS]) * rp[2 * RS];
        a3 += bf2f(xs[3 * XS]) * rp[3 * RS];
    }
    float av[4] = {a0, a1, a2, a3};
#pragma unroll
    for (int b = 0; b < BB; ++b) {
        int h0 = bt[b * KK * 3];
        float a = av[b] + ((v == h0) ? query[b * DD + lane] : 0.0f);
        agg_bf[(size_t)b * XS + (size_t)v * DD + lane] = f2bf_rne(a);
    }
}

// ---- pack W (layers 1..3) into bf16 B-fragments for mfma_f32_16x16x32_bf16 --
__global__ __launch_bounds__(64) void wfrag_build(
    const float* __restrict__ entW, unsigned short* __restrict__ wbf)
{
    int blk = blockIdx.x;            // li*16 + t*4 + s
    int li = blk >> 4;
    int t = (blk >> 2) & 3, s = blk & 3;
    int lane = threadIdx.x;
    const float* W = entW + (li + 1) * 2 * DD * DD;
    unsigned short* dst = wbf + ((size_t)blk * 64 + lane) * 8;
#pragma unroll
    for (int j = 0; j < 8; ++j) {
        int k = s * 32 + (lane >> 4) * 8 + j;
        int n = t * 16 + (lane & 15);
        dst[j] = f2bf_rne(W[k * DD + n]);
    }
}

// dense via MFMA: 1 wave = 16 rows x 64 cols, K=128 (x||agg), W in registers.
// A-fragments load directly from bf16 mirrors (no conversion).
__global__ __launch_bounds__(256) void ent_dense6(
    const unsigned short* __restrict__ wfrag,
    const float* __restrict__ bias, const float* __restrict__ g,
    const float* __restrict__ beta,
    float* __restrict__ x, unsigned short* __restrict__ x_bf,
    const unsigned short* __restrict__ agg_bf)
{
    int lane = threadIdx.x & 63;
    int gw = blockIdx.x * 4 + (int)(threadIdx.x >> 6);
    int base = gw * 16;
    if (base >= BB * NN) return;

    s16x8 bfr[4][4];
#pragma unroll
    for (int t = 0; t < 4; ++t)
#pragma unroll
        for (int s = 0; s < 4; ++s)
            bfr[s][t] = *(const s16x8*)&wfrag[((size_t)(t * 4 + s) * 64 + lane) * 8];

    f32x4 acc[4] = {f32x4{0,0,0,0}, f32x4{0,0,0,0}, f32x4{0,0,0,0}, f32x4{0,0,0,0}};
    const size_t arow = (size_t)(base + (lane & 15)) * DD;
    const int koff = (lane >> 4) * 8;
#pragma unroll
    for (int s = 0; s < 4; ++s) {
        const unsigned short* src = (s < 2) ? (x_bf + arow + s * 32 + koff)
                                            : (agg_bf + arow + (s - 2) * 32 + koff);
        s16x8 a = *(const s16x8*)src;
#pragma unroll
        for (int t = 0; t < 4; ++t)
            acc[t] = __builtin_amdgcn_mfma_f32_16x16x32_bf16(a, bfr[s][t], acc[t], 0, 0, 0);
    }

    float bia[4], gt[4], bet[4];
#pragma unroll
    for (int t = 0; t < 4; ++t) {
        int col = (lane & 15) + 16 * t;
        bia[t] = bias[col]; gt[t] = g[col]; bet[t] = beta[col];
    }
#pragma unroll
    for (int r = 0; r < 4; ++r) {
        float v0 = acc[0][r] + bia[0];
        float v1 = acc[1][r] + bia[1];
        float v2 = acc[2][r] + bia[2];
        float v3 = acc[3][r] + bia[3];
        float sum = v0 + v1 + v2 + v3;
#pragma unroll
        for (int off = 1; off < 16; off <<= 1) sum += __shfl_xor(sum, off, 64);
        float m = sum * (1.0f / DD);
        float c0 = v0 - m, c1 = v1 - m, c2 = v2 - m, c3 = v3 - m;
        float q = c0 * c0 + c1 * c1 + c2 * c2 + c3 * c3;
#pragma unroll
        for (int off = 1; off < 16; off <<= 1) q += __shfl_xor(q, off, 64);
        float inv = rsqrtf(q * (1.0f / DD) + 1e-5f);
        size_t row = (size_t)(base + (lane >> 4) * 4 + r) * DD;
        float cs[4] = {c0, c1, c2, c3};
#pragma unroll
        for (int t = 0; t < 4; ++t) {
            int col = (lane & 15) + 16 * t;
            float xo = x[row + col];
            float o = cs[t] * inv * gt[t] + bet[t];
            float res = fmaxf(o, 0.0f) + xo;
            x[row + col] = res;
            x_bf[row + col] = f2bf_rne(res);
        }
    }
}

// ==================== readout ================================================
__global__ __launch_bounds__(128) void readout(
    const int* __restrict__ bt, const float* __restrict__ x,
    const float* __restrict__ query,
    const float* __restrict__ W1, const float* __restrict__ b1,
    const float* __restrict__ W2, const float* __restrict__ b2,
    float* __restrict__ out)
{
    int b = blockIdx.x / KK, k = blockIdx.x - b * KK;
    int t = bt[(b * KK + k) * 3 + 1];
    __shared__ float feat[2 * DD];
    __shared__ float red[2 * DD];
    int j = threadIdx.x;
    if (j < DD) feat[j] = x[((size_t)b * NN + t) * DD + j];
    else        feat[j] = query[b * DD + (j - DD)];
    __syncthreads();
    float h = b1[j];
#pragma unroll 8
    for (int i = 0; i < 2 * DD; ++i) h += feat[i] * W1[i * 2 * DD + j];
    h = fmaxf(h, 0.0f);
    red[j] = h * W2[j];
    __syncthreads();
    for (int s = 64; s > 0; s >>= 1) {
        if (j < s) red[j] += red[j + s];
        __syncthreads();
    }
    if (j == 0) out[blockIdx.x] = red[0] + b2[0];
}

extern "C" void kernel_launch(void* const* d_in, const int* in_sizes, int n_in,
                              void* d_out, int out_size, void* d_ws, size_t ws_size,
                              hipStream_t stream) {
    const int*   edge_index     = (const int*)d_in[0];
    const int*   edge_type      = (const int*)d_in[1];
    const int*   rel_edge_index = (const int*)d_in[2];
    const int*   rel_edge_type  = (const int*)d_in[3];
    const int*   batch_triples  = (const int*)d_in[4];
    const float* rel_emb        = (const float*)d_in[5];
    const float* rel_W          = (const float*)d_in[6];
    const float* rel_b          = (const float*)d_in[7];
    const float* rel_g          = (const float*)d_in[8];
    const float* rel_beta       = (const float*)d_in[9];
    const float* proj_W1        = (const float*)d_in[10];
    const float* proj_b1        = (const float*)d_in[11];
    const float* proj_W2        = (const float*)d_in[12];
    const float* proj_b2        = (const float*)d_in[13];
    const float* ent_W          = (const float*)d_in[14];
    const float* ent_b          = (const float*)d_in[15];
    const float* ent_g          = (const float*)d_in[16];
    const float* ent_beta       = (const float*)d_in[17];
    const float* mlp_W1         = (const float*)d_in[18];
    const float* mlp_b1         = (const float*)d_in[19];
    const float* mlp_W2         = (const float*)d_in[20];
    const float* mlp_b2         = (const float*)d_in[21];

    float* ws = (float*)d_ws;
    float* x_ent    = ws;                                   // B*N*D f32
    float* xrel0    = x_ent    + (size_t)BB * NN * DD;      // B*R*D
    float* xrel1    = xrel0    + BB * RR * DD;              // B*R*D
    float* rel_buf  = xrel1    + BB * RR * DD;              // B*R*D
    float* query    = rel_buf  + BB * RR * DD;              // B*D
    int*   deg      = (int*)(query + BB * DD);              // N
    int*   rowptr   = deg + NN;                             // N+1
    int*   cursor   = rowptr + NN + 1;                      // N
    int*   pack     = cursor + NN;                          // E
    int*   fixlist  = pack + EE;                            // BB*FCAP
    int*   fixcnt   = fixlist + BB * FCAP;                  // BB
    int*   bsum     = fixcnt + BB;                          // NSB (pad 256)
    int*   boff     = bsum + 256;                           // NSB (pad 256)
    int*   rptrR    = boff + 256;                           // RR+1 (pad 66)
    int*   rpackR   = rptrR + 66;                           // ERE
    uintptr_t wp = (uintptr_t)(rpackR + ERE);
    wp = (wp + 15) & ~(uintptr_t)15;
    unsigned short* wbf    = (unsigned short*)wp;           // 3*16*64*8
    unsigned short* x_bf   = wbf + 3 * 16 * 64 * 8;         // B*N*D bf16
    unsigned short* agg_bf = x_bf + (size_t)BB * NN * DD;   // B*N*D bf16

    // ---- CSR build (multi-block scan) + rel CSR + W fragment pack ----
    hipMemsetAsync(deg, 0, sizeof(int) * NN, stream);
    hipMemsetAsync(fixcnt, 0, sizeof(int) * BB, stream);
    csr_hist<<<(EE + 255) / 256, 256, 0, stream>>>(edge_index, deg);
    scan_a<<<NSB, 256, 0, stream>>>(deg, bsum);
    scan_b<<<1, 256, 0, stream>>>(bsum, boff, rowptr);
    scan_c<<<NSB, 256, 0, stream>>>(deg, boff, rowptr, cursor);
    csr_fill<<<(EE + 255) / 256, 256, 0, stream>>>(edge_index, edge_type, cursor, pack);
    rel_csr<<<1, 256, 0, stream>>>(rel_edge_index, rel_edge_type, rptrR, rpackR);
    wfrag_build<<<48, 64, 0, stream>>>(ent_W, wbf);

    // ---- relation stage: fused gather+dense per layer, ping-pong ----
    rel_init<<<(BB * RR * DD + 255) / 256, 256, 0, stream>>>(batch_triples, xrel0);
    for (int l = 0; l < LL; ++l) {
        const float* xin = (l & 1) ? xrel1 : xrel0;
        float* xout = (l & 1) ? xrel0 : xrel1;
        rel_layer<<<BB * RR / 4, 256, 0, stream>>>(
            rptrR, rpackR, batch_triples, rel_emb + l * RT * DD,
            rel_W + l * 2 * DD * DD, rel_b + l * DD,
            rel_g + l * DD, rel_beta + l * DD, xin, xout);
    }
    float* rel_repr = xrel0;  // LL=4 even -> final in xrel0
    rel_finish<<<1, 256, 0, stream>>>(batch_triples, rel_repr, query);

    // ---- entity stage: layer 0 fast path ----
    rel_proj<<<(BB * RR * 64) / 256, 256, 0, stream>>>(
        rel_repr, proj_W1, proj_b1, proj_W2, proj_b2, rel_buf);
    l0_scan<<<(EE + 255) / 256, 256, 0, stream>>>(
        edge_index, edge_type, batch_triples, fixlist, fixcnt);
    l0_broadcast<<<1024, 256, 0, stream>>>(ent_b, ent_g, ent_beta, x_ent, x_bf);
    l0_fix<<<(BB * FCAP) / 4, 256, 0, stream>>>(
        batch_triples, fixlist, fixcnt, query, rel_buf,
        ent_W, ent_b, ent_g, ent_beta, x_ent, x_bf);

    // ---- entity stage: layers 1..3 (bf16 gather4 + MFMA dense) ----
    for (int l = 1; l < LL; ++l) {
        rel_proj<<<(BB * RR * 64) / 256, 256, 0, stream>>>(
            rel_repr, proj_W1 + l * DD * DD, proj_b1 + l * DD,
            proj_W2 + l * DD * DD, proj_b2 + l * DD, rel_buf);
        gather_agg4<<<(NN + 3) / 4, 256, 0, stream>>>(
            rowptr, pack, batch_triples, x_bf, rel_buf, query, agg_bf);
        ent_dense6<<<(BB * NN / 16 + 3) / 4, 256, 0, stream>>>(
            wbf + (size_t)(l - 1) * 16 * 64 * 8,
            ent_b + l * DD, ent_g + l * DD, ent_beta + l * DD,
            x_ent, x_bf, agg_bf);
    }

    readout<<<BB * KK, 2 * DD, 0, stream>>>(batch_triples, x_ent, query,
                                            mlp_W1, mlp_b1, mlp_W2, mlp_b2,
                                            (float*)d_out);
}

// Round 10
// 384.803 us; speedup vs baseline: 4.9576x; 1.1168x over previous
//
#include <hip/hip_runtime.h>
#include <hip/hip_bf16.h>

#define BB 4
#define KK 16
#define NN 50000
#define EE 300000
#define RR 64
#define ERE 2048
#define RT 4
#define DD 64
#define LL 4
#define FCAP 256
#define NSB 196  // (NN+255)/256

typedef short s16x8 __attribute__((ext_vector_type(8)));
typedef float f32x4 __attribute__((ext_vector_type(4)));

__device__ __forceinline__ float wsum64(float v) {
#pragma unroll
    for (int off = 32; off > 0; off >>= 1) v += __shfl_xor(v, off, 64);
    return v;
}

__device__ __forceinline__ unsigned short f2bf_rne(float f) {
    unsigned u = __builtin_bit_cast(unsigned, f);
    return (unsigned short)((u + 0x7FFFu + ((u >> 16) & 1u)) >> 16);
}

__device__ __forceinline__ float bf2f(unsigned short h) {
    unsigned u = ((unsigned)h) << 16;
    return __builtin_bit_cast(float, u);
}

// ==================== fused edge pass: dst histogram + layer-0 fixlist =======
__global__ __launch_bounds__(256) void edge_scan(
    const int* __restrict__ edge_index, const int* __restrict__ edge_type,
    const int* __restrict__ bt, int* __restrict__ deg,
    int* __restrict__ fixlist, int* __restrict__ cnt)
{
    int e = blockIdx.x * 256 + threadIdx.x;
    if (e < BB) {
        int h0 = bt[e * KK * 3];
        int pos = atomicAdd(&cnt[e], 1);
        if (pos < FCAP) fixlist[e * FCAP + pos] = h0 | (int)(0xFFFFu << 16);
    }
    if (e >= EE) return;
    int s = edge_index[e];
    int d = edge_index[EE + e];
    int t = edge_type[e];
    atomicAdd(&deg[d], 1);
#pragma unroll
    for (int b = 0; b < BB; ++b) {
        int h0 = bt[b * KK * 3];
        if (s == h0) {
            int pos = atomicAdd(&cnt[b], 1);
            if (pos < FCAP) fixlist[b * FCAP + pos] = d | (t << 16);
        }
    }
}

// ==================== scan pipeline ==========================================
__global__ __launch_bounds__(256) void scan_a(
    const int* __restrict__ deg, int* __restrict__ bsum)
{
    int i = blockIdx.x * 256 + threadIdx.x;
    int v = (i < NN) ? deg[i] : 0;
    int s = v;
#pragma unroll
    for (int off = 32; off > 0; off >>= 1) s += __shfl_xor(s, off, 64);
    __shared__ int ls[4];
    if ((threadIdx.x & 63) == 0) ls[threadIdx.x >> 6] = s;
    __syncthreads();
    if (threadIdx.x == 0) bsum[blockIdx.x] = ls[0] + ls[1] + ls[2] + ls[3];
}

// fused: block 0 = scan_b; block 1 = rel graph CSR; blocks 2..49 = wfrag pack
__global__ __launch_bounds__(256) void setup_small(
    const int* __restrict__ bsum, int* __restrict__ boff, int* __restrict__ rowptr,
    const int* __restrict__ rel_edge_index, const int* __restrict__ rel_edge_type,
    int* __restrict__ rptr, int* __restrict__ rpack,
    const float* __restrict__ entW, unsigned short* __restrict__ wbf)
{
    int t = threadIdx.x;
    if (blockIdx.x == 0) {
        __shared__ int tmp[256];
        int v = (t < NSB) ? bsum[t] : 0;
        tmp[t] = v;
        __syncthreads();
        for (int off = 1; off < 256; off <<= 1) {
            int u = (t >= off) ? tmp[t - off] : 0;
            __syncthreads();
            tmp[t] += u;
            __syncthreads();
        }
        if (t < NSB) boff[t] = tmp[t] - v;
        if (t == 0) rowptr[NN] = EE;
    } else if (blockIdx.x == 1) {
        __shared__ int hdeg[RR];
        __shared__ int hcur[RR];
        if (t < RR) hdeg[t] = 0;
        __syncthreads();
        for (int e = t; e < ERE; e += 256) atomicAdd(&hdeg[rel_edge_index[ERE + e]], 1);
        __syncthreads();
        if (t == 0) {
            int run = 0;
            for (int r = 0; r < RR; ++r) { hcur[r] = run; rptr[r] = run; run += hdeg[r]; }
            rptr[RR] = run;
        }
        __syncthreads();
        for (int e = t; e < ERE; e += 256) {
            int s = rel_edge_index[e];
            int d = rel_edge_index[ERE + e];
            int ty = rel_edge_type[e];
            int pos = atomicAdd(&hcur[d], 1);
            rpack[pos] = s | (ty << 16);
        }
    } else {
        if (t >= 64) return;
        int blk = blockIdx.x - 2;        // li*16 + tt*4 + s
        int li = blk >> 4;
        int tt = (blk >> 2) & 3, s = blk & 3;
        const float* W = entW + (li + 1) * 2 * DD * DD;
        unsigned short* dst = wbf + ((size_t)blk * 64 + t) * 8;
#pragma unroll
        for (int j = 0; j < 8; ++j) {
            int k = s * 32 + (t >> 4) * 8 + j;
            int n = tt * 16 + (t & 15);
            dst[j] = f2bf_rne(W[k * DD + n]);
        }
    }
}

__global__ __launch_bounds__(256) void scan_c(
    const int* __restrict__ deg, const int* __restrict__ boff,
    int* __restrict__ rowptr, int* __restrict__ cursor)
{
    __shared__ int tmp[256];
    int t = threadIdx.x;
    int i = blockIdx.x * 256 + t;
    int v = (i < NN) ? deg[i] : 0;
    tmp[t] = v;
    __syncthreads();
    for (int off = 1; off < 256; off <<= 1) {
        int u = (t >= off) ? tmp[t - off] : 0;
        __syncthreads();
        tmp[t] += u;
        __syncthreads();
    }
    if (i < NN) {
        int excl = tmp[t] - v + boff[blockIdx.x];
        rowptr[i] = excl;
        cursor[i] = excl;
    }
}

__global__ __launch_bounds__(256) void csr_fill(
    const int* __restrict__ edge_index, const int* __restrict__ edge_type,
    int* __restrict__ cursor, int* __restrict__ pack)
{
    int e = blockIdx.x * 256 + threadIdx.x;
    if (e >= EE) return;
    int s = edge_index[e];
    int d = edge_index[EE + e];
    int t = edge_type[e];
    int pos = atomicAdd(&cursor[d], 1);
    pack[pos] = s | (t << 16);  // src < 2^16, et < 64
}

// ==================== relation stage =========================================
__global__ __launch_bounds__(256) void rel_init(
    const int* __restrict__ bt, float* __restrict__ xrel)
{
    int i = blockIdx.x * 256 + threadIdx.x;
    if (i >= BB * RR * DD) return;
    int b = i / (RR * DD);
    int r = (i % (RR * DD)) / DD;
    int r0 = bt[(b * KK) * 3 + 2];
    xrel[i] = (r == r0) ? 1.0f : 0.0f;
}

__global__ __launch_bounds__(256) void rel_layer(
    const int* __restrict__ rptr, const int* __restrict__ rpack,
    const int* __restrict__ bt, const float* __restrict__ emb,
    const float* __restrict__ W, const float* __restrict__ bias,
    const float* __restrict__ g, const float* __restrict__ beta,
    const float* __restrict__ xin, float* __restrict__ xout)
{
    int row = blockIdx.x * 4 + (int)(threadIdx.x >> 6);  // 0..BB*RR-1
    int lane = threadIdx.x & 63;
    int b = row >> 6, r = row & 63;
    int r0 = bt[(b * KK) * 3 + 2];
    int beg = rptr[r], end = rptr[r + 1];
    const float* xb = xin + b * RR * DD;
    float av = (r == r0) ? 1.0f : 0.0f;
    for (int j = beg; j < end; ++j) {
        int p = rpack[j];
        av += xb[(p & 0xFFFF) * DD + lane] * emb[(p >> 16) * DD + lane];
    }
    float xv = xin[row * DD + lane];
    float acc = bias[lane];
#pragma unroll 8
    for (int k = 0; k < DD; ++k) {
        acc += __shfl(xv, k, 64) * W[k * DD + lane];
        acc += __shfl(av, k, 64) * W[(DD + k) * DD + lane];
    }
    float m = wsum64(acc) * (1.0f / DD);
    float c = acc - m;
    float v = wsum64(c * c) * (1.0f / DD);
    float o = c * rsqrtf(v + 1e-5f) * g[lane] + beta[lane];
    xout[row * DD + lane] = fmaxf(o, 0.0f) + xv;
}

// all-4-layer projection + query extraction (block 0)
__global__ __launch_bounds__(256) void rel_projq(
    const float* __restrict__ rel_repr, const int* __restrict__ bt,
    const float* __restrict__ W1, const float* __restrict__ b1,
    const float* __restrict__ W2, const float* __restrict__ b2,
    float* __restrict__ rel_buf4, float* __restrict__ query)
{
    int grow = blockIdx.x * 4 + (int)(threadIdx.x >> 6);  // 0..4*B*R-1
    int lane = threadIdx.x & 63;
    int l = grow / (BB * RR);
    int row = grow - l * (BB * RR);
    const float* xr = &rel_repr[row * DD];
    const float* w1 = W1 + l * DD * DD;
    const float* w2 = W2 + l * DD * DD;
    float h = b1[l * DD + lane];
#pragma unroll 8
    for (int k = 0; k < DD; ++k) h += xr[k] * w1[k * DD + lane];
    h = fmaxf(h, 0.0f);
    float o = b2[l * DD + lane];
#pragma unroll 8
    for (int k = 0; k < DD; ++k) o += __shfl(h, k, 64) * w2[k * DD + lane];
    rel_buf4[grow * DD + lane] = o;
    if (blockIdx.x == 0) {
        int i = threadIdx.x;  // 0..255 = B*D
        int b = i / DD, d = i - b * DD;
        int r0 = bt[(b * KK) * 3 + 2];
        query[b * DD + d] = rel_repr[(b * RR + r0) * DD + d];
    }
}

// ==================== entity stage ===========================================
// x f32: [b][v][d]. bf16 mirrors interleaved: [v][b][d] (512 B per vertex).
__global__ __launch_bounds__(256) void l0_broadcast(
    const float* __restrict__ b0, const float* __restrict__ g0,
    const float* __restrict__ be0, float* __restrict__ x,
    unsigned short* __restrict__ x_bfi)
{
    int lane = threadIdx.x & 63;
    float bv = b0[lane];
    float m = wsum64(bv) * (1.0f / DD);
    float c = bv - m;
    float v = wsum64(c * c) * (1.0f / DD);
    float d = fmaxf(c * rsqrtf(v + 1e-5f) * g0[lane] + be0[lane], 0.0f);
    unsigned short dbf = f2bf_rne(d);
    int gw = blockIdx.x * 4 + (threadIdx.x >> 6);
    int nw = gridDim.x * 4;
    // value is row-uniform: flat order vs interleaved order both covered
    for (int row = gw; row < BB * NN; row += nw) {
        x[(size_t)row * DD + lane] = d;
        x_bfi[(size_t)row * DD + lane] = dbf;
    }
}

__global__ __launch_bounds__(256) void l0_fix(
    const int* __restrict__ bt, const int* __restrict__ fixlist,
    const int* __restrict__ cnt, const float* __restrict__ query,
    const float* __restrict__ rel_buf,
    const float* __restrict__ W0, const float* __restrict__ b0,
    const float* __restrict__ g0, const float* __restrict__ be0,
    float* __restrict__ x, unsigned short* __restrict__ x_bfi)
{
    int gidx = blockIdx.x * 4 + (threadIdx.x >> 6);  // 0..BB*FCAP-1
    int lane = threadIdx.x & 63;
    int b = gidx / FCAP, i = gidx - b * FCAP;
    int nc = min(cnt[b], FCAP);
    if (i >= nc) return;
    unsigned ent = (unsigned)fixlist[b * FCAP + i];
    int v = (int)(ent & 0xFFFFu);
    int h0 = bt[b * KK * 3];
    float q = query[b * DD + lane];
    float agg = (v == h0) ? q : 0.0f;
    for (int j = 0; j < nc; ++j) {
        unsigned ej = (unsigned)fixlist[b * FCAP + j];
        if ((int)(ej & 0xFFFFu) == v) {
            unsigned et = ej >> 16;
            if (et != 0xFFFFu)
                agg += q * rel_buf[(b * RR + (int)et) * DD + lane];
        }
    }
    float xr = (v == h0) ? q : 0.0f;
    float acc = b0[lane];
#pragma unroll 8
    for (int k = 0; k < DD; ++k) {
        acc += __shfl(xr, k, 64) * W0[k * DD + lane];
        acc += __shfl(agg, k, 64) * W0[(DD + k) * DD + lane];
    }
    float m = wsum64(acc) * (1.0f / DD);
    float c = acc - m;
    float vv = wsum64(c * c) * (1.0f / DD);
    float o = c * rsqrtf(vv + 1e-5f) * g0[lane] + be0[lane];
    float res = fmaxf(o, 0.0f) + xr;
    x[((size_t)b * NN + v) * DD + lane] = res;
    x_bfi[((size_t)v * BB + b) * DD + lane] = f2bf_rne(res);
}

// gather, interleaved: per edge ONE contiguous 512 B region (all 4 batches)
__global__ __launch_bounds__(256) void gather_agg4(
    const int* __restrict__ rowptr, const int* __restrict__ pack,
    const int* __restrict__ bt,
    const unsigned short* __restrict__ x_bfi, const float* __restrict__ rel_buf,
    const float* __restrict__ query, unsigned short* __restrict__ agg_bfi)
{
    int v = blockIdx.x * 4 + (int)(threadIdx.x >> 6);
    int lane = threadIdx.x & 63;
    if (v >= NN) return;
    int beg = rowptr[v], end = rowptr[v + 1];
    const int RS = RR * DD;              // batch stride in rel_buf
    float a0 = 0.0f, a1 = 0.0f, a2 = 0.0f, a3 = 0.0f;
    for (int j = beg; j < end; ++j) {
        int p = pack[j];
        const unsigned short* xs = x_bfi + (size_t)(p & 0xFFFF) * (BB * DD) + lane;
        const float* rp = rel_buf + (p >> 16) * DD + lane;
        a0 += bf2f(xs[0])      * rp[0];
        a1 += bf2f(xs[DD])     * rp[RS];
        a2 += bf2f(xs[2 * DD]) * rp[2 * RS];
        a3 += bf2f(xs[3 * DD]) * rp[3 * RS];
    }
    float av[4] = {a0, a1, a2, a3};
#pragma unroll
    for (int b = 0; b < BB; ++b) {
        int h0 = bt[b * KK * 3];
        float a = av[b] + ((v == h0) ? query[b * DD + lane] : 0.0f);
        agg_bfi[((size_t)v * BB + b) * DD + lane] = f2bf_rne(a);
    }
}

// dense via MFMA on interleaved rows rf = v*4+b
__global__ __launch_bounds__(256) void ent_dense6(
    const unsigned short* __restrict__ wfrag,
    const float* __restrict__ bias, const float* __restrict__ g,
    const float* __restrict__ beta,
    float* __restrict__ x, unsigned short* __restrict__ x_bfi,
    const unsigned short* __restrict__ agg_bfi)
{
    int lane = threadIdx.x & 63;
    int gw = blockIdx.x * 4 + (int)(threadIdx.x >> 6);
    int base = gw * 16;
    if (base >= BB * NN) return;

    s16x8 bfr[4][4];
#pragma unroll
    for (int t = 0; t < 4; ++t)
#pragma unroll
        for (int s = 0; s < 4; ++s)
            bfr[s][t] = *(const s16x8*)&wfrag[((size_t)(t * 4 + s) * 64 + lane) * 8];

    f32x4 acc[4] = {f32x4{0,0,0,0}, f32x4{0,0,0,0}, f32x4{0,0,0,0}, f32x4{0,0,0,0}};
    const size_t arow = (size_t)(base + (lane & 15)) * DD;
    const int koff = (lane >> 4) * 8;
#pragma unroll
    for (int s = 0; s < 4; ++s) {
        const unsigned short* src = (s < 2) ? (x_bfi + arow + s * 32 + koff)
                                            : (agg_bfi + arow + (s - 2) * 32 + koff);
        s16x8 a = *(const s16x8*)src;
#pragma unroll
        for (int t = 0; t < 4; ++t)
            acc[t] = __builtin_amdgcn_mfma_f32_16x16x32_bf16(a, bfr[s][t], acc[t], 0, 0, 0);
    }

    float bia[4], gt[4], bet[4];
#pragma unroll
    for (int t = 0; t < 4; ++t) {
        int col = (lane & 15) + 16 * t;
        bia[t] = bias[col]; gt[t] = g[col]; bet[t] = beta[col];
    }
#pragma unroll
    for (int r = 0; r < 4; ++r) {
        float v0 = acc[0][r] + bia[0];
        float v1 = acc[1][r] + bia[1];
        float v2 = acc[2][r] + bia[2];
        float v3 = acc[3][r] + bia[3];
        float sum = v0 + v1 + v2 + v3;
#pragma unroll
        for (int off = 1; off < 16; off <<= 1) sum += __shfl_xor(sum, off, 64);
        float m = sum * (1.0f / DD);
        float c0 = v0 - m, c1 = v1 - m, c2 = v2 - m, c3 = v3 - m;
        float q = c0 * c0 + c1 * c1 + c2 * c2 + c3 * c3;
#pragma unroll
        for (int off = 1; off < 16; off <<= 1) q += __shfl_xor(q, off, 64);
        float inv = rsqrtf(q * (1.0f / DD) + 1e-5f);
        int rf = base + (lane >> 4) * 4 + r;
        int vv2 = rf >> 2, bb2 = rf & 3;
        size_t frow = ((size_t)bb2 * NN + vv2) * DD;
        size_t irow = (size_t)rf * DD;
        float cs[4] = {c0, c1, c2, c3};
#pragma unroll
        for (int t = 0; t < 4; ++t) {
            int col = (lane & 15) + 16 * t;
            float xo = x[frow + col];
            float o = cs[t] * inv * gt[t] + bet[t];
            float res = fmaxf(o, 0.0f) + xo;
            x[frow + col] = res;
            x_bfi[irow + col] = f2bf_rne(res);
        }
    }
}

// ==================== readout ================================================
__global__ __launch_bounds__(128) void readout(
    const int* __restrict__ bt, const float* __restrict__ x,
    const float* __restrict__ query,
    const float* __restrict__ W1, const float* __restrict__ b1,
    const float* __restrict__ W2, const float* __restrict__ b2,
    float* __restrict__ out)
{
    int b = blockIdx.x / KK, k = blockIdx.x - b * KK;
    int t = bt[(b * KK + k) * 3 + 1];
    __shared__ float feat[2 * DD];
    __shared__ float red[2 * DD];
    int j = threadIdx.x;
    if (j < DD) feat[j] = x[((size_t)b * NN + t) * DD + j];
    else        feat[j] = query[b * DD + (j - DD)];
    __syncthreads();
    float h = b1[j];
#pragma unroll 8
    for (int i = 0; i < 2 * DD; ++i) h += feat[i] * W1[i * 2 * DD + j];
    h = fmaxf(h, 0.0f);
    red[j] = h * W2[j];
    __syncthreads();
    for (int s = 64; s > 0; s >>= 1) {
        if (j < s) red[j] += red[j + s];
        __syncthreads();
    }
    if (j == 0) out[blockIdx.x] = red[0] + b2[0];
}

extern "C" void kernel_launch(void* const* d_in, const int* in_sizes, int n_in,
                              void* d_out, int out_size, void* d_ws, size_t ws_size,
                              hipStream_t stream) {
    const int*   edge_index     = (const int*)d_in[0];
    const int*   edge_type      = (const int*)d_in[1];
    const int*   rel_edge_index = (const int*)d_in[2];
    const int*   rel_edge_type  = (const int*)d_in[3];
    const int*   batch_triples  = (const int*)d_in[4];
    const float* rel_emb        = (const float*)d_in[5];
    const float* rel_W          = (const float*)d_in[6];
    const float* rel_b          = (const float*)d_in[7];
    const float* rel_g          = (const float*)d_in[8];
    const float* rel_beta       = (const float*)d_in[9];
    const float* proj_W1        = (const float*)d_in[10];
    const float* proj_b1        = (const float*)d_in[11];
    const float* proj_W2        = (const float*)d_in[12];
    const float* proj_b2        = (const float*)d_in[13];
    const float* ent_W          = (const float*)d_in[14];
    const float* ent_b          = (const float*)d_in[15];
    const float* ent_g          = (const float*)d_in[16];
    const float* ent_beta       = (const float*)d_in[17];
    const float* mlp_W1         = (const float*)d_in[18];
    const float* mlp_b1         = (const float*)d_in[19];
    const float* mlp_W2         = (const float*)d_in[20];
    const float* mlp_b2         = (const float*)d_in[21];

    float* ws = (float*)d_ws;
    float* x_ent    = ws;                                   // B*N*D f32
    float* xrel0    = x_ent    + (size_t)BB * NN * DD;      // B*R*D
    float* xrel1    = xrel0    + BB * RR * DD;              // B*R*D
    float* rel_buf4 = xrel1    + BB * RR * DD;              // 4*B*R*D
    float* query    = rel_buf4 + 4 * BB * RR * DD;          // B*D
    int*   deg      = (int*)(query + BB * DD);              // N
    int*   rowptr   = deg + NN;                             // N+1
    int*   cursor   = rowptr + NN + 1;                      // N
    int*   pack     = cursor + NN;                          // E
    int*   fixlist  = pack + EE;                            // BB*FCAP
    int*   fixcnt   = fixlist + BB * FCAP;                  // BB
    int*   bsum     = fixcnt + BB;                          // NSB (pad 256)
    int*   boff     = bsum + 256;                           // NSB (pad 256)
    int*   rptrR    = boff + 256;                           // RR+1 (pad 66)
    int*   rpackR   = rptrR + 66;                           // ERE
    uintptr_t wp = (uintptr_t)(rpackR + ERE);
    wp = (wp + 15) & ~(uintptr_t)15;
    unsigned short* wbf     = (unsigned short*)wp;          // 3*16*64*8
    unsigned short* x_bfi   = wbf + 3 * 16 * 64 * 8;        // B*N*D bf16 [v][b][d]
    unsigned short* agg_bfi = x_bfi + (size_t)BB * NN * DD; // B*N*D bf16 [v][b][d]

    // ---- CSR build + fixlist + rel CSR + W fragment pack ----
    hipMemsetAsync(deg, 0, sizeof(int) * NN, stream);
    hipMemsetAsync(fixcnt, 0, sizeof(int) * BB, stream);
    edge_scan<<<(EE + 255) / 256, 256, 0, stream>>>(
        edge_index, edge_type, batch_triples, deg, fixlist, fixcnt);
    scan_a<<<NSB, 256, 0, stream>>>(deg, bsum);
    setup_small<<<50, 256, 0, stream>>>(
        bsum, boff, rowptr, rel_edge_index, rel_edge_type, rptrR, rpackR,
        ent_W, wbf);
    scan_c<<<NSB, 256, 0, stream>>>(deg, boff, rowptr, cursor);
    csr_fill<<<(EE + 255) / 256, 256, 0, stream>>>(edge_index, edge_type, cursor, pack);

    // ---- relation stage: fused gather+dense per layer, ping-pong ----
    rel_init<<<(BB * RR * DD + 255) / 256, 256, 0, stream>>>(batch_triples, xrel0);
    for (int l = 0; l < LL; ++l) {
        const float* xin = (l & 1) ? xrel1 : xrel0;
        float* xout = (l & 1) ? xrel0 : xrel1;
        rel_layer<<<BB * RR / 4, 256, 0, stream>>>(
            rptrR, rpackR, batch_triples, rel_emb + l * RT * DD,
            rel_W + l * 2 * DD * DD, rel_b + l * DD,
            rel_g + l * DD, rel_beta + l * DD, xin, xout);
    }
    float* rel_repr = xrel0;  // LL=4 even -> final in xrel0
    rel_projq<<<4 * BB * RR / 4, 256, 0, stream>>>(
        rel_repr, batch_triples, proj_W1, proj_b1, proj_W2, proj_b2,
        rel_buf4, query);

    // ---- entity stage: layer 0 fast path ----
    l0_broadcast<<<1024, 256, 0, stream>>>(ent_b, ent_g, ent_beta, x_ent, x_bfi);
    l0_fix<<<(BB * FCAP) / 4, 256, 0, stream>>>(
        batch_triples, fixlist, fixcnt, query, rel_buf4,
        ent_W, ent_b, ent_g, ent_beta, x_ent, x_bfi);

    // ---- entity stage: layers 1..3 (bf16 gather4 + MFMA dense) ----
    for (int l = 1; l < LL; ++l) {
        gather_agg4<<<(NN + 3) / 4, 256, 0, stream>>>(
            rowptr, pack, batch_triples, x_bfi, rel_buf4 + l * BB * RR * DD,
            query, agg_bfi);
        ent_dense6<<<(BB * NN / 16 + 3) / 4, 256, 0, stream>>>(
            wbf + (size_t)(l - 1) * 16 * 64 * 8,
            ent_b + l * DD, ent_g + l * DD, ent_beta + l * DD,
            x_ent, x_bfi, agg_bfi);
    }

    readout<<<BB * KK, 2 * DD, 0, stream>>>(batch_triples, x_ent, query,
                                            mlp_W1, mlp_b1, mlp_W2, mlp_b2,
                                            (float*)d_out);
}

// Round 11
// 345.926 us; speedup vs baseline: 5.5148x; 1.1124x over previous
//
#include <hip/hip_runtime.h>
#include <hip/hip_bf16.h>

#define BB 4
#define KK 16
#define NN 50000
#define EE 300000
#define RR 64
#define ERE 2048
#define RT 4
#define DD 64
#define LL 4
#define FCAP 256
#define NSB 196  // (NN+255)/256

typedef short s16x8 __attribute__((ext_vector_type(8)));
typedef float f32x4 __attribute__((ext_vector_type(4)));

__device__ __forceinline__ float wsum64(float v) {
#pragma unroll
    for (int off = 32; off > 0; off >>= 1) v += __shfl_xor(v, off, 64);
    return v;
}

__device__ __forceinline__ unsigned short f2bf_rne(float f) {
    unsigned u = __builtin_bit_cast(unsigned, f);
    return (unsigned short)((u + 0x7FFFu + ((u >> 16) & 1u)) >> 16);
}

__device__ __forceinline__ float bf2f(unsigned short h) {
    unsigned u = ((unsigned)h) << 16;
    return __builtin_bit_cast(float, u);
}

// ==================== fused edge pass: dst histogram + layer-0 fixlist =======
__global__ __launch_bounds__(256) void edge_scan(
    const int* __restrict__ edge_index, const int* __restrict__ edge_type,
    const int* __restrict__ bt, int* __restrict__ deg,
    int* __restrict__ fixlist, int* __restrict__ cnt)
{
    int e = blockIdx.x * 256 + threadIdx.x;
    if (e < BB) {
        int h0 = bt[e * KK * 3];
        int pos = atomicAdd(&cnt[e], 1);
        if (pos < FCAP) fixlist[e * FCAP + pos] = h0 | (int)(0xFFFFu << 16);
    }
    if (e >= EE) return;
    int s = edge_index[e];
    int d = edge_index[EE + e];
    int t = edge_type[e];
    atomicAdd(&deg[d], 1);
#pragma unroll
    for (int b = 0; b < BB; ++b) {
        int h0 = bt[b * KK * 3];
        if (s == h0) {
            int pos = atomicAdd(&cnt[b], 1);
            if (pos < FCAP) fixlist[b * FCAP + pos] = d | (t << 16);
        }
    }
}

// ==================== scan pipeline ==========================================
__global__ __launch_bounds__(256) void scan_a(
    const int* __restrict__ deg, int* __restrict__ bsum)
{
    int i = blockIdx.x * 256 + threadIdx.x;
    int v = (i < NN) ? deg[i] : 0;
    int s = v;
#pragma unroll
    for (int off = 32; off > 0; off >>= 1) s += __shfl_xor(s, off, 64);
    __shared__ int ls[4];
    if ((threadIdx.x & 63) == 0) ls[threadIdx.x >> 6] = s;
    __syncthreads();
    if (threadIdx.x == 0) bsum[blockIdx.x] = ls[0] + ls[1] + ls[2] + ls[3];
}

// fused: block 0 = scan_b; block 1 = rel graph CSR; blocks 2..49 = wfrag pack
__global__ __launch_bounds__(256) void setup_small(
    const int* __restrict__ bsum, int* __restrict__ boff, int* __restrict__ rowptr,
    const int* __restrict__ rel_edge_index, const int* __restrict__ rel_edge_type,
    int* __restrict__ rptr, int* __restrict__ rpack,
    const float* __restrict__ entW, unsigned short* __restrict__ wbf)
{
    int t = threadIdx.x;
    if (blockIdx.x == 0) {
        __shared__ int tmp[256];
        int v = (t < NSB) ? bsum[t] : 0;
        tmp[t] = v;
        __syncthreads();
        for (int off = 1; off < 256; off <<= 1) {
            int u = (t >= off) ? tmp[t - off] : 0;
            __syncthreads();
            tmp[t] += u;
            __syncthreads();
        }
        if (t < NSB) boff[t] = tmp[t] - v;
        if (t == 0) rowptr[NN] = EE;
    } else if (blockIdx.x == 1) {
        __shared__ int hdeg[RR];
        __shared__ int hcur[RR];
        if (t < RR) hdeg[t] = 0;
        __syncthreads();
        for (int e = t; e < ERE; e += 256) atomicAdd(&hdeg[rel_edge_index[ERE + e]], 1);
        __syncthreads();
        if (t == 0) {
            int run = 0;
            for (int r = 0; r < RR; ++r) { hcur[r] = run; rptr[r] = run; run += hdeg[r]; }
            rptr[RR] = run;
        }
        __syncthreads();
        for (int e = t; e < ERE; e += 256) {
            int s = rel_edge_index[e];
            int d = rel_edge_index[ERE + e];
            int ty = rel_edge_type[e];
            int pos = atomicAdd(&hcur[d], 1);
            rpack[pos] = s | (ty << 16);
        }
    } else {
        if (t >= 64) return;
        int blk = blockIdx.x - 2;        // li*16 + tt*4 + s
        int li = blk >> 4;
        int tt = (blk >> 2) & 3, s = blk & 3;
        const float* W = entW + (li + 1) * 2 * DD * DD;
        unsigned short* dst = wbf + ((size_t)blk * 64 + t) * 8;
#pragma unroll
        for (int j = 0; j < 8; ++j) {
            int k = s * 32 + (t >> 4) * 8 + j;
            int n = tt * 16 + (t & 15);
            dst[j] = f2bf_rne(W[k * DD + n]);
        }
    }
}

__global__ __launch_bounds__(256) void scan_c(
    const int* __restrict__ deg, const int* __restrict__ boff,
    int* __restrict__ rowptr, int* __restrict__ cursor)
{
    __shared__ int tmp[256];
    int t = threadIdx.x;
    int i = blockIdx.x * 256 + t;
    int v = (i < NN) ? deg[i] : 0;
    tmp[t] = v;
    __syncthreads();
    for (int off = 1; off < 256; off <<= 1) {
        int u = (t >= off) ? tmp[t - off] : 0;
        __syncthreads();
        tmp[t] += u;
        __syncthreads();
    }
    if (i < NN) {
        int excl = tmp[t] - v + boff[blockIdx.x];
        rowptr[i] = excl;
        cursor[i] = excl;
    }
}

__global__ __launch_bounds__(256) void csr_fill(
    const int* __restrict__ edge_index, const int* __restrict__ edge_type,
    int* __restrict__ cursor, int* __restrict__ pack)
{
    int e = blockIdx.x * 256 + threadIdx.x;
    if (e >= EE) return;
    int s = edge_index[e];
    int d = edge_index[EE + e];
    int t = edge_type[e];
    int pos = atomicAdd(&cursor[d], 1);
    pack[pos] = s | (t << 16);  // src < 2^16, et < 64
}

// ==================== relation stage =========================================
__global__ __launch_bounds__(256) void rel_init(
    const int* __restrict__ bt, float* __restrict__ xrel)
{
    int i = blockIdx.x * 256 + threadIdx.x;
    if (i >= BB * RR * DD) return;
    int b = i / (RR * DD);
    int r = (i % (RR * DD)) / DD;
    int r0 = bt[(b * KK) * 3 + 2];
    xrel[i] = (r == r0) ? 1.0f : 0.0f;
}

__global__ __launch_bounds__(256) void rel_layer(
    const int* __restrict__ rptr, const int* __restrict__ rpack,
    const int* __restrict__ bt, const float* __restrict__ emb,
    const float* __restrict__ W, const float* __restrict__ bias,
    const float* __restrict__ g, const float* __restrict__ beta,
    const float* __restrict__ xin, float* __restrict__ xout)
{
    int row = blockIdx.x * 4 + (int)(threadIdx.x >> 6);  // 0..BB*RR-1
    int lane = threadIdx.x & 63;
    int b = row >> 6, r = row & 63;
    int r0 = bt[(b * KK) * 3 + 2];
    int beg = rptr[r], end = rptr[r + 1];
    const float* xb = xin + b * RR * DD;
    float av = (r == r0) ? 1.0f : 0.0f;
    for (int j = beg; j < end; ++j) {
        int p = rpack[j];
        av += xb[(p & 0xFFFF) * DD + lane] * emb[(p >> 16) * DD + lane];
    }
    float xv = xin[row * DD + lane];
    float acc = bias[lane];
#pragma unroll 8
    for (int k = 0; k < DD; ++k) {
        acc += __shfl(xv, k, 64) * W[k * DD + lane];
        acc += __shfl(av, k, 64) * W[(DD + k) * DD + lane];
    }
    float m = wsum64(acc) * (1.0f / DD);
    float c = acc - m;
    float v = wsum64(c * c) * (1.0f / DD);
    float o = c * rsqrtf(v + 1e-5f) * g[lane] + beta[lane];
    xout[row * DD + lane] = fmaxf(o, 0.0f) + xv;
}

// all-4-layer projection + query extraction (block 0)
__global__ __launch_bounds__(256) void rel_projq(
    const float* __restrict__ rel_repr, const int* __restrict__ bt,
    const float* __restrict__ W1, const float* __restrict__ b1,
    const float* __restrict__ W2, const float* __restrict__ b2,
    float* __restrict__ rel_buf4, float* __restrict__ query)
{
    int grow = blockIdx.x * 4 + (int)(threadIdx.x >> 6);  // 0..4*B*R-1
    int lane = threadIdx.x & 63;
    int l = grow / (BB * RR);
    int row = grow - l * (BB * RR);
    const float* xr = &rel_repr[row * DD];
    const float* w1 = W1 + l * DD * DD;
    const float* w2 = W2 + l * DD * DD;
    float h = b1[l * DD + lane];
#pragma unroll 8
    for (int k = 0; k < DD; ++k) h += xr[k] * w1[k * DD + lane];
    h = fmaxf(h, 0.0f);
    float o = b2[l * DD + lane];
#pragma unroll 8
    for (int k = 0; k < DD; ++k) o += __shfl(h, k, 64) * w2[k * DD + lane];
    rel_buf4[grow * DD + lane] = o;
    if (blockIdx.x == 0) {
        int i = threadIdx.x;  // 0..255 = B*D
        int b = i / DD, d = i - b * DD;
        int r0 = bt[(b * KK) * 3 + 2];
        query[b * DD + d] = rel_repr[(b * RR + r0) * DD + d];
    }
}

// ==================== entity stage ===========================================
// x f32: [b][v][d]. bf16 mirrors interleaved: [v][b][d] (512 B per vertex).
__global__ __launch_bounds__(256) void l0_broadcast(
    const float* __restrict__ b0, const float* __restrict__ g0,
    const float* __restrict__ be0, float* __restrict__ x,
    unsigned short* __restrict__ x_bfi)
{
    int lane = threadIdx.x & 63;
    float bv = b0[lane];
    float m = wsum64(bv) * (1.0f / DD);
    float c = bv - m;
    float v = wsum64(c * c) * (1.0f / DD);
    float d = fmaxf(c * rsqrtf(v + 1e-5f) * g0[lane] + be0[lane], 0.0f);
    unsigned short dbf = f2bf_rne(d);
    int gw = blockIdx.x * 4 + (threadIdx.x >> 6);
    int nw = gridDim.x * 4;
    // value is row-uniform: flat order vs interleaved order both covered
    for (int row = gw; row < BB * NN; row += nw) {
        x[(size_t)row * DD + lane] = d;
        x_bfi[(size_t)row * DD + lane] = dbf;
    }
}

__global__ __launch_bounds__(256) void l0_fix(
    const int* __restrict__ bt, const int* __restrict__ fixlist,
    const int* __restrict__ cnt, const float* __restrict__ query,
    const float* __restrict__ rel_buf,
    const float* __restrict__ W0, const float* __restrict__ b0,
    const float* __restrict__ g0, const float* __restrict__ be0,
    float* __restrict__ x, unsigned short* __restrict__ x_bfi)
{
    int gidx = blockIdx.x * 4 + (threadIdx.x >> 6);  // 0..BB*FCAP-1
    int lane = threadIdx.x & 63;
    int b = gidx / FCAP, i = gidx - b * FCAP;
    int nc = min(cnt[b], FCAP);
    if (i >= nc) return;
    unsigned ent = (unsigned)fixlist[b * FCAP + i];
    int v = (int)(ent & 0xFFFFu);
    int h0 = bt[b * KK * 3];
    float q = query[b * DD + lane];
    float agg = (v == h0) ? q : 0.0f;
    for (int j = 0; j < nc; ++j) {
        unsigned ej = (unsigned)fixlist[b * FCAP + j];
        if ((int)(ej & 0xFFFFu) == v) {
            unsigned et = ej >> 16;
            if (et != 0xFFFFu)
                agg += q * rel_buf[(b * RR + (int)et) * DD + lane];
        }
    }
    float xr = (v == h0) ? q : 0.0f;
    float acc = b0[lane];
#pragma unroll 8
    for (int k = 0; k < DD; ++k) {
        acc += __shfl(xr, k, 64) * W0[k * DD + lane];
        acc += __shfl(agg, k, 64) * W0[(DD + k) * DD + lane];
    }
    float m = wsum64(acc) * (1.0f / DD);
    float c = acc - m;
    float vv = wsum64(c * c) * (1.0f / DD);
    float o = c * rsqrtf(vv + 1e-5f) * g0[lane] + be0[lane];
    float res = fmaxf(o, 0.0f) + xr;
    x[((size_t)b * NN + v) * DD + lane] = res;
    x_bfi[((size_t)v * BB + b) * DD + lane] = f2bf_rne(res);
}

// gather: lane l = batch (l>>4), dims 4*(l&15)..+3. Per edge: ONE dwordx2
// x-load (512 B/wave) + ONE float4 rel-load. Unrolled x2 for MLP.
__global__ __launch_bounds__(256) void gather_agg4(
    const int* __restrict__ rowptr, const int* __restrict__ pack,
    const int* __restrict__ bt,
    const unsigned short* __restrict__ x_bfi, const float* __restrict__ rel_buf,
    const float* __restrict__ query, unsigned short* __restrict__ agg_bfi)
{
    int v = blockIdx.x * 4 + (int)(threadIdx.x >> 6);
    int lane = threadIdx.x & 63;
    if (v >= NN) return;
    const int b  = lane >> 4;         // batch handled by this lane
    const int d0 = (lane & 15) * 4;   // dim base
    int beg = rowptr[v], end = rowptr[v + 1];
    const float* rb = rel_buf + (size_t)b * RR * DD + d0;
    f32x4 acc = {0.0f, 0.0f, 0.0f, 0.0f};
    int j = beg;
    for (; j + 1 < end; j += 2) {
        int p0 = pack[j], p1 = pack[j + 1];
        s16x8 dummy;
        ushort4 xv0 = *(const ushort4*)&x_bfi[((size_t)(p0 & 0xFFFF) * BB + b) * DD + d0];
        ushort4 xv1 = *(const ushort4*)&x_bfi[((size_t)(p1 & 0xFFFF) * BB + b) * DD + d0];
        float4 r0 = *(const float4*)&rb[(size_t)(p0 >> 16) * DD];
        float4 r1 = *(const float4*)&rb[(size_t)(p1 >> 16) * DD];
        acc[0] += bf2f(xv0.x) * r0.x + bf2f(xv1.x) * r1.x;
        acc[1] += bf2f(xv0.y) * r0.y + bf2f(xv1.y) * r1.y;
        acc[2] += bf2f(xv0.z) * r0.z + bf2f(xv1.z) * r1.z;
        acc[3] += bf2f(xv0.w) * r0.w + bf2f(xv1.w) * r1.w;
        (void)dummy;
    }
    if (j < end) {
        int p0 = pack[j];
        ushort4 xv0 = *(const ushort4*)&x_bfi[((size_t)(p0 & 0xFFFF) * BB + b) * DD + d0];
        float4 r0 = *(const float4*)&rb[(size_t)(p0 >> 16) * DD];
        acc[0] += bf2f(xv0.x) * r0.x;
        acc[1] += bf2f(xv0.y) * r0.y;
        acc[2] += bf2f(xv0.z) * r0.z;
        acc[3] += bf2f(xv0.w) * r0.w;
    }
    int h0 = bt[b * KK * 3];
    if (v == h0) {
        float4 q = *(const float4*)&query[b * DD + d0];
        acc[0] += q.x; acc[1] += q.y; acc[2] += q.z; acc[3] += q.w;
    }
    ushort4 outv;
    outv.x = f2bf_rne(acc[0]);
    outv.y = f2bf_rne(acc[1]);
    outv.z = f2bf_rne(acc[2]);
    outv.w = f2bf_rne(acc[3]);
    *(ushort4*)&agg_bfi[((size_t)v * BB + b) * DD + d0] = outv;
}

// dense via MFMA on interleaved rows rf = v*4+b
__global__ __launch_bounds__(256) void ent_dense6(
    const unsigned short* __restrict__ wfrag,
    const float* __restrict__ bias, const float* __restrict__ g,
    const float* __restrict__ beta,
    float* __restrict__ x, unsigned short* __restrict__ x_bfi,
    const unsigned short* __restrict__ agg_bfi)
{
    int lane = threadIdx.x & 63;
    int gw = blockIdx.x * 4 + (int)(threadIdx.x >> 6);
    int base = gw * 16;
    if (base >= BB * NN) return;

    s16x8 bfr[4][4];
#pragma unroll
    for (int t = 0; t < 4; ++t)
#pragma unroll
        for (int s = 0; s < 4; ++s)
            bfr[s][t] = *(const s16x8*)&wfrag[((size_t)(t * 4 + s) * 64 + lane) * 8];

    f32x4 acc[4] = {f32x4{0,0,0,0}, f32x4{0,0,0,0}, f32x4{0,0,0,0}, f32x4{0,0,0,0}};
    const size_t arow = (size_t)(base + (lane & 15)) * DD;
    const int koff = (lane >> 4) * 8;
#pragma unroll
    for (int s = 0; s < 4; ++s) {
        const unsigned short* src = (s < 2) ? (x_bfi + arow + s * 32 + koff)
                                            : (agg_bfi + arow + (s - 2) * 32 + koff);
        s16x8 a = *(const s16x8*)src;
#pragma unroll
        for (int t = 0; t < 4; ++t)
            acc[t] = __builtin_amdgcn_mfma_f32_16x16x32_bf16(a, bfr[s][t], acc[t], 0, 0, 0);
    }

    float bia[4], gt[4], bet[4];
#pragma unroll
    for (int t = 0; t < 4; ++t) {
        int col = (lane & 15) + 16 * t;
        bia[t] = bias[col]; gt[t] = g[col]; bet[t] = beta[col];
    }
#pragma unroll
    for (int r = 0; r < 4; ++r) {
        float v0 = acc[0][r] + bia[0];
        float v1 = acc[1][r] + bia[1];
        float v2 = acc[2][r] + bia[2];
        float v3 = acc[3][r] + bia[3];
        float sum = v0 + v1 + v2 + v3;
#pragma unroll
        for (int off = 1; off < 16; off <<= 1) sum += __shfl_xor(sum, off, 64);
        float m = sum * (1.0f / DD);
        float c0 = v0 - m, c1 = v1 - m, c2 = v2 - m, c3 = v3 - m;
        float q = c0 * c0 + c1 * c1 + c2 * c2 + c3 * c3;
#pragma unroll
        for (int off = 1; off < 16; off <<= 1) q += __shfl_xor(q, off, 64);
        float inv = rsqrtf(q * (1.0f / DD) + 1e-5f);
        int rf = base + (lane >> 4) * 4 + r;
        int vv2 = rf >> 2, bb2 = rf & 3;
        size_t frow = ((size_t)bb2 * NN + vv2) * DD;
        size_t irow = (size_t)rf * DD;
        float cs[4] = {c0, c1, c2, c3};
#pragma unroll
        for (int t = 0; t < 4; ++t) {
            int col = (lane & 15) + 16 * t;
            float xo = x[frow + col];
            float o = cs[t] * inv * gt[t] + bet[t];
            float res = fmaxf(o, 0.0f) + xo;
            x[frow + col] = res;
            x_bfi[irow + col] = f2bf_rne(res);
        }
    }
}

// ==================== readout ================================================
__global__ __launch_bounds__(128) void readout(
    const int* __restrict__ bt, const float* __restrict__ x,
    const float* __restrict__ query,
    const float* __restrict__ W1, const float* __restrict__ b1,
    const float* __restrict__ W2, const float* __restrict__ b2,
    float* __restrict__ out)
{
    int b = blockIdx.x / KK, k = blockIdx.x - b * KK;
    int t = bt[(b * KK + k) * 3 + 1];
    __shared__ float feat[2 * DD];
    __shared__ float red[2 * DD];
    int j = threadIdx.x;
    if (j < DD) feat[j] = x[((size_t)b * NN + t) * DD + j];
    else        feat[j] = query[b * DD + (j - DD)];
    __syncthreads();
    float h = b1[j];
#pragma unroll 8
    for (int i = 0; i < 2 * DD; ++i) h += feat[i] * W1[i * 2 * DD + j];
    h = fmaxf(h, 0.0f);
    red[j] = h * W2[j];
    __syncthreads();
    for (int s = 64; s > 0; s >>= 1) {
        if (j < s) red[j] += red[j + s];
        __syncthreads();
    }
    if (j == 0) out[blockIdx.x] = red[0] + b2[0];
}

extern "C" void kernel_launch(void* const* d_in, const int* in_sizes, int n_in,
                              void* d_out, int out_size, void* d_ws, size_t ws_size,
                              hipStream_t stream) {
    const int*   edge_index     = (const int*)d_in[0];
    const int*   edge_type      = (const int*)d_in[1];
    const int*   rel_edge_index = (const int*)d_in[2];
    const int*   rel_edge_type  = (const int*)d_in[3];
    const int*   batch_triples  = (const int*)d_in[4];
    const float* rel_emb        = (const float*)d_in[5];
    const float* rel_W          = (const float*)d_in[6];
    const float* rel_b          = (const float*)d_in[7];
    const float* rel_g          = (const float*)d_in[8];
    const float* rel_beta       = (const float*)d_in[9];
    const float* proj_W1        = (const float*)d_in[10];
    const float* proj_b1        = (const float*)d_in[11];
    const float* proj_W2        = (const float*)d_in[12];
    const float* proj_b2        = (const float*)d_in[13];
    const float* ent_W          = (const float*)d_in[14];
    const float* ent_b          = (const float*)d_in[15];
    const float* ent_g          = (const float*)d_in[16];
    const float* ent_beta       = (const float*)d_in[17];
    const float* mlp_W1         = (const float*)d_in[18];
    const float* mlp_b1         = (const float*)d_in[19];
    const float* mlp_W2         = (const float*)d_in[20];
    const float* mlp_b2         = (const float*)d_in[21];

    float* ws = (float*)d_ws;
    float* x_ent    = ws;                                   // B*N*D f32
    float* xrel0    = x_ent    + (size_t)BB * NN * DD;      // B*R*D
    float* xrel1    = xrel0    + BB * RR * DD;              // B*R*D
    float* rel_buf4 = xrel1    + BB * RR * DD;              // 4*B*R*D
    float* query    = rel_buf4 + 4 * BB * RR * DD;          // B*D
    int*   deg      = (int*)(query + BB * DD);              // N
    int*   rowptr   = deg + NN;                             // N+1
    int*   cursor   = rowptr + NN + 1;                      // N
    int*   pack     = cursor + NN;                          // E
    int*   fixlist  = pack + EE;                            // BB*FCAP
    int*   fixcnt   = fixlist + BB * FCAP;                  // BB
    int*   bsum     = fixcnt + BB;                          // NSB (pad 256)
    int*   boff     = bsum + 256;                           // NSB (pad 256)
    int*   rptrR    = boff + 256;                           // RR+1 (pad 66)
    int*   rpackR   = rptrR + 66;                           // ERE
    uintptr_t wp = (uintptr_t)(rpackR + ERE);
    wp = (wp + 15) & ~(uintptr_t)15;
    unsigned short* wbf     = (unsigned short*)wp;          // 3*16*64*8
    unsigned short* x_bfi   = wbf + 3 * 16 * 64 * 8;        // B*N*D bf16 [v][b][d]
    unsigned short* agg_bfi = x_bfi + (size_t)BB * NN * DD; // B*N*D bf16 [v][b][d]

    // ---- CSR build + fixlist + rel CSR + W fragment pack ----
    hipMemsetAsync(deg, 0, sizeof(int) * NN, stream);
    hipMemsetAsync(fixcnt, 0, sizeof(int) * BB, stream);
    edge_scan<<<(EE + 255) / 256, 256, 0, stream>>>(
        edge_index, edge_type, batch_triples, deg, fixlist, fixcnt);
    scan_a<<<NSB, 256, 0, stream>>>(deg, bsum);
    setup_small<<<50, 256, 0, stream>>>(
        bsum, boff, rowptr, rel_edge_index, rel_edge_type, rptrR, rpackR,
        ent_W, wbf);
    scan_c<<<NSB, 256, 0, stream>>>(deg, boff, rowptr, cursor);
    csr_fill<<<(EE + 255) / 256, 256, 0, stream>>>(edge_index, edge_type, cursor, pack);

    // ---- relation stage: fused gather+dense per layer, ping-pong ----
    rel_init<<<(BB * RR * DD + 255) / 256, 256, 0, stream>>>(batch_triples, xrel0);
    for (int l = 0; l < LL; ++l) {
        const float* xin = (l & 1) ? xrel1 : xrel0;
        float* xout = (l & 1) ? xrel0 : xrel1;
        rel_layer<<<BB * RR / 4, 256, 0, stream>>>(
            rptrR, rpackR, batch_triples, rel_emb + l * RT * DD,
            rel_W + l * 2 * DD * DD, rel_b + l * DD,
            rel_g + l * DD, rel_beta + l * DD, xin, xout);
    }
    float* rel_repr = xrel0;  // LL=4 even -> final in xrel0
    rel_projq<<<4 * BB * RR / 4, 256, 0, stream>>>(
        rel_repr, batch_triples, proj_W1, proj_b1, proj_W2, proj_b2,
        rel_buf4, query);

    // ---- entity stage: layer 0 fast path ----
    l0_broadcast<<<1024, 256, 0, stream>>>(ent_b, ent_g, ent_beta, x_ent, x_bfi);
    l0_fix<<<(BB * FCAP) / 4, 256, 0, stream>>>(
        batch_triples, fixlist, fixcnt, query, rel_buf4,
        ent_W, ent_b, ent_g, ent_beta, x_ent, x_bfi);

    // ---- entity stage: layers 1..3 (bf16 gather4 + MFMA dense) ----
    for (int l = 1; l < LL; ++l) {
        gather_agg4<<<(NN + 3) / 4, 256, 0, stream>>>(
            rowptr, pack, batch_triples, x_bfi, rel_buf4 + l * BB * RR * DD,
            query, agg_bfi);
        ent_dense6<<<(BB * NN / 16 + 3) / 4, 256, 0, stream>>>(
            wbf + (size_t)(l - 1) * 16 * 64 * 8,
            ent_b + l * DD, ent_g + l * DD, ent_beta + l * DD,
            x_ent, x_bfi, agg_bfi);
    }

    readout<<<BB * KK, 2 * DD, 0, stream>>>(batch_triples, x_ent, query,
                                            mlp_W1, mlp_b1, mlp_W2, mlp_b2,
                                            (float*)d_out);
}

// Round 12
// 333.497 us; speedup vs baseline: 5.7203x; 1.0373x over previous
//
#include <hip/hip_runtime.h>
#include <hip/hip_bf16.h>

#define BB 4
#define KK 16
#define NN 50000
#define EE 300000
#define RR 64
#define ERE 2048
#define RT 4
#define DD 64
#define LL 4
#define FCAP 256
#define NSB 196  // (NN+255)/256

typedef short s16x8 __attribute__((ext_vector_type(8)));
typedef float f32x4 __attribute__((ext_vector_type(4)));

__device__ __forceinline__ float wsum64(float v) {
#pragma unroll
    for (int off = 32; off > 0; off >>= 1) v += __shfl_xor(v, off, 64);
    return v;
}

__device__ __forceinline__ unsigned short f2bf_rne(float f) {
    unsigned u = __builtin_bit_cast(unsigned, f);
    return (unsigned short)((u + 0x7FFFu + ((u >> 16) & 1u)) >> 16);
}

__device__ __forceinline__ float bf2f(unsigned short h) {
    unsigned u = ((unsigned)h) << 16;
    return __builtin_bit_cast(float, u);
}

// ==================== fused edge pass: dst histogram + layer-0 fixlist =======
__global__ __launch_bounds__(256) void edge_scan(
    const int* __restrict__ edge_index, const int* __restrict__ edge_type,
    const int* __restrict__ bt, int* __restrict__ deg,
    int* __restrict__ fixlist, int* __restrict__ cnt)
{
    int e = blockIdx.x * 256 + threadIdx.x;
    if (e < BB) {
        int h0 = bt[e * KK * 3];
        int pos = atomicAdd(&cnt[e], 1);
        if (pos < FCAP) fixlist[e * FCAP + pos] = h0 | (int)(0xFFFFu << 16);
    }
    if (e >= EE) return;
    int s = edge_index[e];
    int d = edge_index[EE + e];
    int t = edge_type[e];
    atomicAdd(&deg[d], 1);
#pragma unroll
    for (int b = 0; b < BB; ++b) {
        int h0 = bt[b * KK * 3];
        if (s == h0) {
            int pos = atomicAdd(&cnt[b], 1);
            if (pos < FCAP) fixlist[b * FCAP + pos] = d | (t << 16);
        }
    }
}

// ==================== scan pipeline ==========================================
__global__ __launch_bounds__(256) void scan_a(
    const int* __restrict__ deg, int* __restrict__ bsum)
{
    int i = blockIdx.x * 256 + threadIdx.x;
    int v = (i < NN) ? deg[i] : 0;
    int s = v;
#pragma unroll
    for (int off = 32; off > 0; off >>= 1) s += __shfl_xor(s, off, 64);
    __shared__ int ls[4];
    if ((threadIdx.x & 63) == 0) ls[threadIdx.x >> 6] = s;
    __syncthreads();
    if (threadIdx.x == 0) bsum[blockIdx.x] = ls[0] + ls[1] + ls[2] + ls[3];
}

// fused: block 0 = scan_b; block 1 = rel graph CSR; blocks 2..49 = wfrag pack
__global__ __launch_bounds__(256) void setup_small(
    const int* __restrict__ bsum, int* __restrict__ boff, int* __restrict__ rowptr,
    const int* __restrict__ rel_edge_index, const int* __restrict__ rel_edge_type,
    int* __restrict__ rptr, int* __restrict__ rpack,
    const float* __restrict__ entW, unsigned short* __restrict__ wbf)
{
    int t = threadIdx.x;
    if (blockIdx.x == 0) {
        __shared__ int tmp[256];
        int v = (t < NSB) ? bsum[t] : 0;
        tmp[t] = v;
        __syncthreads();
        for (int off = 1; off < 256; off <<= 1) {
            int u = (t >= off) ? tmp[t - off] : 0;
            __syncthreads();
            tmp[t] += u;
            __syncthreads();
        }
        if (t < NSB) boff[t] = tmp[t] - v;
        if (t == 0) rowptr[NN] = EE;
    } else if (blockIdx.x == 1) {
        __shared__ int hdeg[RR];
        __shared__ int hcur[RR];
        if (t < RR) hdeg[t] = 0;
        __syncthreads();
        for (int e = t; e < ERE; e += 256) atomicAdd(&hdeg[rel_edge_index[ERE + e]], 1);
        __syncthreads();
        if (t == 0) {
            int run = 0;
            for (int r = 0; r < RR; ++r) { hcur[r] = run; rptr[r] = run; run += hdeg[r]; }
            rptr[RR] = run;
        }
        __syncthreads();
        for (int e = t; e < ERE; e += 256) {
            int s = rel_edge_index[e];
            int d = rel_edge_index[ERE + e];
            int ty = rel_edge_type[e];
            int pos = atomicAdd(&hcur[d], 1);
            rpack[pos] = s | (ty << 16);
        }
    } else {
        if (t >= 64) return;
        int blk = blockIdx.x - 2;        // li*16 + tt*4 + s
        int li = blk >> 4;
        int tt = (blk >> 2) & 3, s = blk & 3;
        const float* W = entW + (li + 1) * 2 * DD * DD;
        unsigned short* dst = wbf + ((size_t)blk * 64 + t) * 8;
#pragma unroll
        for (int j = 0; j < 8; ++j) {
            int k = s * 32 + (t >> 4) * 8 + j;
            int n = tt * 16 + (t & 15);
            dst[j] = f2bf_rne(W[k * DD + n]);
        }
    }
}

__global__ __launch_bounds__(256) void scan_c(
    const int* __restrict__ deg, const int* __restrict__ boff,
    int* __restrict__ rowptr, int* __restrict__ cursor)
{
    __shared__ int tmp[256];
    int t = threadIdx.x;
    int i = blockIdx.x * 256 + t;
    int v = (i < NN) ? deg[i] : 0;
    tmp[t] = v;
    __syncthreads();
    for (int off = 1; off < 256; off <<= 1) {
        int u = (t >= off) ? tmp[t - off] : 0;
        __syncthreads();
        tmp[t] += u;
        __syncthreads();
    }
    if (i < NN) {
        int excl = tmp[t] - v + boff[blockIdx.x];
        rowptr[i] = excl;
        cursor[i] = excl;
    }
}

__global__ __launch_bounds__(256) void csr_fill(
    const int* __restrict__ edge_index, const int* __restrict__ edge_type,
    int* __restrict__ cursor, int* __restrict__ pack)
{
    int e = blockIdx.x * 256 + threadIdx.x;
    if (e >= EE) return;
    int s = edge_index[e];
    int d = edge_index[EE + e];
    int t = edge_type[e];
    int pos = atomicAdd(&cursor[d], 1);
    pack[pos] = s | (t << 16);  // src < 2^16, et < 64
}

// ==================== relation stage =========================================
// layer 0: input is the analytic one-hot boundary, no buffer read
__global__ __launch_bounds__(256) void rel_layer0(
    const int* __restrict__ rptr, const int* __restrict__ rpack,
    const int* __restrict__ bt, const float* __restrict__ emb,
    const float* __restrict__ W, const float* __restrict__ bias,
    const float* __restrict__ g, const float* __restrict__ beta,
    float* __restrict__ xout)
{
    int row = blockIdx.x * 4 + (int)(threadIdx.x >> 6);  // 0..BB*RR-1
    int lane = threadIdx.x & 63;
    int b = row >> 6, r = row & 63;
    int r0 = bt[(b * KK) * 3 + 2];
    int beg = rptr[r], end = rptr[r + 1];
    float av = (r == r0) ? 1.0f : 0.0f;
    for (int j = beg; j < end; ++j) {
        int p = rpack[j];
        if ((p & 0xFFFF) == r0) av += emb[(p >> 16) * DD + lane];
    }
    float xv = (r == r0) ? 1.0f : 0.0f;
    float acc = bias[lane];
#pragma unroll 8
    for (int k = 0; k < DD; ++k) {
        acc += __shfl(xv, k, 64) * W[k * DD + lane];
        acc += __shfl(av, k, 64) * W[(DD + k) * DD + lane];
    }
    float m = wsum64(acc) * (1.0f / DD);
    float c = acc - m;
    float v = wsum64(c * c) * (1.0f / DD);
    float o = c * rsqrtf(v + 1e-5f) * g[lane] + beta[lane];
    xout[row * DD + lane] = fmaxf(o, 0.0f) + xv;
}

__global__ __launch_bounds__(256) void rel_layer(
    const int* __restrict__ rptr, const int* __restrict__ rpack,
    const int* __restrict__ bt, const float* __restrict__ emb,
    const float* __restrict__ W, const float* __restrict__ bias,
    const float* __restrict__ g, const float* __restrict__ beta,
    const float* __restrict__ xin, float* __restrict__ xout)
{
    int row = blockIdx.x * 4 + (int)(threadIdx.x >> 6);  // 0..BB*RR-1
    int lane = threadIdx.x & 63;
    int b = row >> 6, r = row & 63;
    int r0 = bt[(b * KK) * 3 + 2];
    int beg = rptr[r], end = rptr[r + 1];
    const float* xb = xin + b * RR * DD;
    float av = (r == r0) ? 1.0f : 0.0f;
    for (int j = beg; j < end; ++j) {
        int p = rpack[j];
        av += xb[(p & 0xFFFF) * DD + lane] * emb[(p >> 16) * DD + lane];
    }
    float xv = xin[row * DD + lane];
    float acc = bias[lane];
#pragma unroll 8
    for (int k = 0; k < DD; ++k) {
        acc += __shfl(xv, k, 64) * W[k * DD + lane];
        acc += __shfl(av, k, 64) * W[(DD + k) * DD + lane];
    }
    float m = wsum64(acc) * (1.0f / DD);
    float c = acc - m;
    float v = wsum64(c * c) * (1.0f / DD);
    float o = c * rsqrtf(v + 1e-5f) * g[lane] + beta[lane];
    xout[row * DD + lane] = fmaxf(o, 0.0f) + xv;
}

// all-4-layer projection + query extraction (block 0)
__global__ __launch_bounds__(256) void rel_projq(
    const float* __restrict__ rel_repr, const int* __restrict__ bt,
    const float* __restrict__ W1, const float* __restrict__ b1,
    const float* __restrict__ W2, const float* __restrict__ b2,
    float* __restrict__ rel_buf4, float* __restrict__ query)
{
    int grow = blockIdx.x * 4 + (int)(threadIdx.x >> 6);  // 0..4*B*R-1
    int lane = threadIdx.x & 63;
    int l = grow / (BB * RR);
    int row = grow - l * (BB * RR);
    const float* xr = &rel_repr[row * DD];
    const float* w1 = W1 + l * DD * DD;
    const float* w2 = W2 + l * DD * DD;
    float h = b1[l * DD + lane];
#pragma unroll 8
    for (int k = 0; k < DD; ++k) h += xr[k] * w1[k * DD + lane];
    h = fmaxf(h, 0.0f);
    float o = b2[l * DD + lane];
#pragma unroll 8
    for (int k = 0; k < DD; ++k) o += __shfl(h, k, 64) * w2[k * DD + lane];
    rel_buf4[grow * DD + lane] = o;
    if (blockIdx.x == 0) {
        int i = threadIdx.x;  // 0..255 = B*D
        int b = i / DD, d = i - b * DD;
        int r0 = bt[(b * KK) * 3 + 2];
        query[b * DD + d] = rel_repr[(b * RR + r0) * DD + d];
    }
}

// ==================== entity stage ===========================================
// x f32: [b][v][d]. bf16 mirrors interleaved: [v][b][d] (512 B per vertex).
__global__ __launch_bounds__(256) void l0_broadcast(
    const float* __restrict__ b0, const float* __restrict__ g0,
    const float* __restrict__ be0, float* __restrict__ x,
    unsigned short* __restrict__ x_bfi)
{
    int lane = threadIdx.x & 63;
    float bv = b0[lane];
    float m = wsum64(bv) * (1.0f / DD);
    float c = bv - m;
    float v = wsum64(c * c) * (1.0f / DD);
    float d = fmaxf(c * rsqrtf(v + 1e-5f) * g0[lane] + be0[lane], 0.0f);
    unsigned short dbf = f2bf_rne(d);
    int gw = blockIdx.x * 4 + (threadIdx.x >> 6);
    int nw = gridDim.x * 4;
    // value is row-uniform: flat order covers interleaved order too
    for (int row = gw; row < BB * NN; row += nw) {
        x[(size_t)row * DD + lane] = d;
        x_bfi[(size_t)row * DD + lane] = dbf;
    }
}

__global__ __launch_bounds__(256) void l0_fix(
    const int* __restrict__ bt, const int* __restrict__ fixlist,
    const int* __restrict__ cnt, const float* __restrict__ query,
    const float* __restrict__ rel_buf,
    const float* __restrict__ W0, const float* __restrict__ b0,
    const float* __restrict__ g0, const float* __restrict__ be0,
    float* __restrict__ x, unsigned short* __restrict__ x_bfi)
{
    int gidx = blockIdx.x * 4 + (threadIdx.x >> 6);  // 0..BB*FCAP-1
    int lane = threadIdx.x & 63;
    int b = gidx / FCAP, i = gidx - b * FCAP;
    int nc = min(cnt[b], FCAP);
    if (i >= nc) return;
    unsigned ent = (unsigned)fixlist[b * FCAP + i];
    int v = (int)(ent & 0xFFFFu);
    int h0 = bt[b * KK * 3];
    float q = query[b * DD + lane];
    float agg = (v == h0) ? q : 0.0f;
    for (int j = 0; j < nc; ++j) {
        unsigned ej = (unsigned)fixlist[b * FCAP + j];
        if ((int)(ej & 0xFFFFu) == v) {
            unsigned et = ej >> 16;
            if (et != 0xFFFFu)
                agg += q * rel_buf[(b * RR + (int)et) * DD + lane];
        }
    }
    float xr = (v == h0) ? q : 0.0f;
    float acc = b0[lane];
#pragma unroll 8
    for (int k = 0; k < DD; ++k) {
        acc += __shfl(xr, k, 64) * W0[k * DD + lane];
        acc += __shfl(agg, k, 64) * W0[(DD + k) * DD + lane];
    }
    float m = wsum64(acc) * (1.0f / DD);
    float c = acc - m;
    float vv = wsum64(c * c) * (1.0f / DD);
    float o = c * rsqrtf(vv + 1e-5f) * g0[lane] + be0[lane];
    float res = fmaxf(o, 0.0f) + xr;
    x[((size_t)b * NN + v) * DD + lane] = res;
    x_bfi[((size_t)v * BB + b) * DD + lane] = f2bf_rne(res);
}

// ==================== fused gather + MFMA dense ==============================
// Block = 4 waves = 16 vertices (NN % 16 == 0). Each wave gathers its own 4
// vertices (lane = batch l>>4, dims 4*(l&15)..+3; one dwordx2 x-load + one
// float4 rel-load per edge), stages bf16 agg in XOR-swizzled LDS, then runs
// its own 16-row MFMA dense. x_bfi double-buffered (gather reads old, dense
// writes new) to avoid cross-block races; f32 x is own-row only.
__global__ __launch_bounds__(256) void gather_dense(
    const int* __restrict__ rowptr, const int* __restrict__ pack,
    const int* __restrict__ bt,
    const unsigned short* __restrict__ xin_bfi,
    const float* __restrict__ rel_buf, const float* __restrict__ query,
    const unsigned short* __restrict__ wfrag,
    const float* __restrict__ bias, const float* __restrict__ g,
    const float* __restrict__ beta,
    float* __restrict__ x, unsigned short* __restrict__ xout_bfi)
{
    __shared__ unsigned short aggL[4 * 16 * DD];  // 8 KB, per-wave 2 KB tile
    const int wid = (int)(threadIdx.x >> 6);
    const int lane = threadIdx.x & 63;
    const int v0 = blockIdx.x * 16 + wid * 4;   // wave's 4 vertices
    const int b = lane >> 4;
    const int d0 = (lane & 15) * 4;
    const float* rb = rel_buf + (size_t)b * RR * DD + d0;
    const int h0 = bt[b * KK * 3];
    char* wls = (char*)&aggL[wid * 16 * DD];

    // ---- gather phase ----
    for (int vv = 0; vv < 4; ++vv) {
        int v = v0 + vv;
        int beg = rowptr[v], end = rowptr[v + 1];
        f32x4 acc = {0.0f, 0.0f, 0.0f, 0.0f};
        int j = beg;
        for (; j + 1 < end; j += 2) {
            int p0 = pack[j], p1 = pack[j + 1];
            ushort4 xv0 = *(const ushort4*)&xin_bfi[((size_t)(p0 & 0xFFFF) * BB + b) * DD + d0];
            ushort4 xv1 = *(const ushort4*)&xin_bfi[((size_t)(p1 & 0xFFFF) * BB + b) * DD + d0];
            float4 r0 = *(const float4*)&rb[(size_t)(p0 >> 16) * DD];
            float4 r1 = *(const float4*)&rb[(size_t)(p1 >> 16) * DD];
            acc[0] += bf2f(xv0.x) * r0.x + bf2f(xv1.x) * r1.x;
            acc[1] += bf2f(xv0.y) * r0.y + bf2f(xv1.y) * r1.y;
            acc[2] += bf2f(xv0.z) * r0.z + bf2f(xv1.z) * r1.z;
            acc[3] += bf2f(xv0.w) * r0.w + bf2f(xv1.w) * r1.w;
        }
        if (j < end) {
            int p0 = pack[j];
            ushort4 xv0 = *(const ushort4*)&xin_bfi[((size_t)(p0 & 0xFFFF) * BB + b) * DD + d0];
            float4 r0 = *(const float4*)&rb[(size_t)(p0 >> 16) * DD];
            acc[0] += bf2f(xv0.x) * r0.x;
            acc[1] += bf2f(xv0.y) * r0.y;
            acc[2] += bf2f(xv0.z) * r0.z;
            acc[3] += bf2f(xv0.w) * r0.w;
        }
        if (v == h0) {
            float4 q = *(const float4*)&query[b * DD + d0];
            acc[0] += q.x; acc[1] += q.y; acc[2] += q.z; acc[3] += q.w;
        }
        ushort4 outv;
        outv.x = f2bf_rne(acc[0]);
        outv.y = f2bf_rne(acc[1]);
        outv.z = f2bf_rne(acc[2]);
        outv.w = f2bf_rne(acc[3]);
        int row = vv * 4 + b;                     // local row 0..15
        int off = (row * 128 + d0 * 2) ^ ((row & 7) << 4);
        *(ushort4*)(wls + off) = outv;
    }
    __syncthreads();

    // ---- dense phase (wave's rows = its own gathered vertices) ----
    s16x8 bfr[4][4];
#pragma unroll
    for (int t = 0; t < 4; ++t)
#pragma unroll
        for (int s = 0; s < 4; ++s)
            bfr[s][t] = *(const s16x8*)&wfrag[((size_t)(t * 4 + s) * 64 + lane) * 8];

    f32x4 acc[4] = {f32x4{0,0,0,0}, f32x4{0,0,0,0}, f32x4{0,0,0,0}, f32x4{0,0,0,0}};
    const int base = v0 * 4;
    const int lrow = lane & 15;
    const size_t arow = (size_t)(base + lrow) * DD;
    const int koff = (lane >> 4) * 8;
#pragma unroll
    for (int s = 0; s < 4; ++s) {
        s16x8 a;
        if (s < 2) {
            a = *(const s16x8*)(xin_bfi + arow + s * 32 + koff);
        } else {
            int off = (lrow * 128 + ((s - 2) * 32 + koff) * 2) ^ ((lrow & 7) << 4);
            a = *(const s16x8*)(wls + off);
        }
#pragma unroll
        for (int t = 0; t < 4; ++t)
            acc[t] = __builtin_amdgcn_mfma_f32_16x16x32_bf16(a, bfr[s][t], acc[t], 0, 0, 0);
    }

    float bia[4], gt[4], bet[4];
#pragma unroll
    for (int t = 0; t < 4; ++t) {
        int col = (lane & 15) + 16 * t;
        bia[t] = bias[col]; gt[t] = g[col]; bet[t] = beta[col];
    }
#pragma unroll
    for (int r = 0; r < 4; ++r) {
        float v0f = acc[0][r] + bia[0];
        float v1f = acc[1][r] + bia[1];
        float v2f = acc[2][r] + bia[2];
        float v3f = acc[3][r] + bia[3];
        float sum = v0f + v1f + v2f + v3f;
#pragma unroll
        for (int off = 1; off < 16; off <<= 1) sum += __shfl_xor(sum, off, 64);
        float m = sum * (1.0f / DD);
        float c0 = v0f - m, c1 = v1f - m, c2 = v2f - m, c3 = v3f - m;
        float q = c0 * c0 + c1 * c1 + c2 * c2 + c3 * c3;
#pragma unroll
        for (int off = 1; off < 16; off <<= 1) q += __shfl_xor(q, off, 64);
        float inv = rsqrtf(q * (1.0f / DD) + 1e-5f);
        int rf = base + (lane >> 4) * 4 + r;
        int vv2 = rf >> 2, bb2 = rf & 3;
        size_t frow = ((size_t)bb2 * NN + vv2) * DD;
        size_t irow = (size_t)rf * DD;
        float cs[4] = {c0, c1, c2, c3};
#pragma unroll
        for (int t = 0; t < 4; ++t) {
            int col = (lane & 15) + 16 * t;
            float xo = x[frow + col];
            float o = cs[t] * inv * gt[t] + bet[t];
            float res = fmaxf(o, 0.0f) + xo;
            x[frow + col] = res;
            xout_bfi[irow + col] = f2bf_rne(res);
        }
    }
}

// ==================== readout ================================================
__global__ __launch_bounds__(128) void readout(
    const int* __restrict__ bt, const float* __restrict__ x,
    const float* __restrict__ query,
    const float* __restrict__ W1, const float* __restrict__ b1,
    const float* __restrict__ W2, const float* __restrict__ b2,
    float* __restrict__ out)
{
    int b = blockIdx.x / KK, k = blockIdx.x - b * KK;
    int t = bt[(b * KK + k) * 3 + 1];
    __shared__ float feat[2 * DD];
    __shared__ float red[2 * DD];
    int j = threadIdx.x;
    if (j < DD) feat[j] = x[((size_t)b * NN + t) * DD + j];
    else        feat[j] = query[b * DD + (j - DD)];
    __syncthreads();
    float h = b1[j];
#pragma unroll 8
    for (int i = 0; i < 2 * DD; ++i) h += feat[i] * W1[i * 2 * DD + j];
    h = fmaxf(h, 0.0f);
    red[j] = h * W2[j];
    __syncthreads();
    for (int s = 64; s > 0; s >>= 1) {
        if (j < s) red[j] += red[j + s];
        __syncthreads();
    }
    if (j == 0) out[blockIdx.x] = red[0] + b2[0];
}

extern "C" void kernel_launch(void* const* d_in, const int* in_sizes, int n_in,
                              void* d_out, int out_size, void* d_ws, size_t ws_size,
                              hipStream_t stream) {
    const int*   edge_index     = (const int*)d_in[0];
    const int*   edge_type      = (const int*)d_in[1];
    const int*   rel_edge_index = (const int*)d_in[2];
    const int*   rel_edge_type  = (const int*)d_in[3];
    const int*   batch_triples  = (const int*)d_in[4];
    const float* rel_emb        = (const float*)d_in[5];
    const float* rel_W          = (const float*)d_in[6];
    const float* rel_b          = (const float*)d_in[7];
    const float* rel_g          = (const float*)d_in[8];
    const float* rel_beta       = (const float*)d_in[9];
    const float* proj_W1        = (const float*)d_in[10];
    const float* proj_b1        = (const float*)d_in[11];
    const float* proj_W2        = (const float*)d_in[12];
    const float* proj_b2        = (const float*)d_in[13];
    const float* ent_W          = (const float*)d_in[14];
    const float* ent_b          = (const float*)d_in[15];
    const float* ent_g          = (const float*)d_in[16];
    const float* ent_beta       = (const float*)d_in[17];
    const float* mlp_W1         = (const float*)d_in[18];
    const float* mlp_b1         = (const float*)d_in[19];
    const float* mlp_W2         = (const float*)d_in[20];
    const float* mlp_b2         = (const float*)d_in[21];

    float* ws = (float*)d_ws;
    float* x_ent    = ws;                                   // B*N*D f32
    float* xrel0    = x_ent    + (size_t)BB * NN * DD;      // B*R*D
    float* xrel1    = xrel0    + BB * RR * DD;              // B*R*D
    float* rel_buf4 = xrel1    + BB * RR * DD;              // 4*B*R*D
    float* query    = rel_buf4 + 4 * BB * RR * DD;          // B*D
    int*   deg      = (int*)(query + BB * DD);              // N
    int*   rowptr   = deg + NN;                             // N+1
    int*   cursor   = rowptr + NN + 1;                      // N
    int*   pack     = cursor + NN;                          // E
    int*   fixlist  = pack + EE;                            // BB*FCAP
    int*   fixcnt   = fixlist + BB * FCAP;                  // BB
    int*   bsum     = fixcnt + BB;                          // NSB (pad 256)
    int*   boff     = bsum + 256;                           // NSB (pad 256)
    int*   rptrR    = boff + 256;                           // RR+1 (pad 66)
    int*   rpackR   = rptrR + 66;                           // ERE
    uintptr_t wp = (uintptr_t)(rpackR + ERE);
    wp = (wp + 15) & ~(uintptr_t)15;
    unsigned short* wbf    = (unsigned short*)wp;           // 3*16*64*8
    unsigned short* x_bfiA = wbf + 3 * 16 * 64 * 8;         // B*N*D bf16 [v][b][d]
    unsigned short* x_bfiB = x_bfiA + (size_t)BB * NN * DD; // B*N*D bf16 [v][b][d]

    // ---- CSR build + fixlist + rel CSR + W fragment pack ----
    hipMemsetAsync(deg, 0, sizeof(int) * NN, stream);
    hipMemsetAsync(fixcnt, 0, sizeof(int) * BB, stream);
    edge_scan<<<(EE + 255) / 256, 256, 0, stream>>>(
        edge_index, edge_type, batch_triples, deg, fixlist, fixcnt);
    scan_a<<<NSB, 256, 0, stream>>>(deg, bsum);
    setup_small<<<50, 256, 0, stream>>>(
        bsum, boff, rowptr, rel_edge_index, rel_edge_type, rptrR, rpackR,
        ent_W, wbf);
    scan_c<<<NSB, 256, 0, stream>>>(deg, boff, rowptr, cursor);
    csr_fill<<<(EE + 255) / 256, 256, 0, stream>>>(edge_index, edge_type, cursor, pack);

    // ---- relation stage ----
    rel_layer0<<<BB * RR / 4, 256, 0, stream>>>(
        rptrR, rpackR, batch_triples, rel_emb,
        rel_W, rel_b, rel_g, rel_beta, xrel1);
    for (int l = 1; l < LL; ++l) {
        const float* xin = (l & 1) ? xrel1 : xrel0;
        float* xout = (l & 1) ? xrel0 : xrel1;
        rel_layer<<<BB * RR / 4, 256, 0, stream>>>(
            rptrR, rpackR, batch_triples, rel_emb + l * RT * DD,
            rel_W + l * 2 * DD * DD, rel_b + l * DD,
            rel_g + l * DD, rel_beta + l * DD, xin, xout);
    }
    float* rel_repr = xrel0;  // l=1 wrote xrel0, l=2 xrel1, l=3 xrel0
    rel_projq<<<4 * BB * RR / 4, 256, 0, stream>>>(
        rel_repr, batch_triples, proj_W1, proj_b1, proj_W2, proj_b2,
        rel_buf4, query);

    // ---- entity stage: layer 0 fast path ----
    l0_broadcast<<<1024, 256, 0, stream>>>(ent_b, ent_g, ent_beta, x_ent, x_bfiA);
    l0_fix<<<(BB * FCAP) / 4, 256, 0, stream>>>(
        batch_triples, fixlist, fixcnt, query, rel_buf4,
        ent_W, ent_b, ent_g, ent_beta, x_ent, x_bfiA);

    // ---- entity stage: layers 1..3 (fused gather + MFMA dense) ----
    unsigned short* bufs[2] = {x_bfiA, x_bfiB};
    for (int l = 1; l < LL; ++l) {
        gather_dense<<<NN / 16, 256, 0, stream>>>(
            rowptr, pack, batch_triples, bufs[(l - 1) & 1],
            rel_buf4 + l * BB * RR * DD, query,
            wbf + (size_t)(l - 1) * 16 * 64 * 8,
            ent_b + l * DD, ent_g + l * DD, ent_beta + l * DD,
            x_ent, bufs[l & 1]);
    }

    readout<<<BB * KK, 2 * DD, 0, stream>>>(batch_triples, x_ent, query,
                                            mlp_W1, mlp_b1, mlp_W2, mlp_b2,
                                            (float*)d_out);
}

// Round 13
// 303.199 us; speedup vs baseline: 6.2919x; 1.0999x over previous
//
#include <hip/hip_runtime.h>
#include <hip/hip_bf16.h>

#define BB 4
#define KK 16
#define NN 50000
#define EE 300000
#define RR 64
#define ERE 2048
#define RT 4
#define DD 64
#define LL 4
#define FCAP 256
#define NSB 196  // (NN+255)/256

typedef short s16x8 __attribute__((ext_vector_type(8)));
typedef float f32x4 __attribute__((ext_vector_type(4)));

__device__ __forceinline__ float wsum64(float v) {
#pragma unroll
    for (int off = 32; off > 0; off >>= 1) v += __shfl_xor(v, off, 64);
    return v;
}

__device__ __forceinline__ unsigned short f2bf_rne(float f) {
    unsigned u = __builtin_bit_cast(unsigned, f);
    return (unsigned short)((u + 0x7FFFu + ((u >> 16) & 1u)) >> 16);
}

__device__ __forceinline__ float bf2f(unsigned short h) {
    unsigned u = ((unsigned)h) << 16;
    return __builtin_bit_cast(float, u);
}

// ==================== fused edge pass: dst histogram + layer-0 fixlist =======
__global__ __launch_bounds__(256) void edge_scan(
    const int* __restrict__ edge_index, const int* __restrict__ edge_type,
    const int* __restrict__ bt, int* __restrict__ deg,
    int* __restrict__ fixlist, int* __restrict__ cnt)
{
    int e = blockIdx.x * 256 + threadIdx.x;
    if (e < BB) {
        int h0 = bt[e * KK * 3];
        int pos = atomicAdd(&cnt[e], 1);
        if (pos < FCAP) fixlist[e * FCAP + pos] = h0 | (int)(0xFFFFu << 16);
    }
    if (e >= EE) return;
    int s = edge_index[e];
    int d = edge_index[EE + e];
    int t = edge_type[e];
    atomicAdd(&deg[d], 1);
#pragma unroll
    for (int b = 0; b < BB; ++b) {
        int h0 = bt[b * KK * 3];
        if (s == h0) {
            int pos = atomicAdd(&cnt[b], 1);
            if (pos < FCAP) fixlist[b * FCAP + pos] = d | (t << 16);
        }
    }
}

// ==================== scan pipeline ==========================================
__global__ __launch_bounds__(256) void scan_a(
    const int* __restrict__ deg, int* __restrict__ bsum)
{
    int i = blockIdx.x * 256 + threadIdx.x;
    int v = (i < NN) ? deg[i] : 0;
    int s = v;
#pragma unroll
    for (int off = 32; off > 0; off >>= 1) s += __shfl_xor(s, off, 64);
    __shared__ int ls[4];
    if ((threadIdx.x & 63) == 0) ls[threadIdx.x >> 6] = s;
    __syncthreads();
    if (threadIdx.x == 0) bsum[blockIdx.x] = ls[0] + ls[1] + ls[2] + ls[3];
}

// fused: block 0 = scan_b; block 1 = rel graph CSR; blocks 2..49 = wfrag pack
__global__ __launch_bounds__(256) void setup_small(
    const int* __restrict__ bsum, int* __restrict__ boff, int* __restrict__ rowptr,
    const int* __restrict__ rel_edge_index, const int* __restrict__ rel_edge_type,
    int* __restrict__ rptr, int* __restrict__ rpack,
    const float* __restrict__ entW, unsigned short* __restrict__ wbf)
{
    int t = threadIdx.x;
    if (blockIdx.x == 0) {
        __shared__ int tmp[256];
        int v = (t < NSB) ? bsum[t] : 0;
        tmp[t] = v;
        __syncthreads();
        for (int off = 1; off < 256; off <<= 1) {
            int u = (t >= off) ? tmp[t - off] : 0;
            __syncthreads();
            tmp[t] += u;
            __syncthreads();
        }
        if (t < NSB) boff[t] = tmp[t] - v;
        if (t == 0) rowptr[NN] = EE;
    } else if (blockIdx.x == 1) {
        __shared__ int hdeg[RR];
        __shared__ int hcur[RR];
        if (t < RR) hdeg[t] = 0;
        __syncthreads();
        for (int e = t; e < ERE; e += 256) atomicAdd(&hdeg[rel_edge_index[ERE + e]], 1);
        __syncthreads();
        if (t == 0) {
            int run = 0;
            for (int r = 0; r < RR; ++r) { hcur[r] = run; rptr[r] = run; run += hdeg[r]; }
            rptr[RR] = run;
        }
        __syncthreads();
        for (int e = t; e < ERE; e += 256) {
            int s = rel_edge_index[e];
            int d = rel_edge_index[ERE + e];
            int ty = rel_edge_type[e];
            int pos = atomicAdd(&hcur[d], 1);
            rpack[pos] = s | (ty << 16);
        }
    } else {
        if (t >= 64) return;
        int blk = blockIdx.x - 2;        // li*16 + tt*4 + s
        int li = blk >> 4;
        int tt = (blk >> 2) & 3, s = blk & 3;
        const float* W = entW + (li + 1) * 2 * DD * DD;
        unsigned short* dst = wbf + ((size_t)blk * 64 + t) * 8;
#pragma unroll
        for (int j = 0; j < 8; ++j) {
            int k = s * 32 + (t >> 4) * 8 + j;
            int n = tt * 16 + (t & 15);
            dst[j] = f2bf_rne(W[k * DD + n]);
        }
    }
}

__global__ __launch_bounds__(256) void scan_c(
    const int* __restrict__ deg, const int* __restrict__ boff,
    int* __restrict__ rowptr, int* __restrict__ cursor)
{
    __shared__ int tmp[256];
    int t = threadIdx.x;
    int i = blockIdx.x * 256 + t;
    int v = (i < NN) ? deg[i] : 0;
    tmp[t] = v;
    __syncthreads();
    for (int off = 1; off < 256; off <<= 1) {
        int u = (t >= off) ? tmp[t - off] : 0;
        __syncthreads();
        tmp[t] += u;
        __syncthreads();
    }
    if (i < NN) {
        int excl = tmp[t] - v + boff[blockIdx.x];
        rowptr[i] = excl;
        cursor[i] = excl;
    }
}

__global__ __launch_bounds__(256) void csr_fill(
    const int* __restrict__ edge_index, const int* __restrict__ edge_type,
    int* __restrict__ cursor, int* __restrict__ pack)
{
    int e = blockIdx.x * 256 + threadIdx.x;
    if (e >= EE) return;
    int s = edge_index[e];
    int d = edge_index[EE + e];
    int t = edge_type[e];
    int pos = atomicAdd(&cursor[d], 1);
    pack[pos] = s | (t << 16);  // src < 2^16, et < 64
}

// ==================== relation stage =========================================
__global__ __launch_bounds__(256) void rel_layer0(
    const int* __restrict__ rptr, const int* __restrict__ rpack,
    const int* __restrict__ bt, const float* __restrict__ emb,
    const float* __restrict__ W, const float* __restrict__ bias,
    const float* __restrict__ g, const float* __restrict__ beta,
    float* __restrict__ xout)
{
    int row = blockIdx.x * 4 + (int)(threadIdx.x >> 6);  // 0..BB*RR-1
    int lane = threadIdx.x & 63;
    int b = row >> 6, r = row & 63;
    int r0 = bt[(b * KK) * 3 + 2];
    int beg = rptr[r], end = rptr[r + 1];
    float av = (r == r0) ? 1.0f : 0.0f;
    for (int j = beg; j < end; ++j) {
        int p = rpack[j];
        if ((p & 0xFFFF) == r0) av += emb[(p >> 16) * DD + lane];
    }
    float xv = (r == r0) ? 1.0f : 0.0f;
    float acc = bias[lane];
#pragma unroll 8
    for (int k = 0; k < DD; ++k) {
        acc += __shfl(xv, k, 64) * W[k * DD + lane];
        acc += __shfl(av, k, 64) * W[(DD + k) * DD + lane];
    }
    float m = wsum64(acc) * (1.0f / DD);
    float c = acc - m;
    float v = wsum64(c * c) * (1.0f / DD);
    float o = c * rsqrtf(v + 1e-5f) * g[lane] + beta[lane];
    xout[row * DD + lane] = fmaxf(o, 0.0f) + xv;
}

__global__ __launch_bounds__(256) void rel_layer(
    const int* __restrict__ rptr, const int* __restrict__ rpack,
    const int* __restrict__ bt, const float* __restrict__ emb,
    const float* __restrict__ W, const float* __restrict__ bias,
    const float* __restrict__ g, const float* __restrict__ beta,
    const float* __restrict__ xin, float* __restrict__ xout)
{
    int row = blockIdx.x * 4 + (int)(threadIdx.x >> 6);  // 0..BB*RR-1
    int lane = threadIdx.x & 63;
    int b = row >> 6, r = row & 63;
    int r0 = bt[(b * KK) * 3 + 2];
    int beg = rptr[r], end = rptr[r + 1];
    const float* xb = xin + b * RR * DD;
    float av = (r == r0) ? 1.0f : 0.0f;
    for (int j = beg; j < end; ++j) {
        int p = rpack[j];
        av += xb[(p & 0xFFFF) * DD + lane] * emb[(p >> 16) * DD + lane];
    }
    float xv = xin[row * DD + lane];
    float acc = bias[lane];
#pragma unroll 8
    for (int k = 0; k < DD; ++k) {
        acc += __shfl(xv, k, 64) * W[k * DD + lane];
        acc += __shfl(av, k, 64) * W[(DD + k) * DD + lane];
    }
    float m = wsum64(acc) * (1.0f / DD);
    float c = acc - m;
    float v = wsum64(c * c) * (1.0f / DD);
    float o = c * rsqrtf(v + 1e-5f) * g[lane] + beta[lane];
    xout[row * DD + lane] = fmaxf(o, 0.0f) + xv;
}

// all-4-layer projection + query extraction (block 0)
__global__ __launch_bounds__(256) void rel_projq(
    const float* __restrict__ rel_repr, const int* __restrict__ bt,
    const float* __restrict__ W1, const float* __restrict__ b1,
    const float* __restrict__ W2, const float* __restrict__ b2,
    float* __restrict__ rel_buf4, float* __restrict__ query)
{
    int grow = blockIdx.x * 4 + (int)(threadIdx.x >> 6);  // 0..4*B*R-1
    int lane = threadIdx.x & 63;
    int l = grow / (BB * RR);
    int row = grow - l * (BB * RR);
    const float* xr = &rel_repr[row * DD];
    const float* w1 = W1 + l * DD * DD;
    const float* w2 = W2 + l * DD * DD;
    float h = b1[l * DD + lane];
#pragma unroll 8
    for (int k = 0; k < DD; ++k) h += xr[k] * w1[k * DD + lane];
    h = fmaxf(h, 0.0f);
    float o = b2[l * DD + lane];
#pragma unroll 8
    for (int k = 0; k < DD; ++k) o += __shfl(h, k, 64) * w2[k * DD + lane];
    rel_buf4[grow * DD + lane] = o;
    if (blockIdx.x == 0) {
        int i = threadIdx.x;  // 0..255 = B*D
        int b = i / DD, d = i - b * DD;
        int r0 = bt[(b * KK) * 3 + 2];
        query[b * DD + d] = rel_repr[(b * RR + r0) * DD + d];
    }
}

// ==================== entity stage ===========================================
// bf16-canonical state, interleaved [v][b][d] (512 B per vertex), dbl-buffered.
__global__ __launch_bounds__(256) void l0_broadcast(
    const float* __restrict__ b0, const float* __restrict__ g0,
    const float* __restrict__ be0, unsigned short* __restrict__ x_bfi)
{
    int lane = threadIdx.x & 63;
    float bv = b0[lane];
    float m = wsum64(bv) * (1.0f / DD);
    float c = bv - m;
    float v = wsum64(c * c) * (1.0f / DD);
    float d = fmaxf(c * rsqrtf(v + 1e-5f) * g0[lane] + be0[lane], 0.0f);
    unsigned short dbf = f2bf_rne(d);
    int gw = blockIdx.x * 4 + (threadIdx.x >> 6);
    int nw = gridDim.x * 4;
    // value is row-uniform: flat order covers interleaved order too
    for (int row = gw; row < BB * NN; row += nw)
        x_bfi[(size_t)row * DD + lane] = dbf;
}

__global__ __launch_bounds__(256) void l0_fix(
    const int* __restrict__ bt, const int* __restrict__ fixlist,
    const int* __restrict__ cnt, const float* __restrict__ query,
    const float* __restrict__ rel_buf,
    const float* __restrict__ W0, const float* __restrict__ b0,
    const float* __restrict__ g0, const float* __restrict__ be0,
    unsigned short* __restrict__ x_bfi)
{
    int gidx = blockIdx.x * 4 + (threadIdx.x >> 6);  // 0..BB*FCAP-1
    int lane = threadIdx.x & 63;
    int b = gidx / FCAP, i = gidx - b * FCAP;
    int nc = min(cnt[b], FCAP);
    if (i >= nc) return;
    unsigned ent = (unsigned)fixlist[b * FCAP + i];
    int v = (int)(ent & 0xFFFFu);
    int h0 = bt[b * KK * 3];
    float q = query[b * DD + lane];
    float agg = (v == h0) ? q : 0.0f;
    for (int j = 0; j < nc; ++j) {
        unsigned ej = (unsigned)fixlist[b * FCAP + j];
        if ((int)(ej & 0xFFFFu) == v) {
            unsigned et = ej >> 16;
            if (et != 0xFFFFu)
                agg += q * rel_buf[(b * RR + (int)et) * DD + lane];
        }
    }
    float xr = (v == h0) ? q : 0.0f;
    float acc = b0[lane];
#pragma unroll 8
    for (int k = 0; k < DD; ++k) {
        acc += __shfl(xr, k, 64) * W0[k * DD + lane];
        acc += __shfl(agg, k, 64) * W0[(DD + k) * DD + lane];
    }
    float m = wsum64(acc) * (1.0f / DD);
    float c = acc - m;
    float vv = wsum64(c * c) * (1.0f / DD);
    float o = c * rsqrtf(vv + 1e-5f) * g0[lane] + be0[lane];
    float res = fmaxf(o, 0.0f) + xr;
    x_bfi[((size_t)v * BB + b) * DD + lane] = f2bf_rne(res);
}

// ==================== fused gather + MFMA dense (bf16-canonical) =============
__global__ __launch_bounds__(256) void gather_dense(
    const int* __restrict__ rowptr, const int* __restrict__ pack,
    const int* __restrict__ bt,
    const unsigned short* __restrict__ xin_bfi,
    const float* __restrict__ rel_buf, const float* __restrict__ query,
    const unsigned short* __restrict__ wfrag,
    const float* __restrict__ bias, const float* __restrict__ g,
    const float* __restrict__ beta,
    unsigned short* __restrict__ xout_bfi)
{
    __shared__ unsigned short aggL[4 * 16 * DD];  // 8 KB, per-wave 2 KB tile
    const int wid = (int)(threadIdx.x >> 6);
    const int lane = threadIdx.x & 63;
    const int v0 = blockIdx.x * 16 + wid * 4;   // wave's 4 vertices
    const int b = lane >> 4;
    const int d0 = (lane & 15) * 4;
    const float* rb = rel_buf + (size_t)b * RR * DD + d0;
    const int h0 = bt[b * KK * 3];
    char* wls = (char*)&aggL[wid * 16 * DD];

    // ---- gather phase ----
    for (int vv = 0; vv < 4; ++vv) {
        int v = v0 + vv;
        int beg = rowptr[v], end = rowptr[v + 1];
        f32x4 acc = {0.0f, 0.0f, 0.0f, 0.0f};
        int j = beg;
        for (; j + 1 < end; j += 2) {
            int p0 = pack[j], p1 = pack[j + 1];
            ushort4 xv0 = *(const ushort4*)&xin_bfi[((size_t)(p0 & 0xFFFF) * BB + b) * DD + d0];
            ushort4 xv1 = *(const ushort4*)&xin_bfi[((size_t)(p1 & 0xFFFF) * BB + b) * DD + d0];
            float4 r0 = *(const float4*)&rb[(size_t)(p0 >> 16) * DD];
            float4 r1 = *(const float4*)&rb[(size_t)(p1 >> 16) * DD];
            acc[0] += bf2f(xv0.x) * r0.x + bf2f(xv1.x) * r1.x;
            acc[1] += bf2f(xv0.y) * r0.y + bf2f(xv1.y) * r1.y;
            acc[2] += bf2f(xv0.z) * r0.z + bf2f(xv1.z) * r1.z;
            acc[3] += bf2f(xv0.w) * r0.w + bf2f(xv1.w) * r1.w;
        }
        if (j < end) {
            int p0 = pack[j];
            ushort4 xv0 = *(const ushort4*)&xin_bfi[((size_t)(p0 & 0xFFFF) * BB + b) * DD + d0];
            float4 r0 = *(const float4*)&rb[(size_t)(p0 >> 16) * DD];
            acc[0] += bf2f(xv0.x) * r0.x;
            acc[1] += bf2f(xv0.y) * r0.y;
            acc[2] += bf2f(xv0.z) * r0.z;
            acc[3] += bf2f(xv0.w) * r0.w;
        }
        if (v == h0) {
            float4 q = *(const float4*)&query[b * DD + d0];
            acc[0] += q.x; acc[1] += q.y; acc[2] += q.z; acc[3] += q.w;
        }
        ushort4 outv;
        outv.x = f2bf_rne(acc[0]);
        outv.y = f2bf_rne(acc[1]);
        outv.z = f2bf_rne(acc[2]);
        outv.w = f2bf_rne(acc[3]);
        int row = vv * 4 + b;                     // local row 0..15
        int off = (row * 128 + d0 * 2) ^ ((row & 7) << 4);
        *(ushort4*)(wls + off) = outv;
    }
    __syncthreads();

    // ---- dense phase (wave's rows = its own gathered vertices) ----
    s16x8 bfr[4][4];
#pragma unroll
    for (int t = 0; t < 4; ++t)
#pragma unroll
        for (int s = 0; s < 4; ++s)
            bfr[s][t] = *(const s16x8*)&wfrag[((size_t)(t * 4 + s) * 64 + lane) * 8];

    f32x4 acc[4] = {f32x4{0,0,0,0}, f32x4{0,0,0,0}, f32x4{0,0,0,0}, f32x4{0,0,0,0}};
    const int base = v0 * 4;
    const int lrow = lane & 15;
    const size_t arow = (size_t)(base + lrow) * DD;
    const int koff = (lane >> 4) * 8;
#pragma unroll
    for (int s = 0; s < 4; ++s) {
        s16x8 a;
        if (s < 2) {
            a = *(const s16x8*)(xin_bfi + arow + s * 32 + koff);
        } else {
            int off = (lrow * 128 + ((s - 2) * 32 + koff) * 2) ^ ((lrow & 7) << 4);
            a = *(const s16x8*)(wls + off);
        }
#pragma unroll
        for (int t = 0; t < 4; ++t)
            acc[t] = __builtin_amdgcn_mfma_f32_16x16x32_bf16(a, bfr[s][t], acc[t], 0, 0, 0);
    }

    float bia[4], gt[4], bet[4];
#pragma unroll
    for (int t = 0; t < 4; ++t) {
        int col = (lane & 15) + 16 * t;
        bia[t] = bias[col]; gt[t] = g[col]; bet[t] = beta[col];
    }
#pragma unroll
    for (int r = 0; r < 4; ++r) {
        float v0f = acc[0][r] + bia[0];
        float v1f = acc[1][r] + bia[1];
        float v2f = acc[2][r] + bia[2];
        float v3f = acc[3][r] + bia[3];
        float sum = v0f + v1f + v2f + v3f;
#pragma unroll
        for (int off = 1; off < 16; off <<= 1) sum += __shfl_xor(sum, off, 64);
        float m = sum * (1.0f / DD);
        float c0 = v0f - m, c1 = v1f - m, c2 = v2f - m, c3 = v3f - m;
        float q = c0 * c0 + c1 * c1 + c2 * c2 + c3 * c3;
#pragma unroll
        for (int off = 1; off < 16; off <<= 1) q += __shfl_xor(q, off, 64);
        float inv = rsqrtf(q * (1.0f / DD) + 1e-5f);
        int rf = base + (lane >> 4) * 4 + r;
        size_t irow = (size_t)rf * DD;
        float cs[4] = {c0, c1, c2, c3};
#pragma unroll
        for (int t = 0; t < 4; ++t) {
            int col = (lane & 15) + 16 * t;
            float xo = bf2f(xin_bfi[irow + col]);   // residual (L2-hot rows)
            float o = cs[t] * inv * gt[t] + bet[t];
            float res = fmaxf(o, 0.0f) + xo;
            xout_bfi[irow + col] = f2bf_rne(res);
        }
    }
}

// ==================== readout ================================================
__global__ __launch_bounds__(128) void readout(
    const int* __restrict__ bt, const unsigned short* __restrict__ x_bfi,
    const float* __restrict__ query,
    const float* __restrict__ W1, const float* __restrict__ b1,
    const float* __restrict__ W2, const float* __restrict__ b2,
    float* __restrict__ out)
{
    int b = blockIdx.x / KK, k = blockIdx.x - b * KK;
    int t = bt[(b * KK + k) * 3 + 1];
    __shared__ float feat[2 * DD];
    __shared__ float red[2 * DD];
    int j = threadIdx.x;
    if (j < DD) feat[j] = bf2f(x_bfi[((size_t)t * BB + b) * DD + j]);
    else        feat[j] = query[b * DD + (j - DD)];
    __syncthreads();
    float h = b1[j];
#pragma unroll 8
    for (int i = 0; i < 2 * DD; ++i) h += feat[i] * W1[i * 2 * DD + j];
    h = fmaxf(h, 0.0f);
    red[j] = h * W2[j];
    __syncthreads();
    for (int s = 64; s > 0; s >>= 1) {
        if (j < s) red[j] += red[j + s];
        __syncthreads();
    }
    if (j == 0) out[blockIdx.x] = red[0] + b2[0];
}

extern "C" void kernel_launch(void* const* d_in, const int* in_sizes, int n_in,
                              void* d_out, int out_size, void* d_ws, size_t ws_size,
                              hipStream_t stream) {
    const int*   edge_index     = (const int*)d_in[0];
    const int*   edge_type      = (const int*)d_in[1];
    const int*   rel_edge_index = (const int*)d_in[2];
    const int*   rel_edge_type  = (const int*)d_in[3];
    const int*   batch_triples  = (const int*)d_in[4];
    const float* rel_emb        = (const float*)d_in[5];
    const float* rel_W          = (const float*)d_in[6];
    const float* rel_b          = (const float*)d_in[7];
    const float* rel_g          = (const float*)d_in[8];
    const float* rel_beta       = (const float*)d_in[9];
    const float* proj_W1        = (const float*)d_in[10];
    const float* proj_b1        = (const float*)d_in[11];
    const float* proj_W2        = (const float*)d_in[12];
    const float* proj_b2        = (const float*)d_in[13];
    const float* ent_W          = (const float*)d_in[14];
    const float* ent_b          = (const float*)d_in[15];
    const float* ent_g          = (const float*)d_in[16];
    const float* ent_beta       = (const float*)d_in[17];
    const float* mlp_W1         = (const float*)d_in[18];
    const float* mlp_b1         = (const float*)d_in[19];
    const float* mlp_W2         = (const float*)d_in[20];
    const float* mlp_b2         = (const float*)d_in[21];

    float* ws = (float*)d_ws;
    float* xrel0    = ws;                                   // B*R*D
    float* xrel1    = xrel0    + BB * RR * DD;              // B*R*D
    float* rel_buf4 = xrel1    + BB * RR * DD;              // 4*B*R*D
    float* query    = rel_buf4 + 4 * BB * RR * DD;          // B*D
    int*   deg      = (int*)(query + BB * DD);              // N
    int*   rowptr   = deg + NN;                             // N+1
    int*   cursor   = rowptr + NN + 1;                      // N
    int*   pack     = cursor + NN;                          // E
    int*   fixlist  = pack + EE;                            // BB*FCAP
    int*   fixcnt   = fixlist + BB * FCAP;                  // BB
    int*   bsum     = fixcnt + BB;                          // NSB (pad 256)
    int*   boff     = bsum + 256;                           // NSB (pad 256)
    int*   rptrR    = boff + 256;                           // RR+1 (pad 66)
    int*   rpackR   = rptrR + 66;                           // ERE
    uintptr_t wp = (uintptr_t)(rpackR + ERE);
    wp = (wp + 15) & ~(uintptr_t)15;
    unsigned short* wbf    = (unsigned short*)wp;           // 3*16*64*8
    unsigned short* x_bfiA = wbf + 3 * 16 * 64 * 8;         // B*N*D bf16 [v][b][d]
    unsigned short* x_bfiB = x_bfiA + (size_t)BB * NN * DD; // B*N*D bf16 [v][b][d]

    // ---- CSR build + fixlist + rel CSR + W fragment pack ----
    hipMemsetAsync(deg, 0, sizeof(int) * NN, stream);
    hipMemsetAsync(fixcnt, 0, sizeof(int) * BB, stream);
    edge_scan<<<(EE + 255) / 256, 256, 0, stream>>>(
        edge_index, edge_type, batch_triples, deg, fixlist, fixcnt);
    scan_a<<<NSB, 256, 0, stream>>>(deg, bsum);
    setup_small<<<50, 256, 0, stream>>>(
        bsum, boff, rowptr, rel_edge_index, rel_edge_type, rptrR, rpackR,
        ent_W, wbf);
    scan_c<<<NSB, 256, 0, stream>>>(deg, boff, rowptr, cursor);
    csr_fill<<<(EE + 255) / 256, 256, 0, stream>>>(edge_index, edge_type, cursor, pack);

    // ---- relation stage ----
    rel_layer0<<<BB * RR / 4, 256, 0, stream>>>(
        rptrR, rpackR, batch_triples, rel_emb,
        rel_W, rel_b, rel_g, rel_beta, xrel1);
    for (int l = 1; l < LL; ++l) {
        const float* xin = (l & 1) ? xrel1 : xrel0;
        float* xout = (l & 1) ? xrel0 : xrel1;
        rel_layer<<<BB * RR / 4, 256, 0, stream>>>(
            rptrR, rpackR, batch_triples, rel_emb + l * RT * DD,
            rel_W + l * 2 * DD * DD, rel_b + l * DD,
            rel_g + l * DD, rel_beta + l * DD, xin, xout);
    }
    float* rel_repr = xrel0;  // l=1 wrote xrel0, l=2 xrel1, l=3 xrel0
    rel_projq<<<4 * BB * RR / 4, 256, 0, stream>>>(
        rel_repr, batch_triples, proj_W1, proj_b1, proj_W2, proj_b2,
        rel_buf4, query);

    // ---- entity stage: layer 0 fast path ----
    l0_broadcast<<<1024, 256, 0, stream>>>(ent_b, ent_g, ent_beta, x_bfiA);
    l0_fix<<<(BB * FCAP) / 4, 256, 0, stream>>>(
        batch_triples, fixlist, fixcnt, query, rel_buf4,
        ent_W, ent_b, ent_g, ent_beta, x_bfiA);

    // ---- entity stage: layers 1..3 (fused gather + MFMA dense) ----
    unsigned short* bufs[2] = {x_bfiA, x_bfiB};
    for (int l = 1; l < LL; ++l) {
        gather_dense<<<NN / 16, 256, 0, stream>>>(
            rowptr, pack, batch_triples, bufs[(l - 1) & 1],
            rel_buf4 + l * BB * RR * DD, query,
            wbf + (size_t)(l - 1) * 16 * 64 * 8,
            ent_b + l * DD, ent_g + l * DD, ent_beta + l * DD,
            bufs[l & 1]);
    }

    readout<<<BB * KK, 2 * DD, 0, stream>>>(batch_triples, bufs[1], query,
                                            mlp_W1, mlp_b1, mlp_W2, mlp_b2,
                                            (float*)d_out);
}